// Round 9
// baseline (18302.325 us; speedup 1.0000x reference)
//
#include <hip/hip_runtime.h>

typedef short bf16x8 __attribute__((ext_vector_type(8)));
typedef float f32x4 __attribute__((ext_vector_type(4)));

#define DEV static __device__ __forceinline__
#define SCOPE_AGENT __HIP_MEMORY_SCOPE_AGENT

// ---------------- numeric helpers ----------------
DEV unsigned short f2bf(float f) {
  unsigned u = __float_as_uint(f);
  unsigned r = u + 0x7fffu + ((u >> 16) & 1u);
  return (unsigned short)(r >> 16);
}
DEV float bf2f(unsigned short h) { return __uint_as_float(((unsigned)h) << 16); }
DEV void f2hilo(float f, unsigned short& hi, unsigned short& lo) {
  hi = f2bf(f);
  lo = f2bf(f - bf2f(hi));
}
DEV float sigm(float x) { return 1.f / (1.f + __expf(-x)); }
DEV float tanh_(float x) {
  x = fminf(15.f, fmaxf(-15.f, x));
  float e = __expf(2.f * x);
  return (e - 1.f) / (e + 1.f);
}

// ---------------- coherent (LLC) access helpers ----------------
DEV void st_sc_u16(unsigned short* p, unsigned short v) {
  __hip_atomic_store(p, v, __ATOMIC_RELAXED, SCOPE_AGENT);
}
DEV void st_sc_f32(float* p, float v) {
  __hip_atomic_store(p, v, __ATOMIC_RELAXED, SCOPE_AGENT);
}
DEV void st_sc_u64(unsigned long long* p, unsigned long long v) {
  __hip_atomic_store(p, v, __ATOMIC_RELAXED, SCOPE_AGENT);
}
DEV unsigned long long ld_sc_u64(const unsigned long long* p) {
  return __hip_atomic_load((unsigned long long*)p, __ATOMIC_RELAXED, SCOPE_AGENT);
}
DEV unsigned ld_sc_u32(const unsigned* p) {
  return __hip_atomic_load((unsigned*)p, __ATOMIC_RELAXED, SCOPE_AGENT);
}
DEV void vm_drain() { asm volatile("s_waitcnt vmcnt(0)" ::: "memory"); }

// ---------------- workspace layout ----------------
constexpr size_t WE1 = 1024 * 352, WE2 = 1024 * 512, WE3 = 1024 * 512,
                 WD1 = 1024 * 768, WD2 = 1024 * 512, WD3 = 320 * 352,
                 WKEY = 256 * 256, WVAL = 256 * 256, WEMB = 256 * 96;
constexpr size_t E1HI = 0, E1LO = E1HI + WE1, E2HI = E1LO + WE1, E2LO = E2HI + WE2,
                 E3HI = E2LO + WE2, E3LO = E3HI + WE3, D1HI = E3LO + WE3, D1LO = D1HI + WD1,
                 D2HI = D1LO + WD1, D2LO = D2HI + WD2, D3HI = D2LO + WD2, D3LO = D3HI + WD3,
                 KHI = D3LO + WD3, KLO = KHI + WKEY, VHI = KLO + WKEY, VLO = VHI + WVAL,
                 EMHI = VLO + WVAL, EMLO = EMHI + WEMB, WTOT = EMLO + WEMB;

constexpr size_t XPAD_ELEMS = (size_t)400 * 64 * 96;
constexpr size_t XPAD_HI_B = WTOT * 2;
constexpr size_t XPAD_LO_B = XPAD_HI_B + XPAD_ELEMS * 2;
constexpr size_t STATE_B = XPAD_LO_B + XPAD_ELEMS * 2;

// state (zeroed each launch): h buffers + flag arrays
constexpr size_t H256_SZB = (size_t)2 * 2 * 64 * 256 * 2;  // [parity][hi/lo][64][256] u16
constexpr size_t HE1 = 0, HE2 = H256_SZB, HE3 = 2 * H256_SZB, HD1 = 3 * H256_SZB,
                 HD2 = 4 * H256_SZB;
constexpr size_t HLAST = 5 * H256_SZB;  // [2][2][64][96] u16
constexpr size_t HLAST_SZB = (size_t)2 * 2 * 64 * 96 * 2;
constexpr size_t BARO = HLAST + HLAST_SZB;  // cnt[9][400] u32
constexpr size_t STATE_BYTES = BARO + 9 * 400 * 4 + 64;

// non-zeroed (fully rewritten before first read each launch)
constexpr size_t RINGK_B = STATE_B + STATE_BYTES;
constexpr size_t RING_SZ = (size_t)22 * 64 * 256 * 4;  // per-batch self-ordered (at owns rows)
constexpr size_t RINGV_B = RINGK_B + RING_SZ;
constexpr size_t CTXH_B = RINGV_B + RING_SZ;
constexpr size_t CTXL_B = CTXH_B + (size_t)64 * 256 * 2;
constexpr size_t D1BP_B = CTXL_B + (size_t)64 * 256 * 2;  // folded d1 bias f32[1024]
constexpr size_t WS_NEED = D1BP_B + 4096;

// layer flag ids; cnt[l][t] counts WGs of layer l done with step t
#define LE1 0
#define LE2 1
#define LE3 2
#define LAT 5
#define LD1 6
#define LD2 7
#define LD3 8
// WG map: e1 0-7 | e2 8-15 | e3 16-23 | at 24-39 (kv fused) | d1 40-47 | d2 48-55 | d3 56-58
// targets: e1/e2/e3/d1/d2: 8, at: 16, d3: 3

constexpr int NWG = 59;
constexpr int WGS = 256;

// ---------------- prep kernels ----------------
__global__ void prep_w(const float* __restrict__ wih, int din, const float* __restrict__ whh,
                       int dh, int rows, int dinp, int kp, unsigned short* __restrict__ whi,
                       unsigned short* __restrict__ wlo) {
  size_t idx = (size_t)blockIdx.x * 256 + threadIdx.x;
  size_t tot = (size_t)rows * kp;
  if (idx >= tot) return;
  int j = (int)(idx / kp), k = (int)(idx % kp);
  float v = 0.f;
  if (k < dinp) {
    if (k < din) v = wih[(size_t)j * din + k];
  } else {
    int k2 = k - dinp;
    if (k2 < dh) v = whh[(size_t)j * dh + k2];
  }
  unsigned short hi, lo;
  f2hilo(v, hi, lo);
  whi[idx] = hi;
  wlo[idx] = lo;
}

// d1 folded weights: [1024][608] = [ W_comb(96: d1Wih[:, :256]@embW, cols>=80 zero) |
//                                    d1Wih[:,256:512] (ctx) | d1Whh (h) ]
__global__ void prep_d1_w(const float* __restrict__ wih, const float* __restrict__ whh,
                          const float* __restrict__ embW, unsigned short* __restrict__ whi,
                          unsigned short* __restrict__ wlo) {
  size_t idx = (size_t)blockIdx.x * 256 + threadIdx.x;
  constexpr size_t tot = (size_t)1024 * 608;
  if (idx >= tot) return;
  int j = (int)(idx / 608), f = (int)(idx % 608);
  float v = 0.f;
  if (f < 96) {
    if (f < 80) {
      const float* wr = wih + (size_t)j * 512;
#pragma unroll 4
      for (int m = 0; m < 256; m++) v += wr[m] * embW[(size_t)m * 80 + f];
    }
  } else if (f < 352) {
    v = wih[(size_t)j * 512 + 256 + (f - 96)];
  } else {
    v = whh[(size_t)j * 256 + (f - 352)];
  }
  unsigned short hi, lo;
  f2hilo(v, hi, lo);
  whi[idx] = hi;
  wlo[idx] = lo;
}

__global__ void prep_d1_bias(const float* __restrict__ wih, const float* __restrict__ embb,
                             const float* __restrict__ d1b, float* __restrict__ out) {
  int j = blockIdx.x * 256 + threadIdx.x;
  if (j >= 1024) return;
  float v = d1b[j];
  const float* wr = wih + (size_t)j * 512;
#pragma unroll 4
  for (int m = 0; m < 256; m++) v += wr[m] * embb[m];
  out[j] = v;
}

__global__ void prep_x(const float* __restrict__ x, unsigned short* __restrict__ xh,
                       unsigned short* __restrict__ xl) {
  size_t idx = (size_t)blockIdx.x * 256 + threadIdx.x;
  if (idx >= XPAD_ELEMS) return;
  int t = (int)(idx / 6144), rbf = (int)(idx % 6144), b = rbf / 96, f = rbf % 96;
  float v = (f < 80) ? x[(size_t)b * 32000 + (size_t)t * 80 + f] : 0.f;
  unsigned short hi, lo;
  f2hilo(v, hi, lo);
  xh[idx] = hi;
  xl[idx] = lo;
}

// ---------------- main kernel pieces ----------------
// LDS staging with 16B XOR swizzle: u16 col c -> c ^ ((row&7)<<3)

template <int COLS, int STRIDE>
DEV void copy_hl(unsigned short* lds, const unsigned short* hi, const unsigned short* lo,
                 int tid) {
  constexpr int CU64 = COLS / 4;
  constexpr int PER = 64 * CU64;
  constexpr int TOT = PER * 2;
  constexpr int loOff = 64 * STRIDE;
  // 32-deep: a full 64KB chunk (TOT=8192) issues in ONE batch -> one LLC RTT
  for (int base = 0; base < TOT; base += WGS * 32) {
    unsigned long long v[32];
    int dst[32];
#pragma unroll
    for (int u = 0; u < 32; u++) {
      int i = base + u * WGS + tid;
      dst[u] = -1;
      if (i < TOT) {
        int pl = (i >= PER) ? 1 : 0;
        int j = pl ? (i - PER) : i;
        int row = j / CU64, cc = j - row * CU64;
        const unsigned long long* s = (const unsigned long long*)(pl ? lo : hi);
        v[u] = ld_sc_u64(s + j);
        dst[u] = (pl ? loOff : 0) + row * STRIDE + ((cc * 4) ^ ((row & 7) << 3));
      }
    }
#pragma unroll
    for (int u = 0; u < 32; u++)
      if (dst[u] >= 0) *(unsigned long long*)(lds + dst[u]) = v[u];
  }
}

DEV void mfma3(f32x4& acc, bf16x8 ah, bf16x8 al, bf16x8 bh, bf16x8 bl) {
  acc = __builtin_amdgcn_mfma_f32_16x16x32_bf16(ah, bh, acc, 0, 0, 0);
  acc = __builtin_amdgcn_mfma_f32_16x16x32_bf16(al, bh, acc, 0, 0, 0);
  acc = __builtin_amdgcn_mfma_f32_16x16x32_bf16(ah, bl, acc, 0, 0, 0);
}

DEV void zacc44(f32x4 (&a)[4][4]) {
#pragma unroll
  for (int g = 0; g < 4; g++)
#pragma unroll
    for (int m = 0; m < 4; m++) a[g][m] = f32x4{0.f, 0.f, 0.f, 0.f};
}

// MFMA over kb index range [kbLo,kbHi) of the staged chunk (K-split support)
template <int STRIDE>
DEV void mfma_range(const unsigned short* lds, int lane, int ut, int H,
                    const unsigned short* __restrict__ Whi,
                    const unsigned short* __restrict__ Wlo, int Kp, int kwOff, int kbLo,
                    int kbHi, f32x4 (&acc)[4][4]) {
  const int col = lane & 15, kg = lane >> 4;
  constexpr int loOff = 64 * STRIDE;
  for (int kb = kbLo; kb < kbHi; kb++) {
    const int ka = kb * 32 + kg * 8;
    bf16x8 ah[4], al[4];
#pragma unroll
    for (int m = 0; m < 4; m++) {
      int row = m * 16 + col;
      int off = row * STRIDE + (ka ^ ((row & 7) << 3));
      ah[m] = *(const bf16x8*)(lds + off);
      al[m] = *(const bf16x8*)(lds + loOff + off);
    }
#pragma unroll
    for (int g = 0; g < 4; g++) {
      size_t wr = (size_t)(g * H + ut * 16 + col) * Kp + kwOff + ka;
      bf16x8 bh = *(const bf16x8*)(Whi + wr);
      bf16x8 bl = *(const bf16x8*)(Wlo + wr);
#pragma unroll
      for (int m = 0; m < 4; m++) mfma3(acc[g][m], ah[m], al[m], bh, bl);
    }
  }
}

// one staged chunk: barrier, copy, barrier, half-K MFMA
template <int COLS, int STRIDE>
DEV void chunk_pass(unsigned short* lds, const unsigned short* hi, const unsigned short* lo,
                    int tid, int lane, int ut, int utActive, int H,
                    const unsigned short* __restrict__ Whi,
                    const unsigned short* __restrict__ Wlo, int Kp, int kwOff, int half,
                    f32x4 (&acc)[4][4]) {
  __syncthreads();  // releases spin + previous LDS consumers done
  copy_hl<COLS, STRIDE>(lds, hi, lo, tid);
  __syncthreads();
  constexpr int NKB = COLS / 32;
  const int lo_kb = half ? (NKB + 1) / 2 : 0;
  const int hi_kb = half ? NKB : (NKB + 1) / 2;
  if (utActive) mfma_range<STRIDE>(lds, lane, ut, H, Whi, Wlo, Kp, kwOff, lo_kb, hi_kb, acc);
}

// combine the two K-halves: half1 writes partials to LDS, half0 adds
DEV void reduce_pair(unsigned short* lds, int lane, int pair, int half, f32x4 (&acc)[4][4]) {
  float* red = (float*)lds;
  const int base = (pair * 64 + lane) * 68;  // stride 68 f32 -> banks spread
  __syncthreads();
  if (half) {
#pragma unroll
    for (int g = 0; g < 4; g++)
#pragma unroll
      for (int m = 0; m < 4; m++)
#pragma unroll
        for (int r = 0; r < 4; r++) red[base + (g * 4 + m) * 4 + r] = acc[g][m][r];
  }
  __syncthreads();
  if (!half) {
#pragma unroll
    for (int g = 0; g < 4; g++)
#pragma unroll
      for (int m = 0; m < 4; m++)
#pragma unroll
        for (int r = 0; r < 4; r++) acc[g][m][r] += red[base + (g * 4 + m) * 4 + r];
  }
}

DEV void cell_update(int lane, int ut, int H, int Hpad, const float* __restrict__ bias,
                     f32x4 (&acc)[4][4], float (&c)[4][4], unsigned short* hwhi,
                     unsigned short* hwlo, float* outp) {
  const int col = lane & 15, kg = lane >> 4;
  const int u = ut * 16 + col;
  const float bi = bias[u], bff = bias[H + u], bg = bias[2 * H + u], bo = bias[3 * H + u];
#pragma unroll
  for (int m = 0; m < 4; m++)
#pragma unroll
    for (int r = 0; r < 4; r++) {
      int b = m * 16 + kg * 4 + r;
      float gi = acc[0][m][r] + bi, gf = acc[1][m][r] + bff;
      float gg = acc[2][m][r] + bg, go = acc[3][m][r] + bo;
      float cn = sigm(gf) * c[m][r] + sigm(gi) * tanh_(gg);
      float hh = sigm(go) * tanh_(cn);
      c[m][r] = cn;
      unsigned short hi, lo;
      f2hilo(hh, hi, lo);
      st_sc_u16(hwhi + b * Hpad + u, hi);
      st_sc_u16(hwlo + b * Hpad + u, lo);
      if (outp) outp[(size_t)b * 30400 + u] = hh;
    }
}

// up to 3 flag waits; null ptr = skip
DEV void spin3(const unsigned* p0, unsigned t0, const unsigned* p1, unsigned t1,
               const unsigned* p2, unsigned t2) {
  for (;;) {
    unsigned a = p0 ? ld_sc_u32(p0) : 0xFFFFFFFFu;
    unsigned b = p1 ? ld_sc_u32(p1) : 0xFFFFFFFFu;
    unsigned c = p2 ? ld_sc_u32(p2) : 0xFFFFFFFFu;
    if (a >= t0 && b >= t1 && c >= t2) return;
    __builtin_amdgcn_s_sleep(1);
  }
}

// WAR/RAW audit (kv fused into at; at(t) computes kv(s), s = t<=20 ? t : t-1; t=21 skips):
//  e1(t): [LE1 t-1] own HE1[q]; [LD3 t-1 RAW hlast, LE2 t-2 WAR HE1[p]].
//  e2(t): [LE2 t-1] own; [LE1 t RAW, LE3 t-2 WAR HE2[p]].
//  e3(t): [LE3 t-1] own; [LE2 t RAW]; PRE-WRITE [LAT t-1 >=16]: at(t-1) is the last
//    reader of he3 parity p (kv(t-2) enc-phase / kv(t-1)... at(t-1) reads he3(s'),
//    s' parity = p for the instance being overwritten) — spin placed after MFMAs,
//    before cell_update stores.
//  at(t): [LE3 s >=8 RAW he3]; t>=21 also [LD2 t-1 RAW q, LD1 t-1 WAR ctx].
//    ring[slot][own batches]: written & read only by this WG -> self-ordered, no flags.
//  d1(t): [LD1 t-1] own (+ d2(t-2) WAR via LAT t <= LD2 t-1); [LD3 t-1] hlast; [LAT t] ctx.
//  d2(t): [LD2 t-1] own; [LD1 t RAW; covers WAR HD2[p]: at(t-1) via LD1 t <= d1(t) <= LAT t
//    <= at(t) <= at(t-1) sequential; d3(t-2) via LD1 t <= LD3 t-1 chain].
//  d3(t): [LD3 t-1] own HLAST[q]; [LD2 t RAW; WAR HLAST[p]: e1(t-1)/d1(t-1) via
//    LD2 t <= LD1 t <= LAT t <= LE3 t-1 <= ... <= LE1 t-1 and LD1 t => d1(t-1)].
__global__ void __launch_bounds__(WGS, 1)
seq_main(const float* e1b, const float* e2b, const float* e3b, const float* d2b,
         const float* d3b, const float* keyb, const float* valb, float* dout,
         unsigned char* ws) {
  __shared__ unsigned short lds_s[32768];  // 64 KB
  unsigned short* lds = lds_s;

  const int wg = blockIdx.x, tid = threadIdx.x;
  const int wv = tid >> 6, lane = tid & 63;
  const int pair = wv >> 1, half = wv & 1;

  unsigned short* W = (unsigned short*)ws;
  const unsigned short* xh = (const unsigned short*)(ws + XPAD_HI_B);
  const unsigned short* xl = (const unsigned short*)(ws + XPAD_LO_B);
  unsigned char* st = ws + STATE_B;
  float* ringk = (float*)(ws + RINGK_B);
  float* ringv = (float*)(ws + RINGV_B);
  unsigned short* ctxh = (unsigned short*)(ws + CTXH_B);
  unsigned short* ctxl = (unsigned short*)(ws + CTXL_B);
  const float* d1bp = (const float*)(ws + D1BP_B);
  unsigned* C = (unsigned*)(st + BARO);
  auto CNT = [&](int l, int tt) { return C + l * 400 + tt; };

  auto hb = [&](size_t off, int par, int hl, int Hpad) {
    return (unsigned short*)(st + off) + (size_t)(par * 2 + hl) * 64 * Hpad;
  };
  auto bump = [&](int l, int tt) {
    if (tid == 0) __hip_atomic_fetch_add(CNT(l, tt), 1u, __ATOMIC_RELAXED, SCOPE_AGENT);
  };

  if (wg < 8) {  // ------------- e1 -------------
    const int ut = wg * 2 + pair;
    float c[4][4] = {{0.f}};
    for (int t = 0; t < 400; ++t) {
      const int p = t & 1, q = p ^ 1;
      f32x4 acc[4][4];
      zacc44(acc);
      if (tid == 0 && t >= 1) spin3(CNT(LE1, t - 1), 8, nullptr, 0, nullptr, 0);
      chunk_pass<256, 256>(lds, hb(HE1, q, 0, 256), hb(HE1, q, 1, 256), tid, lane, ut, 1, 256,
                           W + E1HI, W + E1LO, 352, 96, half, acc);
      if (tid == 0)
        spin3(t >= 21 ? CNT(LD3, t - 1) : nullptr, 3, t >= 2 ? CNT(LE2, t - 2) : nullptr, 8,
              nullptr, 0);
      if (t <= 20)
        chunk_pass<96, 128>(lds, xh + (size_t)t * 6144, xl + (size_t)t * 6144, tid, lane, ut, 1,
                            256, W + E1HI, W + E1LO, 352, 0, half, acc);
      else
        chunk_pass<96, 128>(lds, hb(HLAST, q, 0, 96), hb(HLAST, q, 1, 96), tid, lane, ut, 1,
                            256, W + E1HI, W + E1LO, 352, 0, half, acc);
      reduce_pair(lds, lane, pair, half, acc);
      if (!half)
        cell_update(lane, ut, 256, 256, e1b, acc, c, hb(HE1, p, 0, 256), hb(HE1, p, 1, 256),
                    nullptr);
      vm_drain();
      __syncthreads();
      bump(LE1, t);
    }
  } else if (wg < 16) {  // ------------- e2 -------------
    const int ut = (wg - 8) * 2 + pair;
    float c[4][4] = {{0.f}};
    for (int t = 0; t < 400; ++t) {
      const int p = t & 1, q = p ^ 1;
      f32x4 acc[4][4];
      zacc44(acc);
      if (tid == 0 && t >= 1) spin3(CNT(LE2, t - 1), 8, nullptr, 0, nullptr, 0);
      chunk_pass<256, 256>(lds, hb(HE2, q, 0, 256), hb(HE2, q, 1, 256), tid, lane, ut, 1, 256,
                           W + E2HI, W + E2LO, 512, 256, half, acc);
      if (tid == 0)
        spin3(CNT(LE1, t), 8, t >= 2 ? CNT(LE3, t - 2) : nullptr, 8, nullptr, 0);
      chunk_pass<256, 256>(lds, hb(HE1, p, 0, 256), hb(HE1, p, 1, 256), tid, lane, ut, 1, 256,
                           W + E2HI, W + E2LO, 512, 0, half, acc);
      reduce_pair(lds, lane, pair, half, acc);
      if (!half)
        cell_update(lane, ut, 256, 256, e2b, acc, c, hb(HE2, p, 0, 256), hb(HE2, p, 1, 256),
                    nullptr);
      vm_drain();
      __syncthreads();
      bump(LE2, t);
    }
  } else if (wg < 24) {  // ------------- e3 -------------
    const int ut = (wg - 16) * 2 + pair;
    float c[4][4] = {{0.f}};
    for (int t = 0; t < 400; ++t) {
      const int p = t & 1, q = p ^ 1;
      f32x4 acc[4][4];
      zacc44(acc);
      if (tid == 0 && t >= 1) spin3(CNT(LE3, t - 1), 8, nullptr, 0, nullptr, 0);
      chunk_pass<256, 256>(lds, hb(HE3, q, 0, 256), hb(HE3, q, 1, 256), tid, lane, ut, 1, 256,
                           W + E3HI, W + E3LO, 512, 256, half, acc);
      if (tid == 0) spin3(CNT(LE2, t), 8, nullptr, 0, nullptr, 0);
      chunk_pass<256, 256>(lds, hb(HE2, p, 0, 256), hb(HE2, p, 1, 256), tid, lane, ut, 1, 256,
                           W + E3HI, W + E3LO, 512, 0, half, acc);
      reduce_pair(lds, lane, pair, half, acc);
      // pre-write WAR: last reader of HE3[p]-instance being overwritten is at(t-1)
      if (tid == 0 && t >= 1) spin3(CNT(LAT, t - 1), 16, nullptr, 0, nullptr, 0);
      __syncthreads();
      if (!half)
        cell_update(lane, ut, 256, 256, e3b, acc, c, hb(HE3, p, 0, 256), hb(HE3, p, 1, 256),
                    nullptr);
      vm_drain();
      __syncthreads();
      bump(LE3, t);
    }
  } else if (wg < 40) {  // ------------- at: 16 WGs, kv fused, 1 batch/wave -------------
    const int b0 = (wg - 24) * 4;
    float* kvx = (float*)(lds + 8192);  // f32[4][512] exchange (k | v)
    for (int t = 0; t < 400; ++t) {
      const int s = (t <= 20) ? t : t - 1;  // kv step computed this iteration
      const int ps = s & 1;
      const bool doKV = (t != 21);  // t=21's kv(20) already computed at t=20 (kvx persists)
      if (tid == 0) {
        if (t <= 20)
          spin3(CNT(LE3, t), 8, nullptr, 0, nullptr, 0);
        else
          spin3(CNT(LE3, t - 1), 8, CNT(LD2, t - 1), 8, CNT(LD1, t - 1), 8);
      }
      __syncthreads();
      if (doKV) {
        // stage he3[b0..b0+3][0..255] hi+lo -> LDS rows 0..3 (rows 4-15 garbage, unused)
        for (int i = tid; i < 512; i += WGS) {
          int pl = i >> 8, j = i & 255, row = j >> 6, cc = j & 63;
          const unsigned long long* srcp =
              (const unsigned long long*)hb(HE3, ps, pl, 256) + (size_t)(b0 + row) * 64 + cc;
          unsigned long long v = ld_sc_u64(srcp);
          *(unsigned long long*)(lds + pl * 4096 + row * 256 +
                                 ((cc * 4) ^ ((row & 7) << 3))) = v;
        }
        __syncthreads();
        // kv MFMA (M=16 padded, rows 0-3 valid): wave wv does jt = wv*8..wv*8+7
        const int slot = s % 22;
        const int col = lane & 15, kg = lane >> 4;
        for (int jj = 0; jj < 8; ++jj) {
          int jt = wv * 8 + jj;
          bool isK = jt < 16;
          int j = (isK ? jt : jt - 16) * 16 + col;
          const unsigned short* Whi = W + (isK ? KHI : VHI);
          const unsigned short* Wlo = W + (isK ? KLO : VLO);
          f32x4 acc = f32x4{0.f, 0.f, 0.f, 0.f};
          for (int kb = 0; kb < 8; kb++) {
            int ka = kb * 32 + kg * 8;
            int offA = col * 256 + (ka ^ ((col & 7) << 3));
            bf16x8 ah = *(const bf16x8*)(lds + offA);
            bf16x8 al = *(const bf16x8*)(lds + 4096 + offA);
            size_t wr = (size_t)j * 256 + ka;
            bf16x8 bh = *(const bf16x8*)(Whi + wr);
            bf16x8 bl = *(const bf16x8*)(Wlo + wr);
            mfma3(acc, ah, al, bh, bl);
          }
          if (kg == 0) {
            float bj = (isK ? keyb : valb)[j];
            float* ringp = (isK ? ringk : ringv) + (size_t)slot * 64 * 256;
#pragma unroll
            for (int r = 0; r < 4; r++) {
              float v = acc[r] + bj;
              st_sc_f32(ringp + (size_t)(b0 + r) * 256 + j, v);  // for future steps
              kvx[r * 512 + (isK ? j : 256 + j)] = v;            // for this step
            }
          }
        }
        __syncthreads();
      }
      if (t == 20) {
        // ctx := v20 (just computed, in kvx)
        float f[4];
#pragma unroll
        for (int j = 0; j < 4; j++) f[j] = kvx[wv * 512 + 256 + lane * 4 + j];
        unsigned short hi[4], lo[4];
#pragma unroll
        for (int j = 0; j < 4; j++) f2hilo(f[j], hi[j], lo[j]);
        unsigned long long ph = (unsigned long long)hi[0] | ((unsigned long long)hi[1] << 16) |
                                ((unsigned long long)hi[2] << 32) |
                                ((unsigned long long)hi[3] << 48);
        unsigned long long pl = (unsigned long long)lo[0] | ((unsigned long long)lo[1] << 16) |
                                ((unsigned long long)lo[2] << 32) |
                                ((unsigned long long)lo[3] << 48);
        st_sc_u64((unsigned long long*)(ctxh + (b0 + wv) * 256 + lane * 4), ph);
        st_sc_u64((unsigned long long*)(ctxl + (b0 + wv) * 256 + lane * 4), pl);
      } else if (t >= 21) {
        const int b = b0 + wv;
        const int qp = (t & 1) ^ 1;
        const unsigned short* qh = hb(HD2, qp, 0, 256);
        const unsigned short* ql = hb(HD2, qp, 1, 256);
        unsigned long long hq = ld_sc_u64((const unsigned long long*)(qh + b * 256 + lane * 4));
        unsigned long long lq = ld_sc_u64((const unsigned long long*)(ql + b * 256 + lane * 4));
        float qv[4];
#pragma unroll
        for (int j = 0; j < 4; j++)
          qv[j] = bf2f((unsigned short)(hq >> (16 * j))) + bf2f((unsigned short)(lq >> (16 * j)));
        float sArr[20];
#pragma unroll
        for (int i = 0; i < 19; i++) {
          int slot = (t - 20 + i) % 22;
          const unsigned long long* kp =
              (const unsigned long long*)(ringk + ((size_t)slot * 64 + b) * 256 + lane * 4);
          unsigned long long k0 = ld_sc_u64(kp), k1 = ld_sc_u64(kp + 1);
          sArr[i] = __uint_as_float((unsigned)k0) * qv[0] +
                    __uint_as_float((unsigned)(k0 >> 32)) * qv[1] +
                    __uint_as_float((unsigned)k1) * qv[2] +
                    __uint_as_float((unsigned)(k1 >> 32)) * qv[3];
        }
        {  // newest slot (t-1) from LDS exchange
          float acc19 = 0.f;
#pragma unroll
          for (int j = 0; j < 4; j++) acc19 += kvx[wv * 512 + lane * 4 + j] * qv[j];
          sArr[19] = acc19;
        }
#pragma unroll
        for (int off = 32; off >= 1; off >>= 1)
#pragma unroll
          for (int i = 0; i < 20; i++) sArr[i] += __shfl_xor(sArr[i], off, 64);
        float mx = sArr[0];
#pragma unroll
        for (int i = 1; i < 20; i++) mx = fmaxf(mx, sArr[i]);
        float den = 0.f;
#pragma unroll
        for (int i = 0; i < 20; i++) {
          sArr[i] = __expf(sArr[i] - mx);
          den += sArr[i];
        }
        float inv = 1.f / den;
        float a0 = 0.f, a1 = 0.f, a2 = 0.f, a3 = 0.f;
#pragma unroll
        for (int i = 0; i < 19; i++) {
          int slot = (t - 20 + i) % 22;
          const unsigned long long* vp =
              (const unsigned long long*)(ringv + ((size_t)slot * 64 + b) * 256 + lane * 4);
          unsigned long long v0 = ld_sc_u64(vp), v1 = ld_sc_u64(vp + 1);
          a0 += sArr[i] * __uint_as_float((unsigned)v0);
          a1 += sArr[i] * __uint_as_float((unsigned)(v0 >> 32));
          a2 += sArr[i] * __uint_as_float((unsigned)v1);
          a3 += sArr[i] * __uint_as_float((unsigned)(v1 >> 32));
        }
        a0 += sArr[19] * kvx[wv * 512 + 256 + lane * 4 + 0];
        a1 += sArr[19] * kvx[wv * 512 + 256 + lane * 4 + 1];
        a2 += sArr[19] * kvx[wv * 512 + 256 + lane * 4 + 2];
        a3 += sArr[19] * kvx[wv * 512 + 256 + lane * 4 + 3];
        float f[4] = {a0 * inv, a1 * inv, a2 * inv, a3 * inv};
        unsigned short hi[4], lo[4];
#pragma unroll
        for (int j = 0; j < 4; j++) f2hilo(f[j], hi[j], lo[j]);
        unsigned long long ph = (unsigned long long)hi[0] | ((unsigned long long)hi[1] << 16) |
                                ((unsigned long long)hi[2] << 32) |
                                ((unsigned long long)hi[3] << 48);
        unsigned long long pl = (unsigned long long)lo[0] | ((unsigned long long)lo[1] << 16) |
                                ((unsigned long long)lo[2] << 32) |
                                ((unsigned long long)lo[3] << 48);
        st_sc_u64((unsigned long long*)(ctxh + b * 256 + lane * 4), ph);
        st_sc_u64((unsigned long long*)(ctxl + b * 256 + lane * 4), pl);
      }
      vm_drain();
      __syncthreads();
      bump(LAT, t);
    }
  } else if (wg < 48) {  // ------------- d1 (emb folded): Kp=608 -------------
    const int ut = (wg - 40) * 2 + pair;
    float c[4][4] = {{0.f}};
    for (int t = 20; t < 400; ++t) {
      const int p = t & 1, q = p ^ 1;
      f32x4 acc[4][4];
      zacc44(acc);
      if (tid == 0 && t >= 21) spin3(CNT(LD1, t - 1), 8, nullptr, 0, nullptr, 0);
      chunk_pass<256, 256>(lds, hb(HD1, q, 0, 256), hb(HD1, q, 1, 256), tid, lane, ut, 1, 256,
                           W + D1HI, W + D1LO, 608, 352, half, acc);
      if (tid == 0 && t >= 21) spin3(CNT(LD3, t - 1), 3, nullptr, 0, nullptr, 0);
      if (t == 20)
        chunk_pass<96, 128>(lds, xh + (size_t)19 * 6144, xl + (size_t)19 * 6144, tid, lane, ut,
                            1, 256, W + D1HI, W + D1LO, 608, 0, half, acc);
      else
        chunk_pass<96, 128>(lds, hb(HLAST, q, 0, 96), hb(HLAST, q, 1, 96), tid, lane, ut, 1,
                            256, W + D1HI, W + D1LO, 608, 0, half, acc);
      if (tid == 0) spin3(CNT(LAT, t), 16, nullptr, 0, nullptr, 0);
      chunk_pass<256, 256>(lds, ctxh, ctxl, tid, lane, ut, 1, 256, W + D1HI, W + D1LO, 608, 96,
                           half, acc);
      reduce_pair(lds, lane, pair, half, acc);
      if (!half)
        cell_update(lane, ut, 256, 256, d1bp, acc, c, hb(HD1, p, 0, 256), hb(HD1, p, 1, 256),
                    nullptr);
      vm_drain();
      __syncthreads();
      bump(LD1, t);
    }
  } else if (wg < 56) {  // ------------- d2 -------------
    const int ut = (wg - 48) * 2 + pair;
    float c[4][4] = {{0.f}};
    for (int t = 20; t < 400; ++t) {
      const int p = t & 1, q = p ^ 1;
      f32x4 acc[4][4];
      zacc44(acc);
      if (tid == 0 && t >= 21) spin3(CNT(LD2, t - 1), 8, nullptr, 0, nullptr, 0);
      chunk_pass<256, 256>(lds, hb(HD2, q, 0, 256), hb(HD2, q, 1, 256), tid, lane, ut, 1, 256,
                           W + D2HI, W + D2LO, 512, 256, half, acc);
      if (tid == 0) spin3(CNT(LD1, t), 8, nullptr, 0, nullptr, 0);
      chunk_pass<256, 256>(lds, hb(HD1, p, 0, 256), hb(HD1, p, 1, 256), tid, lane, ut, 1, 256,
                           W + D2HI, W + D2LO, 512, 0, half, acc);
      reduce_pair(lds, lane, pair, half, acc);
      if (!half)
        cell_update(lane, ut, 256, 256, d2b, acc, c, hb(HD2, p, 0, 256), hb(HD2, p, 1, 256),
                    nullptr);
      vm_drain();
      __syncthreads();
      bump(LD2, t);
    }
  } else {  // ------------- d3: 3 WGs, ut 0..4 -------------
    const int ut = (wg - 56) * 2 + pair;
    const int utActive = (ut < 5) ? 1 : 0;
    float c[4][4] = {{0.f}};
    for (int t = 20; t < 400; ++t) {
      const int p = t & 1, q = p ^ 1;
      f32x4 acc[4][4];
      zacc44(acc);
      if (tid == 0 && t >= 21) spin3(CNT(LD3, t - 1), 3, nullptr, 0, nullptr, 0);
      chunk_pass<96, 128>(lds, hb(HLAST, q, 0, 96), hb(HLAST, q, 1, 96), tid, lane, ut, utActive,
                          80, W + D3HI, W + D3LO, 352, 256, half, acc);
      if (tid == 0) spin3(CNT(LD2, t), 8, nullptr, 0, nullptr, 0);
      chunk_pass<256, 256>(lds, hb(HD2, p, 0, 256), hb(HD2, p, 1, 256), tid, lane, ut, utActive,
                           80, W + D3HI, W + D3LO, 352, 0, half, acc);
      reduce_pair(lds, lane, pair, half, acc);
      if (!half && utActive)
        cell_update(lane, ut, 80, 96, d3b, acc, c, hb(HLAST, p, 0, 96), hb(HLAST, p, 1, 96),
                    dout + (size_t)(t - 20) * 80);
      vm_drain();
      __syncthreads();
      bump(LD3, t);
    }
  }
}

// ---------------- launch ----------------
extern "C" void kernel_launch(void* const* d_in, const int* in_sizes, int n_in, void* d_out,
                              int out_size, void* d_ws, size_t ws_size, hipStream_t stream) {
  if (ws_size < WS_NEED) return;

  const float* x = (const float*)d_in[0];
  const float* embW = (const float*)d_in[1];
  const float* embB = (const float*)d_in[2];
  const float* e1Wih = (const float*)d_in[3];
  const float* e1Whh = (const float*)d_in[4];
  const float* e1B = (const float*)d_in[5];
  const float* e2Wih = (const float*)d_in[6];
  const float* e2Whh = (const float*)d_in[7];
  const float* e2B = (const float*)d_in[8];
  const float* e3Wih = (const float*)d_in[9];
  const float* e3Whh = (const float*)d_in[10];
  const float* e3B = (const float*)d_in[11];
  const float* d1Wih = (const float*)d_in[12];
  const float* d1Whh = (const float*)d_in[13];
  const float* d1B = (const float*)d_in[14];
  const float* d2Wih = (const float*)d_in[15];
  const float* d2Whh = (const float*)d_in[16];
  const float* d2B = (const float*)d_in[17];
  const float* d3Wih = (const float*)d_in[18];
  const float* d3Whh = (const float*)d_in[19];
  const float* d3B = (const float*)d_in[20];
  const float* keyW = (const float*)d_in[21];
  const float* keyB = (const float*)d_in[22];
  const float* valW = (const float*)d_in[23];
  const float* valB = (const float*)d_in[24];

  unsigned char* ws = (unsigned char*)d_ws;
  unsigned short* W = (unsigned short*)ws;
  float* doutf = (float*)d_out;

  auto launch_w = [&](const float* wih, int din, const float* whh, int dh, int rows, int dinp,
                      int kp, size_t offhi, size_t offlo) {
    size_t tot = (size_t)rows * kp;
    int blocks = (int)((tot + 255) / 256);
    prep_w<<<blocks, 256, 0, stream>>>(wih, din, whh, dh, rows, dinp, kp, W + offhi, W + offlo);
  };
  launch_w(e1Wih, 80, e1Whh, 256, 1024, 96, 352, E1HI, E1LO);
  launch_w(e2Wih, 256, e2Whh, 256, 1024, 256, 512, E2HI, E2LO);
  launch_w(e3Wih, 256, e3Whh, 256, 1024, 256, 512, E3HI, E3LO);
  launch_w(d2Wih, 256, d2Whh, 256, 1024, 256, 512, D2HI, D2LO);
  launch_w(d3Wih, 256, d3Whh, 80, 320, 256, 352, D3HI, D3LO);
  launch_w(keyW, 256, nullptr, 0, 256, 256, 256, KHI, KLO);
  launch_w(valW, 256, nullptr, 0, 256, 256, 256, VHI, VLO);
  // d1 folded weights + bias
  {
    size_t tot = (size_t)1024 * 608;
    prep_d1_w<<<(int)((tot + 255) / 256), 256, 0, stream>>>(d1Wih, d1Whh, embW, W + D1HI,
                                                            W + D1LO);
    prep_d1_bias<<<4, 256, 0, stream>>>(d1Wih, embB, d1B, (float*)(ws + D1BP_B));
  }
  prep_x<<<(int)((XPAD_ELEMS + 255) / 256), 256, 0, stream>>>(
      x, (unsigned short*)(ws + XPAD_HI_B), (unsigned short*)(ws + XPAD_LO_B));
  hipMemsetAsync(ws + STATE_B, 0, STATE_BYTES, stream);

  seq_main<<<dim3(NWG), dim3(WGS), 0, stream>>>(e1B, e2B, e3B, d2B, d3B, keyB, valB, doutf, ws);
}

// Round 10
// 17103.915 us; speedup vs baseline: 1.0701x; 1.0701x over previous
//
#include <hip/hip_runtime.h>

typedef short bf16x8 __attribute__((ext_vector_type(8)));
typedef float f32x4 __attribute__((ext_vector_type(4)));

#define DEV static __device__ __forceinline__
#define SCOPE_AGENT __HIP_MEMORY_SCOPE_AGENT

// ---------------- numeric helpers ----------------
DEV unsigned short f2bf(float f) {
  unsigned u = __float_as_uint(f);
  unsigned r = u + 0x7fffu + ((u >> 16) & 1u);
  return (unsigned short)(r >> 16);
}
DEV float bf2f(unsigned short h) { return __uint_as_float(((unsigned)h) << 16); }
DEV void f2hilo(float f, unsigned short& hi, unsigned short& lo) {
  hi = f2bf(f);
  lo = f2bf(f - bf2f(hi));
}
DEV float sigm(float x) { return 1.f / (1.f + __expf(-x)); }
DEV float tanh_(float x) {
  x = fminf(15.f, fmaxf(-15.f, x));
  float e = __expf(2.f * x);
  return (e - 1.f) / (e + 1.f);
}

// ---------------- coherent (LLC) access helpers ----------------
DEV void st_sc_u16(unsigned short* p, unsigned short v) {
  __hip_atomic_store(p, v, __ATOMIC_RELAXED, SCOPE_AGENT);
}
DEV void st_sc_f32(float* p, float v) {
  __hip_atomic_store(p, v, __ATOMIC_RELAXED, SCOPE_AGENT);
}
DEV void st_sc_u64(unsigned long long* p, unsigned long long v) {
  __hip_atomic_store(p, v, __ATOMIC_RELAXED, SCOPE_AGENT);
}
DEV unsigned long long ld_sc_u64(const unsigned long long* p) {
  return __hip_atomic_load((unsigned long long*)p, __ATOMIC_RELAXED, SCOPE_AGENT);
}
DEV unsigned ld_sc_u32(const unsigned* p) {
  return __hip_atomic_load((unsigned*)p, __ATOMIC_RELAXED, SCOPE_AGENT);
}
DEV void vm_drain() { asm volatile("s_waitcnt vmcnt(0)" ::: "memory"); }

// ---------------- workspace layout ----------------
constexpr size_t WE1 = 1024 * 352, WE2 = 1024 * 512, WE3 = 1024 * 512,
                 WD1 = 1024 * 768, WD2 = 1024 * 512, WD3 = 320 * 352,
                 WKEY = 256 * 256, WVAL = 256 * 256, WEMB = 256 * 96;
constexpr size_t E1HI = 0, E1LO = E1HI + WE1, E2HI = E1LO + WE1, E2LO = E2HI + WE2,
                 E3HI = E2LO + WE2, E3LO = E3HI + WE3, D1HI = E3LO + WE3, D1LO = D1HI + WD1,
                 D2HI = D1LO + WD1, D2LO = D2HI + WD2, D3HI = D2LO + WD2, D3LO = D3HI + WD3,
                 KHI = D3LO + WD3, KLO = KHI + WKEY, VHI = KLO + WKEY, VLO = VHI + WVAL,
                 EMHI = VLO + WVAL, EMLO = EMHI + WEMB, WTOT = EMLO + WEMB;

constexpr size_t XPAD_ELEMS = (size_t)400 * 64 * 96;
constexpr size_t XPAD_HI_B = WTOT * 2;
constexpr size_t XPAD_LO_B = XPAD_HI_B + XPAD_ELEMS * 2;
constexpr size_t STATE_B = XPAD_LO_B + XPAD_ELEMS * 2;

// state (zeroed each launch): h buffers + flag arrays
constexpr size_t H256_SZB = (size_t)2 * 2 * 64 * 256 * 2;  // [parity][hi/lo][64][256] u16
constexpr size_t HE1 = 0, HE2 = H256_SZB, HE3 = 2 * H256_SZB, HD1 = 3 * H256_SZB,
                 HD2 = 4 * H256_SZB;
constexpr size_t HLAST = 5 * H256_SZB;  // [2][2][64][96] u16
constexpr size_t HLAST_SZB = (size_t)2 * 2 * 64 * 96 * 2;
constexpr size_t BARO = HLAST + HLAST_SZB;  // cnt[9][400] u32
constexpr size_t STATE_BYTES = BARO + 9 * 400 * 4 + 64;

// non-zeroed (fully rewritten before first read each launch)
constexpr size_t RINGK_B = STATE_B + STATE_BYTES;
constexpr size_t RING_SZ = (size_t)22 * 64 * 256 * 4;  // per-batch self-ordered (at owns rows)
constexpr size_t RINGV_B = RINGK_B + RING_SZ;
constexpr size_t CTXH_B = RINGV_B + RING_SZ;
constexpr size_t CTXL_B = CTXH_B + (size_t)64 * 256 * 2;
constexpr size_t D1BP_B = CTXL_B + (size_t)64 * 256 * 2;  // folded d1 bias f32[1024]
constexpr size_t WS_NEED = D1BP_B + 4096;

// layer flag ids; cnt[l][t] counts WGs of layer l done with step t
#define LE1 0
#define LE2 1
#define LE3 2
#define LKS 3  // at-stage: he3 staging reads complete (iteration-indexed)
#define LAT 5
#define LD1 6
#define LD2 7
#define LD3 8
// WG map: e1 0-7 | e2 8-15 | e3 16-23 | at 24-39 (kv fused) | d1 40-47 | d2 48-55 | d3 56-58
// targets: e1/e2/e3/d1/d2: 8, at/LKS: 16, d3: 3

constexpr int NWG = 59;
constexpr int WGS = 256;

// ---------------- prep kernels ----------------
__global__ void prep_w(const float* __restrict__ wih, int din, const float* __restrict__ whh,
                       int dh, int rows, int dinp, int kp, unsigned short* __restrict__ whi,
                       unsigned short* __restrict__ wlo) {
  size_t idx = (size_t)blockIdx.x * 256 + threadIdx.x;
  size_t tot = (size_t)rows * kp;
  if (idx >= tot) return;
  int j = (int)(idx / kp), k = (int)(idx % kp);
  float v = 0.f;
  if (k < dinp) {
    if (k < din) v = wih[(size_t)j * din + k];
  } else {
    int k2 = k - dinp;
    if (k2 < dh) v = whh[(size_t)j * dh + k2];
  }
  unsigned short hi, lo;
  f2hilo(v, hi, lo);
  whi[idx] = hi;
  wlo[idx] = lo;
}

// d1 folded weights: [1024][608] = [ W_comb(96: d1Wih[:, :256]@embW, cols>=80 zero) |
//                                    d1Wih[:,256:512] (ctx) | d1Whh (h) ]
__global__ void prep_d1_w(const float* __restrict__ wih, const float* __restrict__ whh,
                          const float* __restrict__ embW, unsigned short* __restrict__ whi,
                          unsigned short* __restrict__ wlo) {
  size_t idx = (size_t)blockIdx.x * 256 + threadIdx.x;
  constexpr size_t tot = (size_t)1024 * 608;
  if (idx >= tot) return;
  int j = (int)(idx / 608), f = (int)(idx % 608);
  float v = 0.f;
  if (f < 96) {
    if (f < 80) {
      const float* wr = wih + (size_t)j * 512;
#pragma unroll 4
      for (int m = 0; m < 256; m++) v += wr[m] * embW[(size_t)m * 80 + f];
    }
  } else if (f < 352) {
    v = wih[(size_t)j * 512 + 256 + (f - 96)];
  } else {
    v = whh[(size_t)j * 256 + (f - 352)];
  }
  unsigned short hi, lo;
  f2hilo(v, hi, lo);
  whi[idx] = hi;
  wlo[idx] = lo;
}

__global__ void prep_d1_bias(const float* __restrict__ wih, const float* __restrict__ embb,
                             const float* __restrict__ d1b, float* __restrict__ out) {
  int j = blockIdx.x * 256 + threadIdx.x;
  if (j >= 1024) return;
  float v = d1b[j];
  const float* wr = wih + (size_t)j * 512;
#pragma unroll 4
  for (int m = 0; m < 256; m++) v += wr[m] * embb[m];
  out[j] = v;
}

__global__ void prep_x(const float* __restrict__ x, unsigned short* __restrict__ xh,
                       unsigned short* __restrict__ xl) {
  size_t idx = (size_t)blockIdx.x * 256 + threadIdx.x;
  if (idx >= XPAD_ELEMS) return;
  int t = (int)(idx / 6144), rbf = (int)(idx % 6144), b = rbf / 96, f = rbf % 96;
  float v = (f < 80) ? x[(size_t)b * 32000 + (size_t)t * 80 + f] : 0.f;
  unsigned short hi, lo;
  f2hilo(v, hi, lo);
  xh[idx] = hi;
  xl[idx] = lo;
}

// ---------------- main kernel pieces ----------------
// LDS staging with 16B XOR swizzle: u16 col c -> c ^ ((row&7)<<3)

template <int COLS, int STRIDE>
DEV void copy_hl(unsigned short* lds, const unsigned short* hi, const unsigned short* lo,
                 int tid) {
  constexpr int CU64 = COLS / 4;
  constexpr int PER = 64 * CU64;
  constexpr int TOT = PER * 2;
  constexpr int loOff = 64 * STRIDE;
  // 32-deep: a full 64KB chunk (TOT=8192) issues in ONE batch -> one LLC RTT
  for (int base = 0; base < TOT; base += WGS * 32) {
    unsigned long long v[32];
    int dst[32];
#pragma unroll
    for (int u = 0; u < 32; u++) {
      int i = base + u * WGS + tid;
      dst[u] = -1;
      if (i < TOT) {
        int pl = (i >= PER) ? 1 : 0;
        int j = pl ? (i - PER) : i;
        int row = j / CU64, cc = j - row * CU64;
        const unsigned long long* s = (const unsigned long long*)(pl ? lo : hi);
        v[u] = ld_sc_u64(s + j);
        dst[u] = (pl ? loOff : 0) + row * STRIDE + ((cc * 4) ^ ((row & 7) << 3));
      }
    }
#pragma unroll
    for (int u = 0; u < 32; u++)
      if (dst[u] >= 0) *(unsigned long long*)(lds + dst[u]) = v[u];
  }
}

DEV void mfma3(f32x4& acc, bf16x8 ah, bf16x8 al, bf16x8 bh, bf16x8 bl) {
  acc = __builtin_amdgcn_mfma_f32_16x16x32_bf16(ah, bh, acc, 0, 0, 0);
  acc = __builtin_amdgcn_mfma_f32_16x16x32_bf16(al, bh, acc, 0, 0, 0);
  acc = __builtin_amdgcn_mfma_f32_16x16x32_bf16(ah, bl, acc, 0, 0, 0);
}

DEV void zacc44(f32x4 (&a)[4][4]) {
#pragma unroll
  for (int g = 0; g < 4; g++)
#pragma unroll
    for (int m = 0; m < 4; m++) a[g][m] = f32x4{0.f, 0.f, 0.f, 0.f};
}

// MFMA over kb index range [kbLo,kbHi) of the staged chunk (K-split support)
template <int STRIDE>
DEV void mfma_range(const unsigned short* lds, int lane, int ut, int H,
                    const unsigned short* __restrict__ Whi,
                    const unsigned short* __restrict__ Wlo, int Kp, int kwOff, int kbLo,
                    int kbHi, f32x4 (&acc)[4][4]) {
  const int col = lane & 15, kg = lane >> 4;
  constexpr int loOff = 64 * STRIDE;
  for (int kb = kbLo; kb < kbHi; kb++) {
    const int ka = kb * 32 + kg * 8;
    bf16x8 ah[4], al[4];
#pragma unroll
    for (int m = 0; m < 4; m++) {
      int row = m * 16 + col;
      int off = row * STRIDE + (ka ^ ((row & 7) << 3));
      ah[m] = *(const bf16x8*)(lds + off);
      al[m] = *(const bf16x8*)(lds + loOff + off);
    }
#pragma unroll
    for (int g = 0; g < 4; g++) {
      size_t wr = (size_t)(g * H + ut * 16 + col) * Kp + kwOff + ka;
      bf16x8 bh = *(const bf16x8*)(Whi + wr);
      bf16x8 bl = *(const bf16x8*)(Wlo + wr);
#pragma unroll
      for (int m = 0; m < 4; m++) mfma3(acc[g][m], ah[m], al[m], bh, bl);
    }
  }
}

// one staged chunk: barrier, copy, barrier, half-K MFMA
template <int COLS, int STRIDE>
DEV void chunk_pass(unsigned short* lds, const unsigned short* hi, const unsigned short* lo,
                    int tid, int lane, int ut, int utActive, int H,
                    const unsigned short* __restrict__ Whi,
                    const unsigned short* __restrict__ Wlo, int Kp, int kwOff, int half,
                    f32x4 (&acc)[4][4]) {
  __syncthreads();  // releases spin + previous LDS consumers done
  copy_hl<COLS, STRIDE>(lds, hi, lo, tid);
  __syncthreads();
  constexpr int NKB = COLS / 32;
  const int lo_kb = half ? (NKB + 1) / 2 : 0;
  const int hi_kb = half ? NKB : (NKB + 1) / 2;
  if (utActive) mfma_range<STRIDE>(lds, lane, ut, H, Whi, Wlo, Kp, kwOff, lo_kb, hi_kb, acc);
}

// combine the two K-halves: half1 writes partials to LDS, half0 adds
DEV void reduce_pair(unsigned short* lds, int lane, int pair, int half, f32x4 (&acc)[4][4]) {
  float* red = (float*)lds;
  const int base = (pair * 64 + lane) * 68;  // stride 68 f32 -> banks spread
  __syncthreads();
  if (half) {
#pragma unroll
    for (int g = 0; g < 4; g++)
#pragma unroll
      for (int m = 0; m < 4; m++)
#pragma unroll
        for (int r = 0; r < 4; r++) red[base + (g * 4 + m) * 4 + r] = acc[g][m][r];
  }
  __syncthreads();
  if (!half) {
#pragma unroll
    for (int g = 0; g < 4; g++)
#pragma unroll
      for (int m = 0; m < 4; m++)
#pragma unroll
        for (int r = 0; r < 4; r++) acc[g][m][r] += red[base + (g * 4 + m) * 4 + r];
  }
}

DEV void cell_update(int lane, int ut, int H, int Hpad, const float* __restrict__ bias,
                     f32x4 (&acc)[4][4], float (&c)[4][4], unsigned short* hwhi,
                     unsigned short* hwlo, float* outp) {
  const int col = lane & 15, kg = lane >> 4;
  const int u = ut * 16 + col;
  const float bi = bias[u], bff = bias[H + u], bg = bias[2 * H + u], bo = bias[3 * H + u];
#pragma unroll
  for (int m = 0; m < 4; m++)
#pragma unroll
    for (int r = 0; r < 4; r++) {
      int b = m * 16 + kg * 4 + r;
      float gi = acc[0][m][r] + bi, gf = acc[1][m][r] + bff;
      float gg = acc[2][m][r] + bg, go = acc[3][m][r] + bo;
      float cn = sigm(gf) * c[m][r] + sigm(gi) * tanh_(gg);
      float hh = sigm(go) * tanh_(cn);
      c[m][r] = cn;
      unsigned short hi, lo;
      f2hilo(hh, hi, lo);
      st_sc_u16(hwhi + b * Hpad + u, hi);
      st_sc_u16(hwlo + b * Hpad + u, lo);
      if (outp) outp[(size_t)b * 30400 + u] = hh;
    }
}

// up to 3 flag waits; null ptr = skip
DEV void spin3(const unsigned* p0, unsigned t0, const unsigned* p1, unsigned t1,
               const unsigned* p2, unsigned t2) {
  for (;;) {
    unsigned a = p0 ? ld_sc_u32(p0) : 0xFFFFFFFFu;
    unsigned b = p1 ? ld_sc_u32(p1) : 0xFFFFFFFFu;
    unsigned c = p2 ? ld_sc_u32(p2) : 0xFFFFFFFFu;
    if (a >= t0 && b >= t1 && c >= t2) return;
    __builtin_amdgcn_s_sleep(1);
  }
}

// WAR/RAW audit (kv fused, SPLIT spins; at(t): s = t<=20 ? t : t-1; t=21 skips kv):
//  e1(t): [LE1 t-1] own HE1[q]; [LD3 t-1 RAW hlast, LE2 t-2 WAR HE1[p]].
//  e2(t): [LE2 t-1] own; [LE1 t RAW, LE3 t-2 WAR HE2[p]].
//  e3(t): [LE3 t-1] own; [LE2 t RAW]; PRE-WRITE [LKS t-1 >=16]: he3[p]-instance(t-2)'s
//    last reader is the at staging in iteration t-1 (s=t-2) or t-2 (s<=20); LKS(t-1)
//    implies both (per-WG monotone). at iter t-1 staging <= LE3(t-2) only -> ~2 steps
//    of slack, never blocks on decoder.
//  at(t) phase A: [LE3 s >=8] stage he3 -> bump LKS(t) -> kv MFMA (ring+kvx).
//  at(t) phase B (t>=21): [LD2 t-1 RAW q, LD1 t-1 WAR ctx] attention -> ctx -> LAT(t).
//    ring rows owned per-WG -> self-ordered; kvx persists t=20->21 (no stage at 21).
//  d1(t): [LD1 t-1] own (+ d2(t-2) WAR via LAT t <= LD2 t-1); [LD3 t-1] hlast; [LAT t] ctx.
//  d2(t): [LD2 t-1] own; [LD1 t RAW; covers WAR HD2[p]: at(t-1) q-read via LD1 t <= LAT t
//    <= at(t) <= at(t-1) done (per-WG sequential); d3(t-2) via d1(t) <= LD3(t-1)].
//  d3(t): [LD3 t-1] own HLAST[q]; [LD2 t RAW; WAR HLAST[p] covered via LD2 t chains].
__global__ void __launch_bounds__(WGS, 1)
seq_main(const float* e1b, const float* e2b, const float* e3b, const float* d2b,
         const float* d3b, const float* keyb, const float* valb, float* dout,
         unsigned char* ws) {
  __shared__ unsigned short lds_s[32768];  // 64 KB
  unsigned short* lds = lds_s;

  const int wg = blockIdx.x, tid = threadIdx.x;
  const int wv = tid >> 6, lane = tid & 63;
  const int pair = wv >> 1, half = wv & 1;

  unsigned short* W = (unsigned short*)ws;
  const unsigned short* xh = (const unsigned short*)(ws + XPAD_HI_B);
  const unsigned short* xl = (const unsigned short*)(ws + XPAD_LO_B);
  unsigned char* st = ws + STATE_B;
  float* ringk = (float*)(ws + RINGK_B);
  float* ringv = (float*)(ws + RINGV_B);
  unsigned short* ctxh = (unsigned short*)(ws + CTXH_B);
  unsigned short* ctxl = (unsigned short*)(ws + CTXL_B);
  const float* d1bp = (const float*)(ws + D1BP_B);
  unsigned* C = (unsigned*)(st + BARO);
  auto CNT = [&](int l, int tt) { return C + l * 400 + tt; };

  auto hb = [&](size_t off, int par, int hl, int Hpad) {
    return (unsigned short*)(st + off) + (size_t)(par * 2 + hl) * 64 * Hpad;
  };
  auto bump = [&](int l, int tt) {
    if (tid == 0) __hip_atomic_fetch_add(CNT(l, tt), 1u, __ATOMIC_RELAXED, SCOPE_AGENT);
  };

  if (wg < 8) {  // ------------- e1 -------------
    const int ut = wg * 2 + pair;
    float c[4][4] = {{0.f}};
    for (int t = 0; t < 400; ++t) {
      const int p = t & 1, q = p ^ 1;
      f32x4 acc[4][4];
      zacc44(acc);
      if (tid == 0 && t >= 1) spin3(CNT(LE1, t - 1), 8, nullptr, 0, nullptr, 0);
      chunk_pass<256, 256>(lds, hb(HE1, q, 0, 256), hb(HE1, q, 1, 256), tid, lane, ut, 1, 256,
                           W + E1HI, W + E1LO, 352, 96, half, acc);
      if (tid == 0)
        spin3(t >= 21 ? CNT(LD3, t - 1) : nullptr, 3, t >= 2 ? CNT(LE2, t - 2) : nullptr, 8,
              nullptr, 0);
      if (t <= 20)
        chunk_pass<96, 128>(lds, xh + (size_t)t * 6144, xl + (size_t)t * 6144, tid, lane, ut, 1,
                            256, W + E1HI, W + E1LO, 352, 0, half, acc);
      else
        chunk_pass<96, 128>(lds, hb(HLAST, q, 0, 96), hb(HLAST, q, 1, 96), tid, lane, ut, 1,
                            256, W + E1HI, W + E1LO, 352, 0, half, acc);
      reduce_pair(lds, lane, pair, half, acc);
      if (!half)
        cell_update(lane, ut, 256, 256, e1b, acc, c, hb(HE1, p, 0, 256), hb(HE1, p, 1, 256),
                    nullptr);
      vm_drain();
      __syncthreads();
      bump(LE1, t);
    }
  } else if (wg < 16) {  // ------------- e2 -------------
    const int ut = (wg - 8) * 2 + pair;
    float c[4][4] = {{0.f}};
    for (int t = 0; t < 400; ++t) {
      const int p = t & 1, q = p ^ 1;
      f32x4 acc[4][4];
      zacc44(acc);
      if (tid == 0 && t >= 1) spin3(CNT(LE2, t - 1), 8, nullptr, 0, nullptr, 0);
      chunk_pass<256, 256>(lds, hb(HE2, q, 0, 256), hb(HE2, q, 1, 256), tid, lane, ut, 1, 256,
                           W + E2HI, W + E2LO, 512, 256, half, acc);
      if (tid == 0)
        spin3(CNT(LE1, t), 8, t >= 2 ? CNT(LE3, t - 2) : nullptr, 8, nullptr, 0);
      chunk_pass<256, 256>(lds, hb(HE1, p, 0, 256), hb(HE1, p, 1, 256), tid, lane, ut, 1, 256,
                           W + E2HI, W + E2LO, 512, 0, half, acc);
      reduce_pair(lds, lane, pair, half, acc);
      if (!half)
        cell_update(lane, ut, 256, 256, e2b, acc, c, hb(HE2, p, 0, 256), hb(HE2, p, 1, 256),
                    nullptr);
      vm_drain();
      __syncthreads();
      bump(LE2, t);
    }
  } else if (wg < 24) {  // ------------- e3 -------------
    const int ut = (wg - 16) * 2 + pair;
    float c[4][4] = {{0.f}};
    for (int t = 0; t < 400; ++t) {
      const int p = t & 1, q = p ^ 1;
      f32x4 acc[4][4];
      zacc44(acc);
      if (tid == 0 && t >= 1) spin3(CNT(LE3, t - 1), 8, nullptr, 0, nullptr, 0);
      chunk_pass<256, 256>(lds, hb(HE3, q, 0, 256), hb(HE3, q, 1, 256), tid, lane, ut, 1, 256,
                           W + E3HI, W + E3LO, 512, 256, half, acc);
      if (tid == 0) spin3(CNT(LE2, t), 8, nullptr, 0, nullptr, 0);
      chunk_pass<256, 256>(lds, hb(HE2, p, 0, 256), hb(HE2, p, 1, 256), tid, lane, ut, 1, 256,
                           W + E3HI, W + E3LO, 512, 0, half, acc);
      reduce_pair(lds, lane, pair, half, acc);
      // pre-write WAR: at staging of he3[p]-instance(t-2) done once LKS(t-1) reached
      if (tid == 0 && t >= 1) spin3(CNT(LKS, t - 1), 16, nullptr, 0, nullptr, 0);
      __syncthreads();
      if (!half)
        cell_update(lane, ut, 256, 256, e3b, acc, c, hb(HE3, p, 0, 256), hb(HE3, p, 1, 256),
                    nullptr);
      vm_drain();
      __syncthreads();
      bump(LE3, t);
    }
  } else if (wg < 40) {  // ------------- at: 16 WGs, kv fused (split spins) -------------
    const int b0 = (wg - 24) * 4;
    float* kvx = (float*)(lds + 8192);  // f32[4][512] exchange (k | v)
    for (int t = 0; t < 400; ++t) {
      const int s = (t <= 20) ? t : t - 1;  // kv step computed this iteration
      const int ps = s & 1;
      const bool doKV = (t != 21);  // t=21's kv(20) already computed at t=20 (kvx persists)
      // ---- phase A: stage he3 + kv MFMA (only needs LE3(s)) ----
      if (doKV) {
        if (tid == 0) spin3(CNT(LE3, s), 8, nullptr, 0, nullptr, 0);
        __syncthreads();
        for (int i = tid; i < 512; i += WGS) {
          int pl = i >> 8, j = i & 255, row = j >> 6, cc = j & 63;
          const unsigned long long* srcp =
              (const unsigned long long*)hb(HE3, ps, pl, 256) + (size_t)(b0 + row) * 64 + cc;
          unsigned long long v = ld_sc_u64(srcp);
          *(unsigned long long*)(lds + pl * 4096 + row * 256 +
                                 ((cc * 4) ^ ((row & 7) << 3))) = v;
        }
        __syncthreads();
      }
      bump(LKS, t);  // he3 reads complete (or skipped)
      if (doKV) {
        const int slot = s % 22;
        const int col = lane & 15, kg = lane >> 4;
        for (int jj = 0; jj < 8; ++jj) {
          int jt = wv * 8 + jj;
          bool isK = jt < 16;
          int j = (isK ? jt : jt - 16) * 16 + col;
          const unsigned short* Whi = W + (isK ? KHI : VHI);
          const unsigned short* Wlo = W + (isK ? KLO : VLO);
          f32x4 acc = f32x4{0.f, 0.f, 0.f, 0.f};
          for (int kb = 0; kb < 8; kb++) {
            int ka = kb * 32 + kg * 8;
            int offA = col * 256 + (ka ^ ((col & 7) << 3));
            bf16x8 ah = *(const bf16x8*)(lds + offA);
            bf16x8 al = *(const bf16x8*)(lds + 4096 + offA);
            size_t wr = (size_t)j * 256 + ka;
            bf16x8 bh = *(const bf16x8*)(Whi + wr);
            bf16x8 bl = *(const bf16x8*)(Wlo + wr);
            mfma3(acc, ah, al, bh, bl);
          }
          if (kg == 0) {
            float bj = (isK ? keyb : valb)[j];
            float* ringp = (isK ? ringk : ringv) + (size_t)slot * 64 * 256;
#pragma unroll
            for (int r = 0; r < 4; r++) {
              float v = acc[r] + bj;
              st_sc_f32(ringp + (size_t)(b0 + r) * 256 + j, v);  // for future steps
              kvx[r * 512 + (isK ? j : 256 + j)] = v;            // for this step
            }
          }
        }
        __syncthreads();
      }
      // ---- phase B: attention (needs d2/d1 of t-1) ----
      if (t == 20) {
        float f[4];
#pragma unroll
        for (int j = 0; j < 4; j++) f[j] = kvx[wv * 512 + 256 + lane * 4 + j];
        unsigned short hi[4], lo[4];
#pragma unroll
        for (int j = 0; j < 4; j++) f2hilo(f[j], hi[j], lo[j]);
        unsigned long long ph = (unsigned long long)hi[0] | ((unsigned long long)hi[1] << 16) |
                                ((unsigned long long)hi[2] << 32) |
                                ((unsigned long long)hi[3] << 48);
        unsigned long long pl = (unsigned long long)lo[0] | ((unsigned long long)lo[1] << 16) |
                                ((unsigned long long)lo[2] << 32) |
                                ((unsigned long long)lo[3] << 48);
        st_sc_u64((unsigned long long*)(ctxh + (b0 + wv) * 256 + lane * 4), ph);
        st_sc_u64((unsigned long long*)(ctxl + (b0 + wv) * 256 + lane * 4), pl);
      } else if (t >= 21) {
        if (tid == 0) spin3(CNT(LD2, t - 1), 8, CNT(LD1, t - 1), 8, nullptr, 0);
        __syncthreads();
        const int b = b0 + wv;
        const int qp = (t & 1) ^ 1;
        const unsigned short* qh = hb(HD2, qp, 0, 256);
        const unsigned short* ql = hb(HD2, qp, 1, 256);
        unsigned long long hq = ld_sc_u64((const unsigned long long*)(qh + b * 256 + lane * 4));
        unsigned long long lq = ld_sc_u64((const unsigned long long*)(ql + b * 256 + lane * 4));
        float qv[4];
#pragma unroll
        for (int j = 0; j < 4; j++)
          qv[j] = bf2f((unsigned short)(hq >> (16 * j))) + bf2f((unsigned short)(lq >> (16 * j)));
        float sArr[20];
#pragma unroll
        for (int i = 0; i < 19; i++) {
          int slot = (t - 20 + i) % 22;
          const unsigned long long* kp =
              (const unsigned long long*)(ringk + ((size_t)slot * 64 + b) * 256 + lane * 4);
          unsigned long long k0 = ld_sc_u64(kp), k1 = ld_sc_u64(kp + 1);
          sArr[i] = __uint_as_float((unsigned)k0) * qv[0] +
                    __uint_as_float((unsigned)(k0 >> 32)) * qv[1] +
                    __uint_as_float((unsigned)k1) * qv[2] +
                    __uint_as_float((unsigned)(k1 >> 32)) * qv[3];
        }
        {  // newest slot (t-1) from LDS exchange
          float acc19 = 0.f;
#pragma unroll
          for (int j = 0; j < 4; j++) acc19 += kvx[wv * 512 + lane * 4 + j] * qv[j];
          sArr[19] = acc19;
        }
#pragma unroll
        for (int off = 32; off >= 1; off >>= 1)
#pragma unroll
          for (int i = 0; i < 20; i++) sArr[i] += __shfl_xor(sArr[i], off, 64);
        float mx = sArr[0];
#pragma unroll
        for (int i = 1; i < 20; i++) mx = fmaxf(mx, sArr[i]);
        float den = 0.f;
#pragma unroll
        for (int i = 0; i < 20; i++) {
          sArr[i] = __expf(sArr[i] - mx);
          den += sArr[i];
        }
        float inv = 1.f / den;
        float a0 = 0.f, a1 = 0.f, a2 = 0.f, a3 = 0.f;
#pragma unroll
        for (int i = 0; i < 19; i++) {
          int slot = (t - 20 + i) % 22;
          const unsigned long long* vp =
              (const unsigned long long*)(ringv + ((size_t)slot * 64 + b) * 256 + lane * 4);
          unsigned long long v0 = ld_sc_u64(vp), v1 = ld_sc_u64(vp + 1);
          a0 += sArr[i] * __uint_as_float((unsigned)v0);
          a1 += sArr[i] * __uint_as_float((unsigned)(v0 >> 32));
          a2 += sArr[i] * __uint_as_float((unsigned)v1);
          a3 += sArr[i] * __uint_as_float((unsigned)(v1 >> 32));
        }
        a0 += sArr[19] * kvx[wv * 512 + 256 + lane * 4 + 0];
        a1 += sArr[19] * kvx[wv * 512 + 256 + lane * 4 + 1];
        a2 += sArr[19] * kvx[wv * 512 + 256 + lane * 4 + 2];
        a3 += sArr[19] * kvx[wv * 512 + 256 + lane * 4 + 3];
        float f[4] = {a0 * inv, a1 * inv, a2 * inv, a3 * inv};
        unsigned short hi[4], lo[4];
#pragma unroll
        for (int j = 0; j < 4; j++) f2hilo(f[j], hi[j], lo[j]);
        unsigned long long ph = (unsigned long long)hi[0] | ((unsigned long long)hi[1] << 16) |
                                ((unsigned long long)hi[2] << 32) |
                                ((unsigned long long)hi[3] << 48);
        unsigned long long pl = (unsigned long long)lo[0] | ((unsigned long long)lo[1] << 16) |
                                ((unsigned long long)lo[2] << 32) |
                                ((unsigned long long)lo[3] << 48);
        st_sc_u64((unsigned long long*)(ctxh + b * 256 + lane * 4), ph);
        st_sc_u64((unsigned long long*)(ctxl + b * 256 + lane * 4), pl);
      }
      vm_drain();
      __syncthreads();
      bump(LAT, t);
    }
  } else if (wg < 48) {  // ------------- d1 (emb folded): Kp=608 -------------
    const int ut = (wg - 40) * 2 + pair;
    float c[4][4] = {{0.f}};
    for (int t = 20; t < 400; ++t) {
      const int p = t & 1, q = p ^ 1;
      f32x4 acc[4][4];
      zacc44(acc);
      if (tid == 0 && t >= 21) spin3(CNT(LD1, t - 1), 8, nullptr, 0, nullptr, 0);
      chunk_pass<256, 256>(lds, hb(HD1, q, 0, 256), hb(HD1, q, 1, 256), tid, lane, ut, 1, 256,
                           W + D1HI, W + D1LO, 608, 352, half, acc);
      if (tid == 0 && t >= 21) spin3(CNT(LD3, t - 1), 3, nullptr, 0, nullptr, 0);
      if (t == 20)
        chunk_pass<96, 128>(lds, xh + (size_t)19 * 6144, xl + (size_t)19 * 6144, tid, lane, ut,
                            1, 256, W + D1HI, W + D1LO, 608, 0, half, acc);
      else
        chunk_pass<96, 128>(lds, hb(HLAST, q, 0, 96), hb(HLAST, q, 1, 96), tid, lane, ut, 1,
                            256, W + D1HI, W + D1LO, 608, 0, half, acc);
      if (tid == 0) spin3(CNT(LAT, t), 16, nullptr, 0, nullptr, 0);
      chunk_pass<256, 256>(lds, ctxh, ctxl, tid, lane, ut, 1, 256, W + D1HI, W + D1LO, 608, 96,
                           half, acc);
      reduce_pair(lds, lane, pair, half, acc);
      if (!half)
        cell_update(lane, ut, 256, 256, d1bp, acc, c, hb(HD1, p, 0, 256), hb(HD1, p, 1, 256),
                    nullptr);
      vm_drain();
      __syncthreads();
      bump(LD1, t);
    }
  } else if (wg < 56) {  // ------------- d2 -------------
    const int ut = (wg - 48) * 2 + pair;
    float c[4][4] = {{0.f}};
    for (int t = 20; t < 400; ++t) {
      const int p = t & 1, q = p ^ 1;
      f32x4 acc[4][4];
      zacc44(acc);
      if (tid == 0 && t >= 21) spin3(CNT(LD2, t - 1), 8, nullptr, 0, nullptr, 0);
      chunk_pass<256, 256>(lds, hb(HD2, q, 0, 256), hb(HD2, q, 1, 256), tid, lane, ut, 1, 256,
                           W + D2HI, W + D2LO, 512, 256, half, acc);
      if (tid == 0) spin3(CNT(LD1, t), 8, nullptr, 0, nullptr, 0);
      chunk_pass<256, 256>(lds, hb(HD1, p, 0, 256), hb(HD1, p, 1, 256), tid, lane, ut, 1, 256,
                           W + D2HI, W + D2LO, 512, 0, half, acc);
      reduce_pair(lds, lane, pair, half, acc);
      if (!half)
        cell_update(lane, ut, 256, 256, d2b, acc, c, hb(HD2, p, 0, 256), hb(HD2, p, 1, 256),
                    nullptr);
      vm_drain();
      __syncthreads();
      bump(LD2, t);
    }
  } else {  // ------------- d3: 3 WGs, ut 0..4 -------------
    const int ut = (wg - 56) * 2 + pair;
    const int utActive = (ut < 5) ? 1 : 0;
    float c[4][4] = {{0.f}};
    for (int t = 20; t < 400; ++t) {
      const int p = t & 1, q = p ^ 1;
      f32x4 acc[4][4];
      zacc44(acc);
      if (tid == 0 && t >= 21) spin3(CNT(LD3, t - 1), 3, nullptr, 0, nullptr, 0);
      chunk_pass<96, 128>(lds, hb(HLAST, q, 0, 96), hb(HLAST, q, 1, 96), tid, lane, ut, utActive,
                          80, W + D3HI, W + D3LO, 352, 256, half, acc);
      if (tid == 0) spin3(CNT(LD2, t), 8, nullptr, 0, nullptr, 0);
      chunk_pass<256, 256>(lds, hb(HD2, p, 0, 256), hb(HD2, p, 1, 256), tid, lane, ut, utActive,
                           80, W + D3HI, W + D3LO, 352, 0, half, acc);
      reduce_pair(lds, lane, pair, half, acc);
      if (!half && utActive)
        cell_update(lane, ut, 80, 96, d3b, acc, c, hb(HLAST, p, 0, 96), hb(HLAST, p, 1, 96),
                    dout + (size_t)(t - 20) * 80);
      vm_drain();
      __syncthreads();
      bump(LD3, t);
    }
  }
}

// ---------------- launch ----------------
extern "C" void kernel_launch(void* const* d_in, const int* in_sizes, int n_in, void* d_out,
                              int out_size, void* d_ws, size_t ws_size, hipStream_t stream) {
  if (ws_size < WS_NEED) return;

  const float* x = (const float*)d_in[0];
  const float* embW = (const float*)d_in[1];
  const float* embB = (const float*)d_in[2];
  const float* e1Wih = (const float*)d_in[3];
  const float* e1Whh = (const float*)d_in[4];
  const float* e1B = (const float*)d_in[5];
  const float* e2Wih = (const float*)d_in[6];
  const float* e2Whh = (const float*)d_in[7];
  const float* e2B = (const float*)d_in[8];
  const float* e3Wih = (const float*)d_in[9];
  const float* e3Whh = (const float*)d_in[10];
  const float* e3B = (const float*)d_in[11];
  const float* d1Wih = (const float*)d_in[12];
  const float* d1Whh = (const float*)d_in[13];
  const float* d1B = (const float*)d_in[14];
  const float* d2Wih = (const float*)d_in[15];
  const float* d2Whh = (const float*)d_in[16];
  const float* d2B = (const float*)d_in[17];
  const float* d3Wih = (const float*)d_in[18];
  const float* d3Whh = (const float*)d_in[19];
  const float* d3B = (const float*)d_in[20];
  const float* keyW = (const float*)d_in[21];
  const float* keyB = (const float*)d_in[22];
  const float* valW = (const float*)d_in[23];
  const float* valB = (const float*)d_in[24];

  unsigned char* ws = (unsigned char*)d_ws;
  unsigned short* W = (unsigned short*)ws;
  float* doutf = (float*)d_out;

  auto launch_w = [&](const float* wih, int din, const float* whh, int dh, int rows, int dinp,
                      int kp, size_t offhi, size_t offlo) {
    size_t tot = (size_t)rows * kp;
    int blocks = (int)((tot + 255) / 256);
    prep_w<<<blocks, 256, 0, stream>>>(wih, din, whh, dh, rows, dinp, kp, W + offhi, W + offlo);
  };
  launch_w(e1Wih, 80, e1Whh, 256, 1024, 96, 352, E1HI, E1LO);
  launch_w(e2Wih, 256, e2Whh, 256, 1024, 256, 512, E2HI, E2LO);
  launch_w(e3Wih, 256, e3Whh, 256, 1024, 256, 512, E3HI, E3LO);
  launch_w(d2Wih, 256, d2Whh, 256, 1024, 256, 512, D2HI, D2LO);
  launch_w(d3Wih, 256, d3Whh, 80, 320, 256, 352, D3HI, D3LO);
  launch_w(keyW, 256, nullptr, 0, 256, 256, 256, KHI, KLO);
  launch_w(valW, 256, nullptr, 0, 256, 256, 256, VHI, VLO);
  // d1 folded weights + bias
  {
    size_t tot = (size_t)1024 * 608;
    prep_d1_w<<<(int)((tot + 255) / 256), 256, 0, stream>>>(d1Wih, d1Whh, embW, W + D1HI,
                                                            W + D1LO);
    prep_d1_bias<<<4, 256, 0, stream>>>(d1Wih, embB, d1B, (float*)(ws + D1BP_B));
  }
  prep_x<<<(int)((XPAD_ELEMS + 255) / 256), 256, 0, stream>>>(
      x, (unsigned short*)(ws + XPAD_HI_B), (unsigned short*)(ws + XPAD_LO_B));
  hipMemsetAsync(ws + STATE_B, 0, STATE_BYTES, stream);

  seq_main<<<dim3(NWG), dim3(WGS), 0, stream>>>(e1B, e2B, e3B, d2B, d3B, keyB, valB, doutf, ws);
}

// Round 11
// 15632.529 us; speedup vs baseline: 1.1708x; 1.0941x over previous
//
#include <hip/hip_runtime.h>

typedef short bf16x8 __attribute__((ext_vector_type(8)));
typedef float f32x4 __attribute__((ext_vector_type(4)));

#define DEV static __device__ __forceinline__
#define SCOPE_AGENT __HIP_MEMORY_SCOPE_AGENT

// ---------------- numeric helpers ----------------
DEV unsigned short f2bf(float f) {
  unsigned u = __float_as_uint(f);
  unsigned r = u + 0x7fffu + ((u >> 16) & 1u);
  return (unsigned short)(r >> 16);
}
DEV float bf2f(unsigned short h) { return __uint_as_float(((unsigned)h) << 16); }
DEV void f2hilo(float f, unsigned short& hi, unsigned short& lo) {
  hi = f2bf(f);
  lo = f2bf(f - bf2f(hi));
}
DEV float sigm(float x) { return 1.f / (1.f + __expf(-x)); }
DEV float tanh_(float x) {
  x = fminf(15.f, fmaxf(-15.f, x));
  float e = __expf(2.f * x);
  return (e - 1.f) / (e + 1.f);
}

// ---------------- coherent (LLC) access helpers ----------------
DEV void st_sc_u16(unsigned short* p, unsigned short v) {
  __hip_atomic_store(p, v, __ATOMIC_RELAXED, SCOPE_AGENT);
}
DEV void st_sc_f32(float* p, float v) {
  __hip_atomic_store(p, v, __ATOMIC_RELAXED, SCOPE_AGENT);
}
DEV void st_sc_u64(unsigned long long* p, unsigned long long v) {
  __hip_atomic_store(p, v, __ATOMIC_RELAXED, SCOPE_AGENT);
}
DEV unsigned long long ld_sc_u64(const unsigned long long* p) {
  return __hip_atomic_load((unsigned long long*)p, __ATOMIC_RELAXED, SCOPE_AGENT);
}
DEV unsigned ld_sc_u32(const unsigned* p) {
  return __hip_atomic_load((unsigned*)p, __ATOMIC_RELAXED, SCOPE_AGENT);
}
DEV void vm_drain() { asm volatile("s_waitcnt vmcnt(0)" ::: "memory"); }

// ---------------- workspace layout ----------------
constexpr size_t WE1 = 1024 * 352, WE2 = 1024 * 512, WE3 = 1024 * 512,
                 WD1 = 1024 * 768, WD2 = 1024 * 512, WD3 = 320 * 352,
                 WKEY = 256 * 256, WVAL = 256 * 256, WEMB = 256 * 96;
constexpr size_t E1HI = 0, E1LO = E1HI + WE1, E2HI = E1LO + WE1, E2LO = E2HI + WE2,
                 E3HI = E2LO + WE2, E3LO = E3HI + WE3, D1HI = E3LO + WE3, D1LO = D1HI + WD1,
                 D2HI = D1LO + WD1, D2LO = D2HI + WD2, D3HI = D2LO + WD2, D3LO = D3HI + WD3,
                 KHI = D3LO + WD3, KLO = KHI + WKEY, VHI = KLO + WKEY, VLO = VHI + WVAL,
                 EMHI = VLO + WVAL, EMLO = EMHI + WEMB, WTOT = EMLO + WEMB;

constexpr size_t XPAD_ELEMS = (size_t)400 * 64 * 96;
constexpr size_t XPAD_HI_B = WTOT * 2;
constexpr size_t XPAD_LO_B = XPAD_HI_B + XPAD_ELEMS * 2;
constexpr size_t STATE_B = XPAD_LO_B + XPAD_ELEMS * 2;

// state (zeroed each launch): h buffers + flag arrays
constexpr size_t H256_SZB = (size_t)2 * 2 * 64 * 256 * 2;  // [parity][hi/lo][64][256] u16
constexpr size_t HE1 = 0, HE2 = H256_SZB, HE3 = 2 * H256_SZB, HD1 = 3 * H256_SZB,
                 HD2 = 4 * H256_SZB;
constexpr size_t HLAST = 5 * H256_SZB;  // [2][2][64][96] u16
constexpr size_t HLAST_SZB = (size_t)2 * 2 * 64 * 96 * 2;
constexpr size_t BARO = HLAST + HLAST_SZB;  // cnt[9][400] u32
constexpr size_t STATE_BYTES = BARO + 9 * 400 * 4 + 64;

// non-zeroed (fully rewritten before first read each launch)
constexpr size_t RINGK_B = STATE_B + STATE_BYTES;
constexpr size_t RING_SZ = (size_t)22 * 64 * 256 * 4;  // 22 slots: kv(t) only WARs attn(t-2)
constexpr size_t RINGV_B = RINGK_B + RING_SZ;
constexpr size_t CTXH_B = RINGV_B + RING_SZ;                      // [2][64][256] u16 (parity)
constexpr size_t CTXL_B = CTXH_B + (size_t)2 * 64 * 256 * 2;
constexpr size_t D1BP_B = CTXL_B + (size_t)2 * 64 * 256 * 2;      // folded d1 bias f32[1024]
constexpr size_t WS_NEED = D1BP_B + 4096;

// layer flag ids; cnt[l][t] counts WGs of layer l done with step t
#define LE1 0
#define LE2 1
#define LE3 2
#define LKV 3
#define LAT 5
#define LD1 6
#define LD2 7
#define LD3 8
// WG map: e1 0-7 | e2 8-15 | e3 16-23 | kv 24-31 | at 32-47 | d1 48-55 | d2 56-63 | d3 64-66
// targets: e1/e2/e3/kv/d1/d2: 8, at: 16, d3: 3

constexpr int NWG = 67;
constexpr int WGS = 256;
constexpr int HSTG = 20480;  // u16 index of h-store bounce tile [2][64][32]

// ---------------- prep kernels ----------------
__global__ void prep_w(const float* __restrict__ wih, int din, const float* __restrict__ whh,
                       int dh, int rows, int dinp, int kp, unsigned short* __restrict__ whi,
                       unsigned short* __restrict__ wlo) {
  size_t idx = (size_t)blockIdx.x * 256 + threadIdx.x;
  size_t tot = (size_t)rows * kp;
  if (idx >= tot) return;
  int j = (int)(idx / kp), k = (int)(idx % kp);
  float v = 0.f;
  if (k < dinp) {
    if (k < din) v = wih[(size_t)j * din + k];
  } else {
    int k2 = k - dinp;
    if (k2 < dh) v = whh[(size_t)j * dh + k2];
  }
  unsigned short hi, lo;
  f2hilo(v, hi, lo);
  whi[idx] = hi;
  wlo[idx] = lo;
}

// d1 folded weights: [1024][608] = [ W_comb(96: d1Wih[:, :256]@embW, cols>=80 zero) |
//                                    d1Wih[:,256:512] (ctx) | d1Whh (h) ]
__global__ void prep_d1_w(const float* __restrict__ wih, const float* __restrict__ whh,
                          const float* __restrict__ embW, unsigned short* __restrict__ whi,
                          unsigned short* __restrict__ wlo) {
  size_t idx = (size_t)blockIdx.x * 256 + threadIdx.x;
  constexpr size_t tot = (size_t)1024 * 608;
  if (idx >= tot) return;
  int j = (int)(idx / 608), f = (int)(idx % 608);
  float v = 0.f;
  if (f < 96) {
    if (f < 80) {
      const float* wr = wih + (size_t)j * 512;
#pragma unroll 4
      for (int m = 0; m < 256; m++) v += wr[m] * embW[(size_t)m * 80 + f];
    }
  } else if (f < 352) {
    v = wih[(size_t)j * 512 + 256 + (f - 96)];
  } else {
    v = whh[(size_t)j * 256 + (f - 352)];
  }
  unsigned short hi, lo;
  f2hilo(v, hi, lo);
  whi[idx] = hi;
  wlo[idx] = lo;
}

__global__ void prep_d1_bias(const float* __restrict__ wih, const float* __restrict__ embb,
                             const float* __restrict__ d1b, float* __restrict__ out) {
  int j = blockIdx.x * 256 + threadIdx.x;
  if (j >= 1024) return;
  float v = d1b[j];
  const float* wr = wih + (size_t)j * 512;
#pragma unroll 4
  for (int m = 0; m < 256; m++) v += wr[m] * embb[m];
  out[j] = v;
}

__global__ void prep_x(const float* __restrict__ x, unsigned short* __restrict__ xh,
                       unsigned short* __restrict__ xl) {
  size_t idx = (size_t)blockIdx.x * 256 + threadIdx.x;
  if (idx >= XPAD_ELEMS) return;
  int t = (int)(idx / 6144), rbf = (int)(idx % 6144), b = rbf / 96, f = rbf % 96;
  float v = (f < 80) ? x[(size_t)b * 32000 + (size_t)t * 80 + f] : 0.f;
  unsigned short hi, lo;
  f2hilo(v, hi, lo);
  xh[idx] = hi;
  xl[idx] = lo;
}

// ---------------- main kernel pieces ----------------
// LDS staging with 16B XOR swizzle: u16 col c -> c ^ ((row&7)<<3)

template <int COLS, int STRIDE>
DEV void copy_hl(unsigned short* lds, const unsigned short* hi, const unsigned short* lo,
                 int tid) {
  constexpr int CU64 = COLS / 4;
  constexpr int PER = 64 * CU64;
  constexpr int TOT = PER * 2;
  constexpr int loOff = 64 * STRIDE;
  // 32-deep: a full 64KB chunk (TOT=8192) issues in ONE batch -> one LLC RTT
  for (int base = 0; base < TOT; base += WGS * 32) {
    unsigned long long v[32];
    int dst[32];
#pragma unroll
    for (int u = 0; u < 32; u++) {
      int i = base + u * WGS + tid;
      dst[u] = -1;
      if (i < TOT) {
        int pl = (i >= PER) ? 1 : 0;
        int j = pl ? (i - PER) : i;
        int row = j / CU64, cc = j - row * CU64;
        const unsigned long long* s = (const unsigned long long*)(pl ? lo : hi);
        v[u] = ld_sc_u64(s + j);
        dst[u] = (pl ? loOff : 0) + row * STRIDE + ((cc * 4) ^ ((row & 7) << 3));
      }
    }
#pragma unroll
    for (int u = 0; u < 32; u++)
      if (dst[u] >= 0) *(unsigned long long*)(lds + dst[u]) = v[u];
  }
}

DEV void mfma3(f32x4& acc, bf16x8 ah, bf16x8 al, bf16x8 bh, bf16x8 bl) {
  acc = __builtin_amdgcn_mfma_f32_16x16x32_bf16(ah, bh, acc, 0, 0, 0);
  acc = __builtin_amdgcn_mfma_f32_16x16x32_bf16(al, bh, acc, 0, 0, 0);
  acc = __builtin_amdgcn_mfma_f32_16x16x32_bf16(ah, bl, acc, 0, 0, 0);
}

DEV void zacc44(f32x4 (&a)[4][4]) {
#pragma unroll
  for (int g = 0; g < 4; g++)
#pragma unroll
    for (int m = 0; m < 4; m++) a[g][m] = f32x4{0.f, 0.f, 0.f, 0.f};
}

// MFMA over kb index range [kbLo,kbHi) of the staged chunk (K-split support)
template <int STRIDE>
DEV void mfma_range(const unsigned short* lds, int lane, int ut, int H,
                    const unsigned short* __restrict__ Whi,
                    const unsigned short* __restrict__ Wlo, int Kp, int kwOff, int kbLo,
                    int kbHi, f32x4 (&acc)[4][4]) {
  const int col = lane & 15, kg = lane >> 4;
  constexpr int loOff = 64 * STRIDE;
  for (int kb = kbLo; kb < kbHi; kb++) {
    const int ka = kb * 32 + kg * 8;
    bf16x8 ah[4], al[4];
#pragma unroll
    for (int m = 0; m < 4; m++) {
      int row = m * 16 + col;
      int off = row * STRIDE + (ka ^ ((row & 7) << 3));
      ah[m] = *(const bf16x8*)(lds + off);
      al[m] = *(const bf16x8*)(lds + loOff + off);
    }
#pragma unroll
    for (int g = 0; g < 4; g++) {
      size_t wr = (size_t)(g * H + ut * 16 + col) * Kp + kwOff + ka;
      bf16x8 bh = *(const bf16x8*)(Whi + wr);
      bf16x8 bl = *(const bf16x8*)(Wlo + wr);
#pragma unroll
      for (int m = 0; m < 4; m++) mfma3(acc[g][m], ah[m], al[m], bh, bl);
    }
  }
}

// one staged chunk: barrier, copy, barrier, half-K MFMA
template <int COLS, int STRIDE>
DEV void chunk_pass(unsigned short* lds, const unsigned short* hi, const unsigned short* lo,
                    int tid, int lane, int ut, int utActive, int H,
                    const unsigned short* __restrict__ Whi,
                    const unsigned short* __restrict__ Wlo, int Kp, int kwOff, int half,
                    f32x4 (&acc)[4][4]) {
  __syncthreads();  // releases spin + previous LDS consumers done
  copy_hl<COLS, STRIDE>(lds, hi, lo, tid);
  __syncthreads();
  constexpr int NKB = COLS / 32;
  const int lo_kb = half ? (NKB + 1) / 2 : 0;
  const int hi_kb = half ? NKB : (NKB + 1) / 2;
  if (utActive) mfma_range<STRIDE>(lds, lane, ut, H, Whi, Wlo, Kp, kwOff, lo_kb, hi_kb, acc);
}

// combine the two K-halves: half1 writes partials to LDS, half0 adds
DEV void reduce_pair(unsigned short* lds, int lane, int pair, int half, f32x4 (&acc)[4][4]) {
  float* red = (float*)lds;
  const int base = (pair * 64 + lane) * 68;  // stride 68 f32 -> banks spread
  __syncthreads();
  if (half) {
#pragma unroll
    for (int g = 0; g < 4; g++)
#pragma unroll
      for (int m = 0; m < 4; m++)
#pragma unroll
        for (int r = 0; r < 4; r++) red[base + (g * 4 + m) * 4 + r] = acc[g][m][r];
  }
  __syncthreads();
  if (!half) {
#pragma unroll
    for (int g = 0; g < 4; g++)
#pragma unroll
      for (int m = 0; m < 4; m++)
#pragma unroll
        for (int r = 0; r < 4; r++) acc[g][m][r] += red[base + (g * 4 + m) * 4 + r];
  }
}

// cell update -> LDS bounce tile hstage[2][64][32] (hi|lo); half0 waves only
DEV void cell_update_lds(unsigned short* hstage, int lane, int pairIdx, int ut, int H,
                         const float* __restrict__ bias, f32x4 (&acc)[4][4], float (&c)[4][4],
                         float* outp) {
  const int col = lane & 15, kg = lane >> 4;
  const int u = ut * 16 + col;
  const int uloc = pairIdx * 16 + col;
  const float bi = bias[u], bff = bias[H + u], bg = bias[2 * H + u], bo = bias[3 * H + u];
#pragma unroll
  for (int m = 0; m < 4; m++)
#pragma unroll
    for (int r = 0; r < 4; r++) {
      int b = m * 16 + kg * 4 + r;
      float gi = acc[0][m][r] + bi, gf = acc[1][m][r] + bff;
      float gg = acc[2][m][r] + bg, go = acc[3][m][r] + bo;
      float cn = sigm(gf) * c[m][r] + sigm(gi) * tanh_(gg);
      float hh = sigm(go) * tanh_(cn);
      c[m][r] = cn;
      unsigned short hi, lo;
      f2hilo(hh, hi, lo);
      hstage[b * 32 + uloc] = hi;
      hstage[2048 + b * 32 + uloc] = lo;
      if (outp) outp[(size_t)b * 30400 + u] = hh;
    }
}

// coalesced u64 sc1 store of the WG's h slice (ncols = 32 or 16)
DEV void store_h(const unsigned short* hstage, int tid, unsigned short* hwhi,
                 unsigned short* hwlo, int u0, int Hpad, int ncols) {
  const int rowu64 = ncols >> 2;
  const int per = 64 * rowu64;
  for (int i = tid; i < per * 2; i += WGS) {
    int pl = (i >= per) ? 1 : 0;
    int j = pl ? i - per : i;
    int b = j / rowu64, cc = j - b * rowu64;
    unsigned long long v = *(const unsigned long long*)(hstage + pl * 2048 + b * 32 + cc * 4);
    st_sc_u64((unsigned long long*)((pl ? hwlo : hwhi) + (size_t)b * Hpad + u0) + cc, v);
  }
}

// linear (key/val): full-K per wave
template <int K, int STRIDE>
DEV void mfma_lin(const unsigned short* lds, int lane, int jt,
                  const unsigned short* __restrict__ Whi,
                  const unsigned short* __restrict__ Wlo, int Kp, f32x4 (&acc)[4]) {
  const int col = lane & 15, kg = lane >> 4;
  constexpr int loOff = 64 * STRIDE;
#pragma unroll
  for (int kb = 0; kb < K; kb += 32) {
    const int ka = kb + kg * 8;
    size_t wr = (size_t)(jt * 16 + col) * Kp + ka;
    bf16x8 bh = *(const bf16x8*)(Whi + wr);
    bf16x8 bl = *(const bf16x8*)(Wlo + wr);
#pragma unroll
    for (int m = 0; m < 4; m++) {
      int row = m * 16 + col;
      int off = row * STRIDE + (ka ^ ((row & 7) << 3));
      bf16x8 ah = *(const bf16x8*)(lds + off);
      bf16x8 al = *(const bf16x8*)(lds + loOff + off);
      mfma3(acc[m], ah, al, bh, bl);
    }
  }
}

// up to 3 flag waits; null ptr = skip
DEV void spin3(const unsigned* p0, unsigned t0, const unsigned* p1, unsigned t1,
               const unsigned* p2, unsigned t2) {
  for (;;) {
    unsigned a = p0 ? ld_sc_u32(p0) : 0xFFFFFFFFu;
    unsigned b = p1 ? ld_sc_u32(p1) : 0xFFFFFFFFu;
    unsigned c = p2 ? ld_sc_u32(p2) : 0xFFFFFFFFu;
    if (a >= t0 && b >= t1 && c >= t2) return;
    __builtin_amdgcn_s_sleep(1);
  }
}

// WAR/RAW audit (R8 topology + ctx parity; own/old chunk first, fresh dep last):
//  e1(t): [LE1 t-1] own HE1[q]; [LD3 t-1 RAW hlast, LE2 t-2 WAR HE1[p]].
//  e2(t): [LE2 t-1] own; [LE1 t RAW, LE3 t-2 WAR HE2[p]].
//  e3(t): [LE3 t-1] own; [LE2 t RAW, LKV t-2 WAR HE3[p] (kv(t-2) reads parity p)].
//  kv(t): [LE3 t RAW, LAT t-2 WAR ring slot t%22 (attn(t-2) last reader)].
//  at(t): [LKV t-1 RAW ring, LD2 t-1 RAW q]. ctx[t&1] write WAR vs d1(t-2)'s read of
//    ctx[t&1]-instance(t-2): at(t) >= LD2(t-1) >= d2(t-1) >= LD1(t-1) >= d1(t-1) >=
//    LD1(t-2) = d1(t-2) complete. LD1 spin REMOVED (parity makes it redundant).
//  d1(t): [LD1 t-1] own (+ d2(t-2) WAR HD1[p] via LAT t <= LD2 t-1 chain);
//    [LD3 t-1] hlast; [LAT t] ctx[t&1].
//  d2(t): [LD2 t-1] own; [LD1 t RAW; WAR HD2[p]: at(t-1) via LD1 t <= LAT t <= at(t) >=
//    at(t-1) per-WG sequential; d3(t-2) via LD1 t <= d1(t) <= LD3(t-1) >= d3(t-1) >= d3(t-2)].
//  d3(t): [LD3 t-1] own HLAST[q]; [LD2 t RAW; WAR HLAST[p]: e1(t-1)/d1(t-1) via LD2 t <=
//    LD1 t <= LAT t <= LKV t-1 <= LE3 t-1 <= ... <= LE1 t-1, and LD1 t => d1(t-1)].
__global__ void __launch_bounds__(WGS, 1)
seq_main(const float* e1b, const float* e2b, const float* e3b, const float* d2b,
         const float* d3b, const float* keyb, const float* valb, float* dout,
         unsigned char* ws) {
  __shared__ unsigned short lds_s[32768];  // 64 KB
  unsigned short* lds = lds_s;

  const int wg = blockIdx.x, tid = threadIdx.x;
  const int wv = tid >> 6, lane = tid & 63;
  const int pair = wv >> 1, half = wv & 1;

  unsigned short* W = (unsigned short*)ws;
  const unsigned short* xh = (const unsigned short*)(ws + XPAD_HI_B);
  const unsigned short* xl = (const unsigned short*)(ws + XPAD_LO_B);
  unsigned char* st = ws + STATE_B;
  float* ringk = (float*)(ws + RINGK_B);
  float* ringv = (float*)(ws + RINGV_B);
  unsigned short* ctxh = (unsigned short*)(ws + CTXH_B);
  unsigned short* ctxl = (unsigned short*)(ws + CTXL_B);
  const float* d1bp = (const float*)(ws + D1BP_B);
  unsigned* C = (unsigned*)(st + BARO);
  auto CNT = [&](int l, int tt) { return C + l * 400 + tt; };

  auto hb = [&](size_t off, int par, int hl, int Hpad) {
    return (unsigned short*)(st + off) + (size_t)(par * 2 + hl) * 64 * Hpad;
  };
  auto bump = [&](int l, int tt) {
    if (tid == 0) __hip_atomic_fetch_add(CNT(l, tt), 1u, __ATOMIC_RELAXED, SCOPE_AGENT);
  };

  if (wg < 8) {  // ------------- e1 -------------
    const int ut = wg * 2 + pair;
    const int u0 = wg * 32;
    float c[4][4] = {{0.f}};
    for (int t = 0; t < 400; ++t) {
      const int p = t & 1, q = p ^ 1;
      f32x4 acc[4][4];
      zacc44(acc);
      if (tid == 0 && t >= 1) spin3(CNT(LE1, t - 1), 8, nullptr, 0, nullptr, 0);
      chunk_pass<256, 256>(lds, hb(HE1, q, 0, 256), hb(HE1, q, 1, 256), tid, lane, ut, 1, 256,
                           W + E1HI, W + E1LO, 352, 96, half, acc);
      if (tid == 0)
        spin3(t >= 21 ? CNT(LD3, t - 1) : nullptr, 3, t >= 2 ? CNT(LE2, t - 2) : nullptr, 8,
              nullptr, 0);
      if (t <= 20)
        chunk_pass<96, 128>(lds, xh + (size_t)t * 6144, xl + (size_t)t * 6144, tid, lane, ut, 1,
                            256, W + E1HI, W + E1LO, 352, 0, half, acc);
      else
        chunk_pass<96, 128>(lds, hb(HLAST, q, 0, 96), hb(HLAST, q, 1, 96), tid, lane, ut, 1,
                            256, W + E1HI, W + E1LO, 352, 0, half, acc);
      reduce_pair(lds, lane, pair, half, acc);
      if (!half) cell_update_lds(lds + HSTG, lane, pair, ut, 256, e1b, acc, c, nullptr);
      __syncthreads();
      store_h(lds + HSTG, tid, hb(HE1, p, 0, 256), hb(HE1, p, 1, 256), u0, 256, 32);
      vm_drain();
      __syncthreads();
      bump(LE1, t);
    }
  } else if (wg < 16) {  // ------------- e2 -------------
    const int ut = (wg - 8) * 2 + pair;
    const int u0 = (wg - 8) * 32;
    float c[4][4] = {{0.f}};
    for (int t = 0; t < 400; ++t) {
      const int p = t & 1, q = p ^ 1;
      f32x4 acc[4][4];
      zacc44(acc);
      if (tid == 0 && t >= 1) spin3(CNT(LE2, t - 1), 8, nullptr, 0, nullptr, 0);
      chunk_pass<256, 256>(lds, hb(HE2, q, 0, 256), hb(HE2, q, 1, 256), tid, lane, ut, 1, 256,
                           W + E2HI, W + E2LO, 512, 256, half, acc);
      if (tid == 0)
        spin3(CNT(LE1, t), 8, t >= 2 ? CNT(LE3, t - 2) : nullptr, 8, nullptr, 0);
      chunk_pass<256, 256>(lds, hb(HE1, p, 0, 256), hb(HE1, p, 1, 256), tid, lane, ut, 1, 256,
                           W + E2HI, W + E2LO, 512, 0, half, acc);
      reduce_pair(lds, lane, pair, half, acc);
      if (!half) cell_update_lds(lds + HSTG, lane, pair, ut, 256, e2b, acc, c, nullptr);
      __syncthreads();
      store_h(lds + HSTG, tid, hb(HE2, p, 0, 256), hb(HE2, p, 1, 256), u0, 256, 32);
      vm_drain();
      __syncthreads();
      bump(LE2, t);
    }
  } else if (wg < 24) {  // ------------- e3 -------------
    const int ut = (wg - 16) * 2 + pair;
    const int u0 = (wg - 16) * 32;
    float c[4][4] = {{0.f}};
    for (int t = 0; t < 400; ++t) {
      const int p = t & 1, q = p ^ 1;
      f32x4 acc[4][4];
      zacc44(acc);
      if (tid == 0 && t >= 1) spin3(CNT(LE3, t - 1), 8, nullptr, 0, nullptr, 0);
      chunk_pass<256, 256>(lds, hb(HE3, q, 0, 256), hb(HE3, q, 1, 256), tid, lane, ut, 1, 256,
                           W + E3HI, W + E3LO, 512, 256, half, acc);
      if (tid == 0)
        spin3(CNT(LE2, t), 8, t >= 2 ? CNT(LKV, t - 2) : nullptr, 8, nullptr, 0);
      chunk_pass<256, 256>(lds, hb(HE2, p, 0, 256), hb(HE2, p, 1, 256), tid, lane, ut, 1, 256,
                           W + E3HI, W + E3LO, 512, 0, half, acc);
      reduce_pair(lds, lane, pair, half, acc);
      if (!half) cell_update_lds(lds + HSTG, lane, pair, ut, 256, e3b, acc, c, nullptr);
      __syncthreads();
      store_h(lds + HSTG, tid, hb(HE3, p, 0, 256), hb(HE3, p, 1, 256), u0, 256, 32);
      vm_drain();
      __syncthreads();
      bump(LE3, t);
    }
  } else if (wg < 32) {  // ------------- kv: 8 WGs (24-27 key, 28-31 val) -------------
    const bool isKey = wg < 28;
    const unsigned short* Whi = W + (isKey ? KHI : VHI);
    const unsigned short* Wlo = W + (isKey ? KLO : VLO);
    const float* bias = isKey ? keyb : valb;
    float* ring = isKey ? ringk : ringv;
    const int jt = (wg - (isKey ? 24 : 28)) * 4 + wv;
    const int col = lane & 15, kg = lane >> 4;
    for (int t = 0; t < 400; ++t) {
      const int p = t & 1;
      const int slot = t % 22;
      if (tid == 0)
        spin3(CNT(LE3, t), 8, t >= 22 ? CNT(LAT, t - 2) : nullptr, 16, nullptr, 0);
      __syncthreads();
      copy_hl<256, 256>(lds, hb(HE3, p, 0, 256), hb(HE3, p, 1, 256), tid);
      __syncthreads();
      float* outp = ring + (size_t)slot * 64 * 256;
      f32x4 acc[4];
#pragma unroll
      for (int m = 0; m < 4; m++) acc[m] = f32x4{0.f, 0.f, 0.f, 0.f};
      mfma_lin<256, 256>(lds, lane, jt, Whi, Wlo, 256, acc);
      int j = jt * 16 + col;
      float bj = bias[j];
#pragma unroll
      for (int m = 0; m < 4; m++)
#pragma unroll
        for (int r = 0; r < 4; r++) {
          int b = m * 16 + kg * 4 + r;
          st_sc_f32(outp + (size_t)b * 256 + j, acc[m][r] + bj);
        }
      vm_drain();
      __syncthreads();
      bump(LKV, t);
    }
  } else if (wg < 48) {  // ------------- attn: 16 WGs, 1 row/wave -------------
    const int b = (wg - 32) * 4 + wv;
    for (int t = 20; t < 400; ++t) {
      unsigned short* ch = ctxh + (size_t)(t & 1) * 64 * 256;
      unsigned short* cl = ctxl + (size_t)(t & 1) * 64 * 256;
      if (t == 20) {
        if (tid == 0) spin3(CNT(LKV, 20), 8, nullptr, 0, nullptr, 0);
        __syncthreads();
        // ctx := v20 (ring slot 20)
        const unsigned long long* vp =
            (const unsigned long long*)(ringv + ((size_t)20 * 64 + b) * 256 + lane * 4);
        unsigned long long v0 = ld_sc_u64(vp), v1 = ld_sc_u64(vp + 1);
        float f[4] = {__uint_as_float((unsigned)v0), __uint_as_float((unsigned)(v0 >> 32)),
                      __uint_as_float((unsigned)v1), __uint_as_float((unsigned)(v1 >> 32))};
        unsigned short hi[4], lo[4];
#pragma unroll
        for (int j = 0; j < 4; j++) f2hilo(f[j], hi[j], lo[j]);
        unsigned long long ph = (unsigned long long)hi[0] | ((unsigned long long)hi[1] << 16) |
                                ((unsigned long long)hi[2] << 32) |
                                ((unsigned long long)hi[3] << 48);
        unsigned long long pl = (unsigned long long)lo[0] | ((unsigned long long)lo[1] << 16) |
                                ((unsigned long long)lo[2] << 32) |
                                ((unsigned long long)lo[3] << 48);
        st_sc_u64((unsigned long long*)(ch + b * 256 + lane * 4), ph);
        st_sc_u64((unsigned long long*)(cl + b * 256 + lane * 4), pl);
      } else {
        if (tid == 0) spin3(CNT(LKV, t - 1), 8, CNT(LD2, t - 1), 8, nullptr, 0);
        __syncthreads();
        const int qp = (t & 1) ^ 1;
        const unsigned short* qh = hb(HD2, qp, 0, 256);
        const unsigned short* ql = hb(HD2, qp, 1, 256);
        unsigned long long hq = ld_sc_u64((const unsigned long long*)(qh + b * 256 + lane * 4));
        unsigned long long lq = ld_sc_u64((const unsigned long long*)(ql + b * 256 + lane * 4));
        float qv[4];
#pragma unroll
        for (int j = 0; j < 4; j++)
          qv[j] = bf2f((unsigned short)(hq >> (16 * j))) + bf2f((unsigned short)(lq >> (16 * j)));
        float sArr[20];
#pragma unroll
        for (int i = 0; i < 20; i++) {
          int slot = (t - 20 + i) % 22;
          const unsigned long long* kp =
              (const unsigned long long*)(ringk + ((size_t)slot * 64 + b) * 256 + lane * 4);
          unsigned long long k0 = ld_sc_u64(kp), k1 = ld_sc_u64(kp + 1);
          sArr[i] = __uint_as_float((unsigned)k0) * qv[0] +
                    __uint_as_float((unsigned)(k0 >> 32)) * qv[1] +
                    __uint_as_float((unsigned)k1) * qv[2] +
                    __uint_as_float((unsigned)(k1 >> 32)) * qv[3];
        }
#pragma unroll
        for (int off = 32; off >= 1; off >>= 1)
#pragma unroll
          for (int i = 0; i < 20; i++) sArr[i] += __shfl_xor(sArr[i], off, 64);
        float mx = sArr[0];
#pragma unroll
        for (int i = 1; i < 20; i++) mx = fmaxf(mx, sArr[i]);
        float den = 0.f;
#pragma unroll
        for (int i = 0; i < 20; i++) {
          sArr[i] = __expf(sArr[i] - mx);
          den += sArr[i];
        }
        float inv = 1.f / den;
        float a0 = 0.f, a1 = 0.f, a2 = 0.f, a3 = 0.f;
#pragma unroll
        for (int i = 0; i < 20; i++) {
          int slot = (t - 20 + i) % 22;
          const unsigned long long* vp =
              (const unsigned long long*)(ringv + ((size_t)slot * 64 + b) * 256 + lane * 4);
          unsigned long long v0 = ld_sc_u64(vp), v1 = ld_sc_u64(vp + 1);
          a0 += sArr[i] * __uint_as_float((unsigned)v0);
          a1 += sArr[i] * __uint_as_float((unsigned)(v0 >> 32));
          a2 += sArr[i] * __uint_as_float((unsigned)v1);
          a3 += sArr[i] * __uint_as_float((unsigned)(v1 >> 32));
        }
        float f[4] = {a0 * inv, a1 * inv, a2 * inv, a3 * inv};
        unsigned short hi[4], lo[4];
#pragma unroll
        for (int j = 0; j < 4; j++) f2hilo(f[j], hi[j], lo[j]);
        unsigned long long ph = (unsigned long long)hi[0] | ((unsigned long long)hi[1] << 16) |
                                ((unsigned long long)hi[2] << 32) |
                                ((unsigned long long)hi[3] << 48);
        unsigned long long pl = (unsigned long long)lo[0] | ((unsigned long long)lo[1] << 16) |
                                ((unsigned long long)lo[2] << 32) |
                                ((unsigned long long)lo[3] << 48);
        st_sc_u64((unsigned long long*)(ch + b * 256 + lane * 4), ph);
        st_sc_u64((unsigned long long*)(cl + b * 256 + lane * 4), pl);
      }
      vm_drain();
      __syncthreads();
      bump(LAT, t);
    }
  } else if (wg < 56) {  // ------------- d1 (emb folded): Kp=608 -------------
    const int ut = (wg - 48) * 2 + pair;
    const int u0 = (wg - 48) * 32;
    float c[4][4] = {{0.f}};
    for (int t = 20; t < 400; ++t) {
      const int p = t & 1, q = p ^ 1;
      f32x4 acc[4][4];
      zacc44(acc);
      if (tid == 0 && t >= 21) spin3(CNT(LD1, t - 1), 8, nullptr, 0, nullptr, 0);
      chunk_pass<256, 256>(lds, hb(HD1, q, 0, 256), hb(HD1, q, 1, 256), tid, lane, ut, 1, 256,
                           W + D1HI, W + D1LO, 608, 352, half, acc);
      if (tid == 0 && t >= 21) spin3(CNT(LD3, t - 1), 3, nullptr, 0, nullptr, 0);
      if (t == 20)
        chunk_pass<96, 128>(lds, xh + (size_t)19 * 6144, xl + (size_t)19 * 6144, tid, lane, ut,
                            1, 256, W + D1HI, W + D1LO, 608, 0, half, acc);
      else
        chunk_pass<96, 128>(lds, hb(HLAST, q, 0, 96), hb(HLAST, q, 1, 96), tid, lane, ut, 1,
                            256, W + D1HI, W + D1LO, 608, 0, half, acc);
      if (tid == 0) spin3(CNT(LAT, t), 16, nullptr, 0, nullptr, 0);
      chunk_pass<256, 256>(lds, ctxh + (size_t)p * 64 * 256, ctxl + (size_t)p * 64 * 256, tid,
                           lane, ut, 1, 256, W + D1HI, W + D1LO, 608, 96, half, acc);
      reduce_pair(lds, lane, pair, half, acc);
      if (!half) cell_update_lds(lds + HSTG, lane, pair, ut, 256, d1bp, acc, c, nullptr);
      __syncthreads();
      store_h(lds + HSTG, tid, hb(HD1, p, 0, 256), hb(HD1, p, 1, 256), u0, 256, 32);
      vm_drain();
      __syncthreads();
      bump(LD1, t);
    }
  } else if (wg < 64) {  // ------------- d2 -------------
    const int ut = (wg - 56) * 2 + pair;
    const int u0 = (wg - 56) * 32;
    float c[4][4] = {{0.f}};
    for (int t = 20; t < 400; ++t) {
      const int p = t & 1, q = p ^ 1;
      f32x4 acc[4][4];
      zacc44(acc);
      if (tid == 0 && t >= 21) spin3(CNT(LD2, t - 1), 8, nullptr, 0, nullptr, 0);
      chunk_pass<256, 256>(lds, hb(HD2, q, 0, 256), hb(HD2, q, 1, 256), tid, lane, ut, 1, 256,
                           W + D2HI, W + D2LO, 512, 256, half, acc);
      if (tid == 0) spin3(CNT(LD1, t), 8, nullptr, 0, nullptr, 0);
      chunk_pass<256, 256>(lds, hb(HD1, p, 0, 256), hb(HD1, p, 1, 256), tid, lane, ut, 1, 256,
                           W + D2HI, W + D2LO, 512, 0, half, acc);
      reduce_pair(lds, lane, pair, half, acc);
      if (!half) cell_update_lds(lds + HSTG, lane, pair, ut, 256, d2b, acc, c, nullptr);
      __syncthreads();
      store_h(lds + HSTG, tid, hb(HD2, p, 0, 256), hb(HD2, p, 1, 256), u0, 256, 32);
      vm_drain();
      __syncthreads();
      bump(LD2, t);
    }
  } else {  // ------------- d3: 3 WGs, ut 0..4 -------------
    const int ut = (wg - 64) * 2 + pair;
    const int utActive = (ut < 5) ? 1 : 0;
    const int u0 = (wg - 64) * 32;
    const int ncols = (wg == 66) ? 16 : 32;
    float c[4][4] = {{0.f}};
    for (int t = 20; t < 400; ++t) {
      const int p = t & 1, q = p ^ 1;
      f32x4 acc[4][4];
      zacc44(acc);
      if (tid == 0 && t >= 21) spin3(CNT(LD3, t - 1), 3, nullptr, 0, nullptr, 0);
      chunk_pass<96, 128>(lds, hb(HLAST, q, 0, 96), hb(HLAST, q, 1, 96), tid, lane, ut, utActive,
                          80, W + D3HI, W + D3LO, 352, 256, half, acc);
      if (tid == 0) spin3(CNT(LD2, t), 8, nullptr, 0, nullptr, 0);
      chunk_pass<256, 256>(lds, hb(HD2, p, 0, 256), hb(HD2, p, 1, 256), tid, lane, ut, utActive,
                           80, W + D3HI, W + D3LO, 352, 0, half, acc);
      reduce_pair(lds, lane, pair, half, acc);
      if (!half && utActive)
        cell_update_lds(lds + HSTG, lane, pair, ut, 80, d3b, acc, c,
                        dout + (size_t)(t - 20) * 80);
      __syncthreads();
      store_h(lds + HSTG, tid, hb(HLAST, p, 0, 96), hb(HLAST, p, 1, 96), u0, 96, ncols);
      vm_drain();
      __syncthreads();
      bump(LD3, t);
    }
  }
}

// ---------------- launch ----------------
extern "C" void kernel_launch(void* const* d_in, const int* in_sizes, int n_in, void* d_out,
                              int out_size, void* d_ws, size_t ws_size, hipStream_t stream) {
  if (ws_size < WS_NEED) return;

  const float* x = (const float*)d_in[0];
  const float* embW = (const float*)d_in[1];
  const float* embB = (const float*)d_in[2];
  const float* e1Wih = (const float*)d_in[3];
  const float* e1Whh = (const float*)d_in[4];
  const float* e1B = (const float*)d_in[5];
  const float* e2Wih = (const float*)d_in[6];
  const float* e2Whh = (const float*)d_in[7];
  const float* e2B = (const float*)d_in[8];
  const float* e3Wih = (const float*)d_in[9];
  const float* e3Whh = (const float*)d_in[10];
  const float* e3B = (const float*)d_in[11];
  const float* d1Wih = (const float*)d_in[12];
  const float* d1Whh = (const float*)d_in[13];
  const float* d1B = (const float*)d_in[14];
  const float* d2Wih = (const float*)d_in[15];
  const float* d2Whh = (const float*)d_in[16];
  const float* d2B = (const float*)d_in[17];
  const float* d3Wih = (const float*)d_in[18];
  const float* d3Whh = (const float*)d_in[19];
  const float* d3B = (const float*)d_in[20];
  const float* keyW = (const float*)d_in[21];
  const float* keyB = (const float*)d_in[22];
  const float* valW = (const float*)d_in[23];
  const float* valB = (const float*)d_in[24];

  unsigned char* ws = (unsigned char*)d_ws;
  unsigned short* W = (unsigned short*)ws;
  float* doutf = (float*)d_out;

  auto launch_w = [&](const float* wih, int din, const float* whh, int dh, int rows, int dinp,
                      int kp, size_t offhi, size_t offlo) {
    size_t tot = (size_t)rows * kp;
    int blocks = (int)((tot + 255) / 256);
    prep_w<<<blocks, 256, 0, stream>>>(wih, din, whh, dh, rows, dinp, kp, W + offhi, W + offlo);
  };
  launch_w(e1Wih, 80, e1Whh, 256, 1024, 96, 352, E1HI, E1LO);
  launch_w(e2Wih, 256, e2Whh, 256, 1024, 256, 512, E2HI, E2LO);
  launch_w(e3Wih, 256, e3Whh, 256, 1024, 256, 512, E3HI, E3LO);
  launch_w(d2Wih, 256, d2Whh, 256, 1024, 256, 512, D2HI, D2LO);
  launch_w(d3Wih, 256, d3Whh, 80, 320, 256, 352, D3HI, D3LO);
  launch_w(keyW, 256, nullptr, 0, 256, 256, 256, KHI, KLO);
  launch_w(valW, 256, nullptr, 0, 256, 256, 256, VHI, VLO);
  // d1 folded weights + bias
  {
    size_t tot = (size_t)1024 * 608;
    prep_d1_w<<<(int)((tot + 255) / 256), 256, 0, stream>>>(d1Wih, d1Whh, embW, W + D1HI,
                                                            W + D1LO);
    prep_d1_bias<<<4, 256, 0, stream>>>(d1Wih, embB, d1B, (float*)(ws + D1BP_B));
  }
  prep_x<<<(int)((XPAD_ELEMS + 255) / 256), 256, 0, stream>>>(
      x, (unsigned short*)(ws + XPAD_HI_B), (unsigned short*)(ws + XPAD_LO_B));
  hipMemsetAsync(ws + STATE_B, 0, STATE_BYTES, stream);

  seq_main<<<dim3(NWG), dim3(WGS), 0, stream>>>(e1B, e2B, e3B, d2B, d3B, keyB, valB, doutf, ws);
}

// Round 12
// 15515.987 us; speedup vs baseline: 1.1796x; 1.0075x over previous
//
#include <hip/hip_runtime.h>

typedef short bf16x8 __attribute__((ext_vector_type(8)));
typedef float f32x4 __attribute__((ext_vector_type(4)));
typedef unsigned long long u64;

#define DEV static __device__ __forceinline__
#define SCOPE_AGENT __HIP_MEMORY_SCOPE_AGENT

// ---------------- numeric helpers ----------------
DEV unsigned short f2bf(float f) {
  unsigned u = __float_as_uint(f);
  unsigned r = u + 0x7fffu + ((u >> 16) & 1u);
  return (unsigned short)(r >> 16);
}
DEV float bf2f(unsigned short h) { return __uint_as_float(((unsigned)h) << 16); }
DEV void f2hilo(float f, unsigned short& hi, unsigned short& lo) {
  hi = f2bf(f);
  lo = f2bf(f - bf2f(hi));
}
DEV float sigm(float x) { return 1.f / (1.f + __expf(-x)); }
DEV float tanh_(float x) {
  x = fminf(15.f, fmaxf(-15.f, x));
  float e = __expf(2.f * x);
  return (e - 1.f) / (e + 1.f);
}

// ---------------- coherent (LLC) access helpers ----------------
DEV void st_sc_u16(unsigned short* p, unsigned short v) {
  __hip_atomic_store(p, v, __ATOMIC_RELAXED, SCOPE_AGENT);
}
DEV void st_sc_f32(float* p, float v) {
  __hip_atomic_store(p, v, __ATOMIC_RELAXED, SCOPE_AGENT);
}
DEV void st_sc_u64(u64* p, u64 v) {
  __hip_atomic_store(p, v, __ATOMIC_RELAXED, SCOPE_AGENT);
}
DEV u64 ld_sc_u64(const u64* p) {
  return __hip_atomic_load((u64*)p, __ATOMIC_RELAXED, SCOPE_AGENT);
}
DEV unsigned ld_sc_u32(const unsigned* p) {
  return __hip_atomic_load((unsigned*)p, __ATOMIC_RELAXED, SCOPE_AGENT);
}
DEV void vm_drain() { asm volatile("s_waitcnt vmcnt(0)" ::: "memory"); }

// ---------------- workspace layout ----------------
constexpr size_t WE1 = 1024 * 352, WE2 = 1024 * 512, WE3 = 1024 * 512,
                 WD1 = 1024 * 768, WD2 = 1024 * 512, WD3 = 320 * 352,
                 WKEY = 256 * 256, WVAL = 256 * 256, WEMB = 256 * 96;
constexpr size_t E1HI = 0, E1LO = E1HI + WE1, E2HI = E1LO + WE1, E2LO = E2HI + WE2,
                 E3HI = E2LO + WE2, E3LO = E3HI + WE3, D1HI = E3LO + WE3, D1LO = D1HI + WD1,
                 D2HI = D1LO + WD1, D2LO = D2HI + WD2, D3HI = D2LO + WD2, D3LO = D3HI + WD3,
                 KHI = D3LO + WD3, KLO = KHI + WKEY, VHI = KLO + WKEY, VLO = VHI + WVAL,
                 EMHI = VLO + WVAL, EMLO = EMHI + WEMB, WTOT = EMLO + WEMB;

constexpr size_t XPAD_ELEMS = (size_t)400 * 64 * 96;
constexpr size_t XPAD_HI_B = WTOT * 2;
constexpr size_t XPAD_LO_B = XPAD_HI_B + XPAD_ELEMS * 2;
constexpr size_t STATE_B = XPAD_LO_B + XPAD_ELEMS * 2;

// state (zeroed each launch): h buffers + flag arrays
constexpr size_t H256_SZB = (size_t)2 * 2 * 64 * 256 * 2;  // [parity][hi/lo][64][256] u16
constexpr size_t HE1 = 0, HE2 = H256_SZB, HE3 = 2 * H256_SZB, HD1 = 3 * H256_SZB,
                 HD2 = 4 * H256_SZB;
constexpr size_t HLAST = 5 * H256_SZB;  // [2][2][64][96] u16
constexpr size_t HLAST_SZB = (size_t)2 * 2 * 64 * 96 * 2;
constexpr size_t BARO = HLAST + HLAST_SZB;  // cnt[9][400] u32
constexpr size_t STATE_BYTES = BARO + 9 * 400 * 4 + 64;

// non-zeroed (fully rewritten before first read each launch)
constexpr size_t RINGK_B = STATE_B + STATE_BYTES;
constexpr size_t RING_SZ = (size_t)22 * 64 * 256 * 4;
constexpr size_t RINGV_B = RINGK_B + RING_SZ;
constexpr size_t CTXH_B = RINGV_B + RING_SZ;                  // [2][64][256] u16 (parity)
constexpr size_t CTXL_B = CTXH_B + (size_t)2 * 64 * 256 * 2;
constexpr size_t D1BP_B = CTXL_B + (size_t)2 * 64 * 256 * 2;  // folded d1 bias f32[1024]
constexpr size_t P_B = D1BP_B + 4096;                         // kv partials [2][8][64][512] f32
constexpr size_t P_SZ = (size_t)2 * 8 * 64 * 512 * 4;
constexpr size_t WS_NEED = P_B + P_SZ;

// layer flag ids; cnt[l][t] counts WGs of layer l done with step t
#define LE1 0
#define LE2 1
#define LE3 2
#define LAT 5
#define LD1 6
#define LD2 7
#define LD3 8
// WG map: e1 0-7 | e2 8-15 | e3 16-23 | at 24-39 | d1 40-47 | d2 48-55 | d3 56-58
// targets: e1/e2/e3/d1/d2: 8, at: 16, d3: 3

constexpr int NWG = 59;
constexpr int WGS = 256;
constexpr int HSTG = 20480;  // u16 idx of e3 bounce [64][40] hi + [64][40] lo (stride 40)

// ---------------- prep kernels ----------------
__global__ void prep_w(const float* __restrict__ wih, int din, const float* __restrict__ whh,
                       int dh, int rows, int dinp, int kp, unsigned short* __restrict__ whi,
                       unsigned short* __restrict__ wlo) {
  size_t idx = (size_t)blockIdx.x * 256 + threadIdx.x;
  size_t tot = (size_t)rows * kp;
  if (idx >= tot) return;
  int j = (int)(idx / kp), k = (int)(idx % kp);
  float v = 0.f;
  if (k < dinp) {
    if (k < din) v = wih[(size_t)j * din + k];
  } else {
    int k2 = k - dinp;
    if (k2 < dh) v = whh[(size_t)j * dh + k2];
  }
  unsigned short hi, lo;
  f2hilo(v, hi, lo);
  whi[idx] = hi;
  wlo[idx] = lo;
}

// d1 folded weights: [1024][608] = [W_comb(96) | ctx(256) | Whh(256)]
__global__ void prep_d1_w(const float* __restrict__ wih, const float* __restrict__ whh,
                          const float* __restrict__ embW, unsigned short* __restrict__ whi,
                          unsigned short* __restrict__ wlo) {
  size_t idx = (size_t)blockIdx.x * 256 + threadIdx.x;
  constexpr size_t tot = (size_t)1024 * 608;
  if (idx >= tot) return;
  int j = (int)(idx / 608), f = (int)(idx % 608);
  float v = 0.f;
  if (f < 96) {
    if (f < 80) {
      const float* wr = wih + (size_t)j * 512;
#pragma unroll 4
      for (int m = 0; m < 256; m++) v += wr[m] * embW[(size_t)m * 80 + f];
    }
  } else if (f < 352) {
    v = wih[(size_t)j * 512 + 256 + (f - 96)];
  } else {
    v = whh[(size_t)j * 256 + (f - 352)];
  }
  unsigned short hi, lo;
  f2hilo(v, hi, lo);
  whi[idx] = hi;
  wlo[idx] = lo;
}

__global__ void prep_d1_bias(const float* __restrict__ wih, const float* __restrict__ embb,
                             const float* __restrict__ d1b, float* __restrict__ out) {
  int j = blockIdx.x * 256 + threadIdx.x;
  if (j >= 1024) return;
  float v = d1b[j];
  const float* wr = wih + (size_t)j * 512;
#pragma unroll 4
  for (int m = 0; m < 256; m++) v += wr[m] * embb[m];
  out[j] = v;
}

__global__ void prep_x(const float* __restrict__ x, unsigned short* __restrict__ xh,
                       unsigned short* __restrict__ xl) {
  size_t idx = (size_t)blockIdx.x * 256 + threadIdx.x;
  if (idx >= XPAD_ELEMS) return;
  int t = (int)(idx / 6144), rbf = (int)(idx % 6144), b = rbf / 96, f = rbf % 96;
  float v = (f < 80) ? x[(size_t)b * 32000 + (size_t)t * 80 + f] : 0.f;
  unsigned short hi, lo;
  f2hilo(v, hi, lo);
  xh[idx] = hi;
  xl[idx] = lo;
}

// ---------------- main kernel pieces ----------------
// LDS staging with 16B XOR swizzle: u16 col c -> c ^ ((row&7)<<3)

template <int COLS, int STRIDE>
DEV void copy_hl(unsigned short* lds, const unsigned short* hi, const unsigned short* lo,
                 int tid) {
  constexpr int CU64 = COLS / 4;
  constexpr int PER = 64 * CU64;
  constexpr int TOT = PER * 2;
  constexpr int loOff = 64 * STRIDE;
  for (int base = 0; base < TOT; base += WGS * 32) {
    u64 v[32];
    int dst[32];
#pragma unroll
    for (int u = 0; u < 32; u++) {
      int i = base + u * WGS + tid;
      dst[u] = -1;
      if (i < TOT) {
        int pl = (i >= PER) ? 1 : 0;
        int j = pl ? (i - PER) : i;
        int row = j / CU64, cc = j - row * CU64;
        const u64* s = (const u64*)(pl ? lo : hi);
        v[u] = ld_sc_u64(s + j);
        dst[u] = (pl ? loOff : 0) + row * STRIDE + ((cc * 4) ^ ((row & 7) << 3));
      }
    }
#pragma unroll
    for (int u = 0; u < 32; u++)
      if (dst[u] >= 0) *(u64*)(lds + dst[u]) = v[u];
  }
}

DEV void mfma3(f32x4& acc, bf16x8 ah, bf16x8 al, bf16x8 bh, bf16x8 bl) {
  acc = __builtin_amdgcn_mfma_f32_16x16x32_bf16(ah, bh, acc, 0, 0, 0);
  acc = __builtin_amdgcn_mfma_f32_16x16x32_bf16(al, bh, acc, 0, 0, 0);
  acc = __builtin_amdgcn_mfma_f32_16x16x32_bf16(ah, bl, acc, 0, 0, 0);
}

DEV void zacc44(f32x4 (&a)[4][4]) {
#pragma unroll
  for (int g = 0; g < 4; g++)
#pragma unroll
    for (int m = 0; m < 4; m++) a[g][m] = f32x4{0.f, 0.f, 0.f, 0.f};
}

template <int STRIDE>
DEV void mfma_range(const unsigned short* lds, int lane, int ut, int H,
                    const unsigned short* __restrict__ Whi,
                    const unsigned short* __restrict__ Wlo, int Kp, int kwOff, int kbLo,
                    int kbHi, f32x4 (&acc)[4][4]) {
  const int col = lane & 15, kg = lane >> 4;
  constexpr int loOff = 64 * STRIDE;
  for (int kb = kbLo; kb < kbHi; kb++) {
    const int ka = kb * 32 + kg * 8;
    bf16x8 ah[4], al[4];
#pragma unroll
    for (int m = 0; m < 4; m++) {
      int row = m * 16 + col;
      int off = row * STRIDE + (ka ^ ((row & 7) << 3));
      ah[m] = *(const bf16x8*)(lds + off);
      al[m] = *(const bf16x8*)(lds + loOff + off);
    }
#pragma unroll
    for (int g = 0; g < 4; g++) {
      size_t wr = (size_t)(g * H + ut * 16 + col) * Kp + kwOff + ka;
      bf16x8 bh = *(const bf16x8*)(Whi + wr);
      bf16x8 bl = *(const bf16x8*)(Wlo + wr);
#pragma unroll
      for (int m = 0; m < 4; m++) mfma3(acc[g][m], ah[m], al[m], bh, bl);
    }
  }
}

template <int COLS, int STRIDE>
DEV void chunk_pass(unsigned short* lds, const unsigned short* hi, const unsigned short* lo,
                    int tid, int lane, int ut, int utActive, int H,
                    const unsigned short* __restrict__ Whi,
                    const unsigned short* __restrict__ Wlo, int Kp, int kwOff, int half,
                    f32x4 (&acc)[4][4]) {
  __syncthreads();
  copy_hl<COLS, STRIDE>(lds, hi, lo, tid);
  __syncthreads();
  constexpr int NKB = COLS / 32;
  const int lo_kb = half ? (NKB + 1) / 2 : 0;
  const int hi_kb = half ? NKB : (NKB + 1) / 2;
  if (utActive) mfma_range<STRIDE>(lds, lane, ut, H, Whi, Wlo, Kp, kwOff, lo_kb, hi_kb, acc);
}

DEV void reduce_pair(unsigned short* lds, int lane, int pair, int half, f32x4 (&acc)[4][4]) {
  float* red = (float*)lds;
  const int base = (pair * 64 + lane) * 68;
  __syncthreads();
  if (half) {
#pragma unroll
    for (int g = 0; g < 4; g++)
#pragma unroll
      for (int m = 0; m < 4; m++)
#pragma unroll
        for (int r = 0; r < 4; r++) red[base + (g * 4 + m) * 4 + r] = acc[g][m][r];
  }
  __syncthreads();
  if (!half) {
#pragma unroll
    for (int g = 0; g < 4; g++)
#pragma unroll
      for (int m = 0; m < 4; m++)
#pragma unroll
        for (int r = 0; r < 4; r++) acc[g][m][r] += red[base + (g * 4 + m) * 4 + r];
  }
}

// scattered-store cell update (R8 style)
DEV void cell_update(int lane, int ut, int H, int Hpad, const float* __restrict__ bias,
                     f32x4 (&acc)[4][4], float (&c)[4][4], unsigned short* hwhi,
                     unsigned short* hwlo, float* outp) {
  const int col = lane & 15, kg = lane >> 4;
  const int u = ut * 16 + col;
  const float bi = bias[u], bff = bias[H + u], bg = bias[2 * H + u], bo = bias[3 * H + u];
#pragma unroll
  for (int m = 0; m < 4; m++)
#pragma unroll
    for (int r = 0; r < 4; r++) {
      int b = m * 16 + kg * 4 + r;
      float gi = acc[0][m][r] + bi, gf = acc[1][m][r] + bff;
      float gg = acc[2][m][r] + bg, go = acc[3][m][r] + bo;
      float cn = sigm(gf) * c[m][r] + sigm(gi) * tanh_(gg);
      float hh = sigm(go) * tanh_(cn);
      c[m][r] = cn;
      unsigned short hi, lo;
      f2hilo(hh, hi, lo);
      st_sc_u16(hwhi + b * Hpad + u, hi);
      st_sc_u16(hwlo + b * Hpad + u, lo);
      if (outp) outp[(size_t)b * 30400 + u] = hh;
    }
}

// e3-only: cell update into stride-40 bounce (for kv-partial A operand)
DEV void cell_update_lds40(unsigned short* hstage, int lane, int pairIdx, int ut, int H,
                           const float* __restrict__ bias, f32x4 (&acc)[4][4],
                           float (&c)[4][4]) {
  const int col = lane & 15, kg = lane >> 4;
  const int u = ut * 16 + col;
  const int uloc = pairIdx * 16 + col;
  const float bi = bias[u], bff = bias[H + u], bg = bias[2 * H + u], bo = bias[3 * H + u];
#pragma unroll
  for (int m = 0; m < 4; m++)
#pragma unroll
    for (int r = 0; r < 4; r++) {
      int b = m * 16 + kg * 4 + r;
      float gi = acc[0][m][r] + bi, gf = acc[1][m][r] + bff;
      float gg = acc[2][m][r] + bg, go = acc[3][m][r] + bo;
      float cn = sigm(gf) * c[m][r] + sigm(gi) * tanh_(gg);
      float hh = sigm(go) * tanh_(cn);
      c[m][r] = cn;
      unsigned short hi, lo;
      f2hilo(hh, hi, lo);
      hstage[b * 40 + uloc] = hi;
      hstage[2560 + b * 40 + uloc] = lo;
    }
}

// coalesced HE3 store from stride-40 bounce
DEV void store_h40(const unsigned short* hstage, int tid, unsigned short* hwhi,
                   unsigned short* hwlo, int u0) {
  for (int i = tid; i < 1024; i += WGS) {
    int pl = i >> 9;
    int j = i & 511;
    int b = j >> 3, cc = j & 7;
    u64 v = *(const u64*)(hstage + pl * 2560 + b * 40 + cc * 4);
    st_sc_u64((u64*)((pl ? hwlo : hwhi) + (size_t)b * 256 + u0) + cc, v);
  }
}

DEV void spin3(const unsigned* p0, unsigned t0, const unsigned* p1, unsigned t1,
               const unsigned* p2, unsigned t2) {
  for (;;) {
    unsigned a = p0 ? ld_sc_u32(p0) : 0xFFFFFFFFu;
    unsigned b = p1 ? ld_sc_u32(p1) : 0xFFFFFFFFu;
    unsigned c = p2 ? ld_sc_u32(p2) : 0xFFFFFFFFu;
    if (a >= t0 && b >= t1 && c >= t2) return;
    __builtin_amdgcn_s_sleep(1);
  }
}

// WAR/RAW audit (kv stage deleted; e3 emits partials P[t&1][wg]; at sums):
//  e1(t): [LE1 t-1] own HE1[q]; [LD3 t-1 RAW hlast, LE2 t-2 WAR HE1[p]].
//  e2(t): [LE2 t-1] own; [LE1 t RAW, LE3 t-2 WAR HE2[p]].
//  e3(t): [LE3 t-1] own HE3[q] (also covers HE3[p] WAR: only e3 reads HE3 now);
//    [LE2 t RAW]; P[t&1] WAR vs at-sum of step t-2 (at iteration sigma(t-2), sigma(s)=
//    s<=20?s:s+1): explicit [LAT t-2 >=16] for 2<=t<=22; t>=23 covered transitively:
//    e3(t)<=LE2(t)<=...<=e1(t)<=LD3(t-1)<=d3(t-1)<=LD2(t-1)<=d2(t-1)<=LD1(t-1)<=d1(t-1)
//    <=LAT(t-1)>=at(sigma(t-2)) done.
//  at(t): sums s=(t<=20?t:t-1), skip t==21: [LE3 s >=8]; ring slot s%22 rows WG-private,
//    self-ordered. t>=21 attention: [LD2 t-1 RAW q]; ctx[t&1] WAR covered via
//    at(t)<=LD2(t-1)<=d2(t-1)<=LD1(t-1)=d1(t-1) done (parity double-buffer).
//  d1(t): [LD1 t-1] own (+ d2(t-2) WAR via LAT t <= LD2 t-1); [LD3 t-1] hlast; [LAT t] ctx.
//  d2(t): [LD2 t-1] own; [LD1 t RAW; WAR HD2[p] covered as before].
//  d3(t): [LD3 t-1] own HLAST[q]; [LD2 t RAW; WAR HLAST[p] covered via LD2 t chains].
__global__ void __launch_bounds__(WGS, 1)
seq_main(const float* e1b, const float* e2b, const float* e3b, const float* d2b,
         const float* d3b, const float* keyb, const float* valb, float* dout,
         unsigned char* ws) {
  __shared__ unsigned short lds_s[32768];  // 64 KB
  unsigned short* lds = lds_s;

  const int wg = blockIdx.x, tid = threadIdx.x;
  const int wv = tid >> 6, lane = tid & 63;
  const int pair = wv >> 1, half = wv & 1;

  unsigned short* W = (unsigned short*)ws;
  const unsigned short* xh = (const unsigned short*)(ws + XPAD_HI_B);
  const unsigned short* xl = (const unsigned short*)(ws + XPAD_LO_B);
  unsigned char* st = ws + STATE_B;
  float* ringk = (float*)(ws + RINGK_B);
  float* ringv = (float*)(ws + RINGV_B);
  unsigned short* ctxh = (unsigned short*)(ws + CTXH_B);
  unsigned short* ctxl = (unsigned short*)(ws + CTXL_B);
  const float* d1bp = (const float*)(ws + D1BP_B);
  float* Pbuf = (float*)(ws + P_B);
  unsigned* C = (unsigned*)(st + BARO);
  auto CNT = [&](int l, int tt) { return C + l * 400 + tt; };

  auto hb = [&](size_t off, int par, int hl, int Hpad) {
    return (unsigned short*)(st + off) + (size_t)(par * 2 + hl) * 64 * Hpad;
  };
  auto bump = [&](int l, int tt) {
    if (tid == 0) __hip_atomic_fetch_add(CNT(l, tt), 1u, __ATOMIC_RELAXED, SCOPE_AGENT);
  };

  if (wg < 8) {  // ------------- e1 -------------
    const int ut = wg * 2 + pair;
    float c[4][4] = {{0.f}};
    for (int t = 0; t < 400; ++t) {
      const int p = t & 1, q = p ^ 1;
      f32x4 acc[4][4];
      zacc44(acc);
      if (tid == 0 && t >= 1) spin3(CNT(LE1, t - 1), 8, nullptr, 0, nullptr, 0);
      chunk_pass<256, 256>(lds, hb(HE1, q, 0, 256), hb(HE1, q, 1, 256), tid, lane, ut, 1, 256,
                           W + E1HI, W + E1LO, 352, 96, half, acc);
      if (tid == 0)
        spin3(t >= 21 ? CNT(LD3, t - 1) : nullptr, 3, t >= 2 ? CNT(LE2, t - 2) : nullptr, 8,
              nullptr, 0);
      if (t <= 20)
        chunk_pass<96, 128>(lds, xh + (size_t)t * 6144, xl + (size_t)t * 6144, tid, lane, ut, 1,
                            256, W + E1HI, W + E1LO, 352, 0, half, acc);
      else
        chunk_pass<96, 128>(lds, hb(HLAST, q, 0, 96), hb(HLAST, q, 1, 96), tid, lane, ut, 1,
                            256, W + E1HI, W + E1LO, 352, 0, half, acc);
      reduce_pair(lds, lane, pair, half, acc);
      if (!half)
        cell_update(lane, ut, 256, 256, e1b, acc, c, hb(HE1, p, 0, 256), hb(HE1, p, 1, 256),
                    nullptr);
      vm_drain();
      __syncthreads();
      bump(LE1, t);
    }
  } else if (wg < 16) {  // ------------- e2 -------------
    const int ut = (wg - 8) * 2 + pair;
    float c[4][4] = {{0.f}};
    for (int t = 0; t < 400; ++t) {
      const int p = t & 1, q = p ^ 1;
      f32x4 acc[4][4];
      zacc44(acc);
      if (tid == 0 && t >= 1) spin3(CNT(LE2, t - 1), 8, nullptr, 0, nullptr, 0);
      chunk_pass<256, 256>(lds, hb(HE2, q, 0, 256), hb(HE2, q, 1, 256), tid, lane, ut, 1, 256,
                           W + E2HI, W + E2LO, 512, 256, half, acc);
      if (tid == 0)
        spin3(CNT(LE1, t), 8, t >= 2 ? CNT(LE3, t - 2) : nullptr, 8, nullptr, 0);
      chunk_pass<256, 256>(lds, hb(HE1, p, 0, 256), hb(HE1, p, 1, 256), tid, lane, ut, 1, 256,
                           W + E2HI, W + E2LO, 512, 0, half, acc);
      reduce_pair(lds, lane, pair, half, acc);
      if (!half)
        cell_update(lane, ut, 256, 256, e2b, acc, c, hb(HE2, p, 0, 256), hb(HE2, p, 1, 256),
                    nullptr);
      vm_drain();
      __syncthreads();
      bump(LE2, t);
    }
  } else if (wg < 24) {  // ------------- e3 (+ kv partials) -------------
    const int ut = (wg - 16) * 2 + pair;
    const int u0 = (wg - 16) * 32;
    float c[4][4] = {{0.f}};
    for (int t = 0; t < 400; ++t) {
      const int p = t & 1, q = p ^ 1;
      f32x4 acc[4][4];
      zacc44(acc);
      if (tid == 0 && t >= 1) spin3(CNT(LE3, t - 1), 8, nullptr, 0, nullptr, 0);
      chunk_pass<256, 256>(lds, hb(HE3, q, 0, 256), hb(HE3, q, 1, 256), tid, lane, ut, 1, 256,
                           W + E3HI, W + E3LO, 512, 256, half, acc);
      if (tid == 0) spin3(CNT(LE2, t), 8, nullptr, 0, nullptr, 0);
      chunk_pass<256, 256>(lds, hb(HE2, p, 0, 256), hb(HE2, p, 1, 256), tid, lane, ut, 1, 256,
                           W + E3HI, W + E3LO, 512, 0, half, acc);
      reduce_pair(lds, lane, pair, half, acc);
      // P[t&1] WAR pacing: phase 1 + boundary explicit; phase 2 transitive
      if (tid == 0 && t >= 2 && t <= 22) spin3(CNT(LAT, t - 2), 16, nullptr, 0, nullptr, 0);
      __syncthreads();
      unsigned short* hstage = lds + HSTG;
      if (!half) cell_update_lds40(hstage, lane, pair, ut, 256, e3b, acc, c);
      __syncthreads();
      store_h40(hstage, tid, hb(HE3, p, 0, 256), hb(HE3, p, 1, 256), u0);
      // kv partials: this WG's 32-unit K-slice for all 512 outputs (k|v)
      {
        const int col = lane & 15, kg = lane >> 4;
        bf16x8 ah[4], al[4];
#pragma unroll
        for (int m = 0; m < 4; m++) {
          ah[m] = *(const bf16x8*)(hstage + (m * 16 + col) * 40 + kg * 8);
          al[m] = *(const bf16x8*)(hstage + 2560 + (m * 16 + col) * 40 + kg * 8);
        }
        float* Pw = Pbuf + ((size_t)(t & 1) * 8 + (wg - 16)) * (64 * 512);
        for (int jj = 0; jj < 8; ++jj) {
          int jt = wv * 8 + jj;
          bool isK = jt < 16;
          int jrow = (isK ? jt : jt - 16) * 16 + col;
          size_t wr = (size_t)jrow * 256 + u0 + kg * 8;
          bf16x8 bh = *(const bf16x8*)(W + (isK ? KHI : VHI) + wr);
          bf16x8 bl = *(const bf16x8*)(W + (isK ? KLO : VLO) + wr);
          f32x4 a4[4];
#pragma unroll
          for (int m = 0; m < 4; m++) a4[m] = f32x4{0.f, 0.f, 0.f, 0.f};
#pragma unroll
          for (int m = 0; m < 4; m++) mfma3(a4[m], ah[m], al[m], bh, bl);
          int f = isK ? jrow : jrow + 256;
#pragma unroll
          for (int m = 0; m < 4; m++)
#pragma unroll
            for (int r = 0; r < 4; r++) {
              int b2 = m * 16 + kg * 4 + r;
              st_sc_f32(Pw + (size_t)b2 * 512 + f, a4[m][r]);
            }
        }
      }
      vm_drain();
      __syncthreads();
      bump(LE3, t);
    }
  } else if (wg < 40) {  // ------------- at: 16 WGs, 1 row/wave; sums kv partials ------
    const int b0 = (wg - 24) * 4;
    const int b = b0 + wv;
    for (int t = 0; t < 400; ++t) {
      const int s = (t <= 20) ? t : t - 1;
      const bool doSum = (t != 21);
      float v[8];
      if (doSum) {
        if (tid == 0) spin3(CNT(LE3, s), 8, nullptr, 0, nullptr, 0);
        __syncthreads();
        const int slot = s % 22;
        const float* Pb = Pbuf + (size_t)(s & 1) * 8 * 64 * 512;
        const int f0 = lane * 8;
#pragma unroll
        for (int j = 0; j < 8; j++)
          v[j] = (f0 + j < 256) ? keyb[f0 + j] : valb[f0 + j - 256];
        for (int w = 0; w < 8; w++) {
          const u64* src = (const u64*)(Pb + ((size_t)w * 64 + b) * 512 + f0);
#pragma unroll
          for (int j2 = 0; j2 < 4; j2++) {
            u64 d = ld_sc_u64(src + j2);
            v[j2 * 2] += __uint_as_float((unsigned)d);
            v[j2 * 2 + 1] += __uint_as_float((unsigned)(d >> 32));
          }
        }
        float* ringp = (lane < 32) ? ringk : ringv;
        int fe = (lane < 32) ? f0 : f0 - 256;
        float* dstp = ringp + ((size_t)slot * 64 + b) * 256 + fe;
#pragma unroll
        for (int j2 = 0; j2 < 4; j2++) {
          u64 d = ((u64)__float_as_uint(v[j2 * 2 + 1]) << 32) | __float_as_uint(v[j2 * 2]);
          st_sc_u64((u64*)dstp + j2, d);
        }
      }
      if (t == 20 && lane >= 32) {
        // ctx := v20 (values in v[], parity 0)
        int e = lane * 8 - 256;
        unsigned short hi[8], lo[8];
#pragma unroll
        for (int j = 0; j < 8; j++) f2hilo(v[j], hi[j], lo[j]);
        u64 ph0 = (u64)hi[0] | ((u64)hi[1] << 16) | ((u64)hi[2] << 32) | ((u64)hi[3] << 48);
        u64 ph1 = (u64)hi[4] | ((u64)hi[5] << 16) | ((u64)hi[6] << 32) | ((u64)hi[7] << 48);
        u64 pl0 = (u64)lo[0] | ((u64)lo[1] << 16) | ((u64)lo[2] << 32) | ((u64)lo[3] << 48);
        u64 pl1 = (u64)lo[4] | ((u64)lo[5] << 16) | ((u64)lo[6] << 32) | ((u64)lo[7] << 48);
        st_sc_u64((u64*)(ctxh + b * 256 + e), ph0);
        st_sc_u64((u64*)(ctxh + b * 256 + e) + 1, ph1);
        st_sc_u64((u64*)(ctxl + b * 256 + e), pl0);
        st_sc_u64((u64*)(ctxl + b * 256 + e) + 1, pl1);
      }
      if (t >= 21) {
        vm_drain();  // own ring stores visible before own reads
        if (tid == 0) spin3(CNT(LD2, t - 1), 8, nullptr, 0, nullptr, 0);
        __syncthreads();
        unsigned short* ch = ctxh + (size_t)(t & 1) * 64 * 256;
        unsigned short* cl = ctxl + (size_t)(t & 1) * 64 * 256;
        const int qp = (t & 1) ^ 1;
        const unsigned short* qh = hb(HD2, qp, 0, 256);
        const unsigned short* ql = hb(HD2, qp, 1, 256);
        u64 hq = ld_sc_u64((const u64*)(qh + b * 256 + lane * 4));
        u64 lq = ld_sc_u64((const u64*)(ql + b * 256 + lane * 4));
        float qv[4];
#pragma unroll
        for (int j = 0; j < 4; j++)
          qv[j] = bf2f((unsigned short)(hq >> (16 * j))) + bf2f((unsigned short)(lq >> (16 * j)));
        float sArr[20];
#pragma unroll
        for (int i = 0; i < 20; i++) {
          int slot = (t - 20 + i) % 22;
          const u64* kp = (const u64*)(ringk + ((size_t)slot * 64 + b) * 256 + lane * 4);
          u64 k0 = ld_sc_u64(kp), k1 = ld_sc_u64(kp + 1);
          sArr[i] = __uint_as_float((unsigned)k0) * qv[0] +
                    __uint_as_float((unsigned)(k0 >> 32)) * qv[1] +
                    __uint_as_float((unsigned)k1) * qv[2] +
                    __uint_as_float((unsigned)(k1 >> 32)) * qv[3];
        }
#pragma unroll
        for (int off = 32; off >= 1; off >>= 1)
#pragma unroll
          for (int i = 0; i < 20; i++) sArr[i] += __shfl_xor(sArr[i], off, 64);
        float mx = sArr[0];
#pragma unroll
        for (int i = 1; i < 20; i++) mx = fmaxf(mx, sArr[i]);
        float den = 0.f;
#pragma unroll
        for (int i = 0; i < 20; i++) {
          sArr[i] = __expf(sArr[i] - mx);
          den += sArr[i];
        }
        float inv = 1.f / den;
        float a0 = 0.f, a1 = 0.f, a2 = 0.f, a3 = 0.f;
#pragma unroll
        for (int i = 0; i < 20; i++) {
          int slot = (t - 20 + i) % 22;
          const u64* vp = (const u64*)(ringv + ((size_t)slot * 64 + b) * 256 + lane * 4);
          u64 v0 = ld_sc_u64(vp), v1 = ld_sc_u64(vp + 1);
          a0 += sArr[i] * __uint_as_float((unsigned)v0);
          a1 += sArr[i] * __uint_as_float((unsigned)(v0 >> 32));
          a2 += sArr[i] * __uint_as_float((unsigned)v1);
          a3 += sArr[i] * __uint_as_float((unsigned)(v1 >> 32));
        }
        float f[4] = {a0 * inv, a1 * inv, a2 * inv, a3 * inv};
        unsigned short hi[4], lo[4];
#pragma unroll
        for (int j = 0; j < 4; j++) f2hilo(f[j], hi[j], lo[j]);
        u64 ph = (u64)hi[0] | ((u64)hi[1] << 16) | ((u64)hi[2] << 32) | ((u64)hi[3] << 48);
        u64 pl = (u64)lo[0] | ((u64)lo[1] << 16) | ((u64)lo[2] << 32) | ((u64)lo[3] << 48);
        st_sc_u64((u64*)(ch + b * 256 + lane * 4), ph);
        st_sc_u64((u64*)(cl + b * 256 + lane * 4), pl);
      }
      vm_drain();
      __syncthreads();
      bump(LAT, t);
    }
  } else if (wg < 48) {  // ------------- d1 (emb folded): Kp=608 -------------
    const int ut = (wg - 40) * 2 + pair;
    float c[4][4] = {{0.f}};
    for (int t = 20; t < 400; ++t) {
      const int p = t & 1, q = p ^ 1;
      f32x4 acc[4][4];
      zacc44(acc);
      if (tid == 0 && t >= 21) spin3(CNT(LD1, t - 1), 8, nullptr, 0, nullptr, 0);
      chunk_pass<256, 256>(lds, hb(HD1, q, 0, 256), hb(HD1, q, 1, 256), tid, lane, ut, 1, 256,
                           W + D1HI, W + D1LO, 608, 352, half, acc);
      if (tid == 0 && t >= 21) spin3(CNT(LD3, t - 1), 3, nullptr, 0, nullptr, 0);
      if (t == 20)
        chunk_pass<96, 128>(lds, xh + (size_t)19 * 6144, xl + (size_t)19 * 6144, tid, lane, ut,
                            1, 256, W + D1HI, W + D1LO, 608, 0, half, acc);
      else
        chunk_pass<96, 128>(lds, hb(HLAST, q, 0, 96), hb(HLAST, q, 1, 96), tid, lane, ut, 1,
                            256, W + D1HI, W + D1LO, 608, 0, half, acc);
      if (tid == 0) spin3(CNT(LAT, t), 16, nullptr, 0, nullptr, 0);
      chunk_pass<256, 256>(lds, ctxh + (size_t)p * 64 * 256, ctxl + (size_t)p * 64 * 256, tid,
                           lane, ut, 1, 256, W + D1HI, W + D1LO, 608, 96, half, acc);
      reduce_pair(lds, lane, pair, half, acc);
      if (!half)
        cell_update(lane, ut, 256, 256, d1bp, acc, c, hb(HD1, p, 0, 256), hb(HD1, p, 1, 256),
                    nullptr);
      vm_drain();
      __syncthreads();
      bump(LD1, t);
    }
  } else if (wg < 56) {  // ------------- d2 -------------
    const int ut = (wg - 48) * 2 + pair;
    float c[4][4] = {{0.f}};
    for (int t = 20; t < 400; ++t) {
      const int p = t & 1, q = p ^ 1;
      f32x4 acc[4][4];
      zacc44(acc);
      if (tid == 0 && t >= 21) spin3(CNT(LD2, t - 1), 8, nullptr, 0, nullptr, 0);
      chunk_pass<256, 256>(lds, hb(HD2, q, 0, 256), hb(HD2, q, 1, 256), tid, lane, ut, 1, 256,
                           W + D2HI, W + D2LO, 512, 256, half, acc);
      if (tid == 0) spin3(CNT(LD1, t), 8, nullptr, 0, nullptr, 0);
      chunk_pass<256, 256>(lds, hb(HD1, p, 0, 256), hb(HD1, p, 1, 256), tid, lane, ut, 1, 256,
                           W + D2HI, W + D2LO, 512, 0, half, acc);
      reduce_pair(lds, lane, pair, half, acc);
      if (!half)
        cell_update(lane, ut, 256, 256, d2b, acc, c, hb(HD2, p, 0, 256), hb(HD2, p, 1, 256),
                    nullptr);
      vm_drain();
      __syncthreads();
      bump(LD2, t);
    }
  } else {  // ------------- d3: 3 WGs, ut 0..4 -------------
    const int ut = (wg - 56) * 2 + pair;
    const int utActive = (ut < 5) ? 1 : 0;
    float c[4][4] = {{0.f}};
    for (int t = 20; t < 400; ++t) {
      const int p = t & 1, q = p ^ 1;
      f32x4 acc[4][4];
      zacc44(acc);
      if (tid == 0 && t >= 21) spin3(CNT(LD3, t - 1), 3, nullptr, 0, nullptr, 0);
      chunk_pass<96, 128>(lds, hb(HLAST, q, 0, 96), hb(HLAST, q, 1, 96), tid, lane, ut, utActive,
                          80, W + D3HI, W + D3LO, 352, 256, half, acc);
      if (tid == 0) spin3(CNT(LD2, t), 8, nullptr, 0, nullptr, 0);
      chunk_pass<256, 256>(lds, hb(HD2, p, 0, 256), hb(HD2, p, 1, 256), tid, lane, ut, utActive,
                           80, W + D3HI, W + D3LO, 352, 0, half, acc);
      reduce_pair(lds, lane, pair, half, acc);
      if (!half && utActive)
        cell_update(lane, ut, 80, 96, d3b, acc, c, hb(HLAST, p, 0, 96), hb(HLAST, p, 1, 96),
                    dout + (size_t)(t - 20) * 80);
      vm_drain();
      __syncthreads();
      bump(LD3, t);
    }
  }
}

// ---------------- launch ----------------
extern "C" void kernel_launch(void* const* d_in, const int* in_sizes, int n_in, void* d_out,
                              int out_size, void* d_ws, size_t ws_size, hipStream_t stream) {
  if (ws_size < WS_NEED) return;

  const float* x = (const float*)d_in[0];
  const float* embW = (const float*)d_in[1];
  const float* embB = (const float*)d_in[2];
  const float* e1Wih = (const float*)d_in[3];
  const float* e1Whh = (const float*)d_in[4];
  const float* e1B = (const float*)d_in[5];
  const float* e2Wih = (const float*)d_in[6];
  const float* e2Whh = (const float*)d_in[7];
  const float* e2B = (const float*)d_in[8];
  const float* e3Wih = (const float*)d_in[9];
  const float* e3Whh = (const float*)d_in[10];
  const float* e3B = (const float*)d_in[11];
  const float* d1Wih = (const float*)d_in[12];
  const float* d1Whh = (const float*)d_in[13];
  const float* d1B = (const float*)d_in[14];
  const float* d2Wih = (const float*)d_in[15];
  const float* d2Whh = (const float*)d_in[16];
  const float* d2B = (const float*)d_in[17];
  const float* d3Wih = (const float*)d_in[18];
  const float* d3Whh = (const float*)d_in[19];
  const float* d3B = (const float*)d_in[20];
  const float* keyW = (const float*)d_in[21];
  const float* keyB = (const float*)d_in[22];
  const float* valW = (const float*)d_in[23];
  const float* valB = (const float*)d_in[24];

  unsigned char* ws = (unsigned char*)d_ws;
  unsigned short* W = (unsigned short*)ws;
  float* doutf = (float*)d_out;

  auto launch_w = [&](const float* wih, int din, const float* whh, int dh, int rows, int dinp,
                      int kp, size_t offhi, size_t offlo) {
    size_t tot = (size_t)rows * kp;
    int blocks = (int)((tot + 255) / 256);
    prep_w<<<blocks, 256, 0, stream>>>(wih, din, whh, dh, rows, dinp, kp, W + offhi, W + offlo);
  };
  launch_w(e1Wih, 80, e1Whh, 256, 1024, 96, 352, E1HI, E1LO);
  launch_w(e2Wih, 256, e2Whh, 256, 1024, 256, 512, E2HI, E2LO);
  launch_w(e3Wih, 256, e3Whh, 256, 1024, 256, 512, E3HI, E3LO);
  launch_w(d2Wih, 256, d2Whh, 256, 1024, 256, 512, D2HI, D2LO);
  launch_w(d3Wih, 256, d3Whh, 80, 320, 256, 352, D3HI, D3LO);
  launch_w(keyW, 256, nullptr, 0, 256, 256, 256, KHI, KLO);
  launch_w(valW, 256, nullptr, 0, 256, 256, 256, VHI, VLO);
  {
    size_t tot = (size_t)1024 * 608;
    prep_d1_w<<<(int)((tot + 255) / 256), 256, 0, stream>>>(d1Wih, d1Whh, embW, W + D1HI,
                                                            W + D1LO);
    prep_d1_bias<<<4, 256, 0, stream>>>(d1Wih, embB, d1B, (float*)(ws + D1BP_B));
  }
  prep_x<<<(int)((XPAD_ELEMS + 255) / 256), 256, 0, stream>>>(
      x, (unsigned short*)(ws + XPAD_HI_B), (unsigned short*)(ws + XPAD_LO_B));
  hipMemsetAsync(ws + STATE_B, 0, STATE_BYTES, stream);

  seq_main<<<dim3(NWG), dim3(WGS), 0, stream>>>(e1B, e2B, e3B, d2B, d3B, keyB, valB, doutf, ws);
}

// Round 13
// 14970.508 us; speedup vs baseline: 1.2226x; 1.0364x over previous
//
#include <hip/hip_runtime.h>

typedef short bf16x8 __attribute__((ext_vector_type(8)));
typedef float f32x4 __attribute__((ext_vector_type(4)));

#define DEV static __device__ __forceinline__
#define SCOPE_AGENT __HIP_MEMORY_SCOPE_AGENT

// ---------------- numeric helpers ----------------
DEV unsigned short f2bf(float f) {
  unsigned u = __float_as_uint(f);
  unsigned r = u + 0x7fffu + ((u >> 16) & 1u);
  return (unsigned short)(r >> 16);
}
DEV float bf2f(unsigned short h) { return __uint_as_float(((unsigned)h) << 16); }
DEV void f2hilo(float f, unsigned short& hi, unsigned short& lo) {
  hi = f2bf(f);
  lo = f2bf(f - bf2f(hi));
}
DEV float sigm(float x) { return 1.f / (1.f + __expf(-x)); }
DEV float tanh_(float x) {
  x = fminf(15.f, fmaxf(-15.f, x));
  float e = __expf(2.f * x);
  return (e - 1.f) / (e + 1.f);
}

// ---------------- coherent (LLC) access helpers ----------------
DEV void st_sc_u16(unsigned short* p, unsigned short v) {
  __hip_atomic_store(p, v, __ATOMIC_RELAXED, SCOPE_AGENT);
}
DEV void st_sc_f32(float* p, float v) {
  __hip_atomic_store(p, v, __ATOMIC_RELAXED, SCOPE_AGENT);
}
DEV void st_sc_u64(unsigned long long* p, unsigned long long v) {
  __hip_atomic_store(p, v, __ATOMIC_RELAXED, SCOPE_AGENT);
}
DEV unsigned long long ld_sc_u64(const unsigned long long* p) {
  return __hip_atomic_load((unsigned long long*)p, __ATOMIC_RELAXED, SCOPE_AGENT);
}
DEV unsigned ld_sc_u32(const unsigned* p) {
  return __hip_atomic_load((unsigned*)p, __ATOMIC_RELAXED, SCOPE_AGENT);
}
DEV void vm_drain() { asm volatile("s_waitcnt vmcnt(0)" ::: "memory"); }

// ---------------- workspace layout ----------------
constexpr size_t WE1 = 1024 * 352, WE2 = 1024 * 512, WE3 = 1024 * 512,
                 WD1 = 1024 * 768, WD2 = 1024 * 512, WD3 = 320 * 352,
                 WKEY = 256 * 256, WVAL = 256 * 256, WEMB = 256 * 96;
constexpr size_t E1HI = 0, E1LO = E1HI + WE1, E2HI = E1LO + WE1, E2LO = E2HI + WE2,
                 E3HI = E2LO + WE2, E3LO = E3HI + WE3, D1HI = E3LO + WE3, D1LO = D1HI + WD1,
                 D2HI = D1LO + WD1, D2LO = D2HI + WD2, D3HI = D2LO + WD2, D3LO = D3HI + WD3,
                 KHI = D3LO + WD3, KLO = KHI + WKEY, VHI = KLO + WKEY, VLO = VHI + WVAL,
                 EMHI = VLO + WVAL, EMLO = EMHI + WEMB, WTOT = EMLO + WEMB;

constexpr size_t XPAD_ELEMS = (size_t)400 * 64 * 96;
constexpr size_t XPAD_HI_B = WTOT * 2;
constexpr size_t XPAD_LO_B = XPAD_HI_B + XPAD_ELEMS * 2;
constexpr size_t STATE_B = XPAD_LO_B + XPAD_ELEMS * 2;

// state (zeroed each launch): h buffers + flag arrays
constexpr size_t H256_SZB = (size_t)2 * 2 * 64 * 256 * 2;  // [parity][hi/lo][64][256] u16
constexpr size_t HE1 = 0, HE2 = H256_SZB, HE3 = 2 * H256_SZB, HD1 = 3 * H256_SZB,
                 HD2 = 4 * H256_SZB;
constexpr size_t HLAST = 5 * H256_SZB;  // [2][2][64][96] u16
constexpr size_t HLAST_SZB = (size_t)2 * 2 * 64 * 96 * 2;
constexpr size_t BARO = HLAST + HLAST_SZB;  // cnt[9][400] u32
constexpr size_t STATE_BYTES = BARO + 9 * 400 * 4 + 64;

// non-zeroed (fully rewritten before first read each launch)
constexpr size_t RINGK_B = STATE_B + STATE_BYTES;
constexpr size_t RING_SZ = (size_t)22 * 64 * 256 * 4;  // 22 slots: kv(t) only WARs attn(t-2)
constexpr size_t RINGV_B = RINGK_B + RING_SZ;
constexpr size_t CTXH_B = RINGV_B + RING_SZ;
constexpr size_t CTXL_B = CTXH_B + (size_t)64 * 256 * 2;
constexpr size_t D1BP_B = CTXL_B + (size_t)64 * 256 * 2;  // folded d1 bias f32[1024]
constexpr size_t WS_NEED = D1BP_B + 4096;

// layer flag ids; cnt[l][t] counts WGs of layer l done with step t
#define LE1 0
#define LE2 1
#define LE3 2
#define LKV 3
#define LAT 5
#define LD1 6
#define LD2 7
#define LD3 8
// WG map: e1 0-7 | e2 8-15 | e3 16-23 | kv 24-31 | at 32-47 | d1 48-55 | d2 56-63 | d3 64-66
// targets: e1/e2/e3/kv/d1/d2: 8, at: 16, d3: 3

constexpr int NWG = 67;
constexpr int WGS = 256;

// ---------------- prep kernels ----------------
__global__ void prep_w(const float* __restrict__ wih, int din, const float* __restrict__ whh,
                       int dh, int rows, int dinp, int kp, unsigned short* __restrict__ whi,
                       unsigned short* __restrict__ wlo) {
  size_t idx = (size_t)blockIdx.x * 256 + threadIdx.x;
  size_t tot = (size_t)rows * kp;
  if (idx >= tot) return;
  int j = (int)(idx / kp), k = (int)(idx % kp);
  float v = 0.f;
  if (k < dinp) {
    if (k < din) v = wih[(size_t)j * din + k];
  } else {
    int k2 = k - dinp;
    if (k2 < dh) v = whh[(size_t)j * dh + k2];
  }
  unsigned short hi, lo;
  f2hilo(v, hi, lo);
  whi[idx] = hi;
  wlo[idx] = lo;
}

// d1 folded weights: [1024][608] = [ W_comb(96: d1Wih[:, :256]@embW, cols>=80 zero) |
//                                    d1Wih[:,256:512] (ctx) | d1Whh (h) ]
__global__ void prep_d1_w(const float* __restrict__ wih, const float* __restrict__ whh,
                          const float* __restrict__ embW, unsigned short* __restrict__ whi,
                          unsigned short* __restrict__ wlo) {
  size_t idx = (size_t)blockIdx.x * 256 + threadIdx.x;
  constexpr size_t tot = (size_t)1024 * 608;
  if (idx >= tot) return;
  int j = (int)(idx / 608), f = (int)(idx % 608);
  float v = 0.f;
  if (f < 96) {
    if (f < 80) {
      const float* wr = wih + (size_t)j * 512;
#pragma unroll 4
      for (int m = 0; m < 256; m++) v += wr[m] * embW[(size_t)m * 80 + f];
    }
  } else if (f < 352) {
    v = wih[(size_t)j * 512 + 256 + (f - 96)];
  } else {
    v = whh[(size_t)j * 256 + (f - 352)];
  }
  unsigned short hi, lo;
  f2hilo(v, hi, lo);
  whi[idx] = hi;
  wlo[idx] = lo;
}

__global__ void prep_d1_bias(const float* __restrict__ wih, const float* __restrict__ embb,
                             const float* __restrict__ d1b, float* __restrict__ out) {
  int j = blockIdx.x * 256 + threadIdx.x;
  if (j >= 1024) return;
  float v = d1b[j];
  const float* wr = wih + (size_t)j * 512;
#pragma unroll 4
  for (int m = 0; m < 256; m++) v += wr[m] * embb[m];
  out[j] = v;
}

__global__ void prep_x(const float* __restrict__ x, unsigned short* __restrict__ xh,
                       unsigned short* __restrict__ xl) {
  size_t idx = (size_t)blockIdx.x * 256 + threadIdx.x;
  if (idx >= XPAD_ELEMS) return;
  int t = (int)(idx / 6144), rbf = (int)(idx % 6144), b = rbf / 96, f = rbf % 96;
  float v = (f < 80) ? x[(size_t)b * 32000 + (size_t)t * 80 + f] : 0.f;
  unsigned short hi, lo;
  f2hilo(v, hi, lo);
  xh[idx] = hi;
  xl[idx] = lo;
}

// ---------------- main kernel pieces ----------------
// LDS staging with 16B XOR swizzle: u16 col c -> c ^ ((row&7)<<3)

template <int COLS, int STRIDE>
DEV void copy_hl(unsigned short* lds, const unsigned short* hi, const unsigned short* lo,
                 int tid) {
  constexpr int CU64 = COLS / 4;
  constexpr int PER = 64 * CU64;
  constexpr int TOT = PER * 2;
  constexpr int loOff = 64 * STRIDE;
  for (int base = 0; base < TOT; base += WGS * 16) {
    unsigned long long v[16];
    int dst[16];
#pragma unroll
    for (int u = 0; u < 16; u++) {
      int i = base + u * WGS + tid;
      dst[u] = -1;
      if (i < TOT) {
        int pl = (i >= PER) ? 1 : 0;
        int j = pl ? (i - PER) : i;
        int row = j / CU64, cc = j - row * CU64;
        const unsigned long long* s = (const unsigned long long*)(pl ? lo : hi);
        v[u] = ld_sc_u64(s + j);
        dst[u] = (pl ? loOff : 0) + row * STRIDE + ((cc * 4) ^ ((row & 7) << 3));
      }
    }
#pragma unroll
    for (int u = 0; u < 16; u++)
      if (dst[u] >= 0) *(unsigned long long*)(lds + dst[u]) = v[u];
  }
}

DEV void mfma3(f32x4& acc, bf16x8 ah, bf16x8 al, bf16x8 bh, bf16x8 bl) {
  acc = __builtin_amdgcn_mfma_f32_16x16x32_bf16(ah, bh, acc, 0, 0, 0);
  acc = __builtin_amdgcn_mfma_f32_16x16x32_bf16(al, bh, acc, 0, 0, 0);
  acc = __builtin_amdgcn_mfma_f32_16x16x32_bf16(ah, bl, acc, 0, 0, 0);
}

DEV void zacc44(f32x4 (&a)[4][4]) {
#pragma unroll
  for (int g = 0; g < 4; g++)
#pragma unroll
    for (int m = 0; m < 4; m++) a[g][m] = f32x4{0.f, 0.f, 0.f, 0.f};
}

// MFMA over kb index range [kbLo,kbHi) of the staged chunk (K-split support)
template <int STRIDE>
DEV void mfma_range(const unsigned short* lds, int lane, int ut, int H,
                    const unsigned short* __restrict__ Whi,
                    const unsigned short* __restrict__ Wlo, int Kp, int kwOff, int kbLo,
                    int kbHi, f32x4 (&acc)[4][4]) {
  const int col = lane & 15, kg = lane >> 4;
  constexpr int loOff = 64 * STRIDE;
  for (int kb = kbLo; kb < kbHi; kb++) {
    const int ka = kb * 32 + kg * 8;
    bf16x8 ah[4], al[4];
#pragma unroll
    for (int m = 0; m < 4; m++) {
      int row = m * 16 + col;
      int off = row * STRIDE + (ka ^ ((row & 7) << 3));
      ah[m] = *(const bf16x8*)(lds + off);
      al[m] = *(const bf16x8*)(lds + loOff + off);
    }
#pragma unroll
    for (int g = 0; g < 4; g++) {
      size_t wr = (size_t)(g * H + ut * 16 + col) * Kp + kwOff + ka;
      bf16x8 bh = *(const bf16x8*)(Whi + wr);
      bf16x8 bl = *(const bf16x8*)(Wlo + wr);
#pragma unroll
      for (int m = 0; m < 4; m++) mfma3(acc[g][m], ah[m], al[m], bh, bl);
    }
  }
}

// one staged chunk: barrier, copy, barrier, half-K MFMA
template <int COLS, int STRIDE>
DEV void chunk_pass(unsigned short* lds, const unsigned short* hi, const unsigned short* lo,
                    int tid, int lane, int ut, int utActive, int H,
                    const unsigned short* __restrict__ Whi,
                    const unsigned short* __restrict__ Wlo, int Kp, int kwOff, int half,
                    f32x4 (&acc)[4][4]) {
  __syncthreads();  // releases spin + previous LDS consumers done
  copy_hl<COLS, STRIDE>(lds, hi, lo, tid);
  __syncthreads();
  constexpr int NKB = COLS / 32;
  const int lo_kb = half ? (NKB + 1) / 2 : 0;
  const int hi_kb = half ? NKB : (NKB + 1) / 2;
  if (utActive) mfma_range<STRIDE>(lds, lane, ut, H, Whi, Wlo, Kp, kwOff, lo_kb, hi_kb, acc);
}

// combine the two K-halves: half1 writes partials to LDS, half0 adds
DEV void reduce_pair(unsigned short* lds, int lane, int pair, int half, f32x4 (&acc)[4][4]) {
  float* red = (float*)lds;
  const int base = (pair * 64 + lane) * 68;  // stride 68 f32 -> banks spread
  __syncthreads();
  if (half) {
#pragma unroll
    for (int g = 0; g < 4; g++)
#pragma unroll
      for (int m = 0; m < 4; m++)
#pragma unroll
        for (int r = 0; r < 4; r++) red[base + (g * 4 + m) * 4 + r] = acc[g][m][r];
  }
  __syncthreads();
  if (!half) {
#pragma unroll
    for (int g = 0; g < 4; g++)
#pragma unroll
      for (int m = 0; m < 4; m++)
#pragma unroll
        for (int r = 0; r < 4; r++) acc[g][m][r] += red[base + (g * 4 + m) * 4 + r];
  }
}

DEV void cell_update(int lane, int ut, int H, int Hpad, const float* __restrict__ bias,
                     f32x4 (&acc)[4][4], float (&c)[4][4], unsigned short* hwhi,
                     unsigned short* hwlo, float* outp) {
  const int col = lane & 15, kg = lane >> 4;
  const int u = ut * 16 + col;
  const float bi = bias[u], bff = bias[H + u], bg = bias[2 * H + u], bo = bias[3 * H + u];
#pragma unroll
  for (int m = 0; m < 4; m++)
#pragma unroll
    for (int r = 0; r < 4; r++) {
      int b = m * 16 + kg * 4 + r;
      float gi = acc[0][m][r] + bi, gf = acc[1][m][r] + bff;
      float gg = acc[2][m][r] + bg, go = acc[3][m][r] + bo;
      float cn = sigm(gf) * c[m][r] + sigm(gi) * tanh_(gg);
      float hh = sigm(go) * tanh_(cn);
      c[m][r] = cn;
      unsigned short hi, lo;
      f2hilo(hh, hi, lo);
      st_sc_u16(hwhi + b * Hpad + u, hi);
      st_sc_u16(hwlo + b * Hpad + u, lo);
      if (outp) outp[(size_t)b * 30400 + u] = hh;
    }
}

// linear (key/val): full-K per wave
template <int K, int STRIDE>
DEV void mfma_lin(const unsigned short* lds, int lane, int jt,
                  const unsigned short* __restrict__ Whi,
                  const unsigned short* __restrict__ Wlo, int Kp, f32x4 (&acc)[4]) {
  const int col = lane & 15, kg = lane >> 4;
  constexpr int loOff = 64 * STRIDE;
#pragma unroll
  for (int kb = 0; kb < K; kb += 32) {
    const int ka = kb + kg * 8;
    size_t wr = (size_t)(jt * 16 + col) * Kp + ka;
    bf16x8 bh = *(const bf16x8*)(Whi + wr);
    bf16x8 bl = *(const bf16x8*)(Wlo + wr);
#pragma unroll
    for (int m = 0; m < 4; m++) {
      int row = m * 16 + col;
      int off = row * STRIDE + (ka ^ ((row & 7) << 3));
      bf16x8 ah = *(const bf16x8*)(lds + off);
      bf16x8 al = *(const bf16x8*)(lds + loOff + off);
      mfma3(acc[m], ah, al, bh, bl);
    }
  }
}

// up to 3 flag waits; null ptr = skip
DEV void spin3(const unsigned* p0, unsigned t0, const unsigned* p1, unsigned t1,
               const unsigned* p2, unsigned t2) {
  for (;;) {
    unsigned a = p0 ? ld_sc_u32(p0) : 0xFFFFFFFFu;
    unsigned b = p1 ? ld_sc_u32(p1) : 0xFFFFFFFFu;
    unsigned c = p2 ? ld_sc_u32(p2) : 0xFFFFFFFFu;
    if (a >= t0 && b >= t1 && c >= t2) return;
    __builtin_amdgcn_s_sleep(1);
  }
}

// WAR/RAW audit (chunk-reordered; own/old chunk first, fresh dep last):
//  e1(t): [A: LE1 t-1] own HE1[q]; [B: LD3 t-1 (RAW hlast), LE2 t-2 (WAR HE1[p])] x/hlast.
//  e2(t): [A: LE2 t-1] own HE2[q]; [B: LE1 t (RAW), LE3 t-2 (WAR HE2[p])] HE1[p].
//  e3(t): [A: LE3 t-1] own HE3[q]; [B: LE2 t (RAW), LKV t-2 (WAR HE3[p])] HE2[p].
//  kv(t): [LE3 t (RAW), LAT t-2 (WAR ring slot t%22)] HE3[p].
//  at(t): [LKV t-1 (RAW ring), LD2 t-1 (RAW q), LD1 t-1 (WAR ctx)].
//  d1(t): [A: LD1 t-1 (RAW own + WAR HD1[p]; d2(t-2) covered via LAT t <= LD2 t-1)]
//         own HD1[q]; [B: LD3 t-1] hlast/x19; [C: LAT t] ctx.
//  d2(t): [A: LD2 t-1] own HD2[q]; [B: LD1 t (RAW; also covers WAR HD2[p]: at(t-1) &
//         d3(t-2) via LD1 t <= LAT t <= LD2 t-1 <= LD1 t-1 <= d1(t-1) <= LD3 t-2)] HD1[p].
//  d3(t): [A: LD3 t-1] own HLAST[q]; [B: LD2 t (RAW; WAR HLAST[p]: e1(t-1)/d1(t-1) covered
//         via LD2 t <= LD1 t <= LAT t <= LKV t-1 <= e3,e2,e1(t-1), and LD1 t => d1(t-1))] HD2[p].
__global__ void __launch_bounds__(WGS, 1)
seq_main(const float* e1b, const float* e2b, const float* e3b, const float* d2b,
         const float* d3b, const float* keyb, const float* valb, float* dout,
         unsigned char* ws) {
  __shared__ unsigned short lds_s[32768];  // 64 KB
  unsigned short* lds = lds_s;

  const int wg = blockIdx.x, tid = threadIdx.x;
  const int wv = tid >> 6, lane = tid & 63;
  const int pair = wv >> 1, half = wv & 1;

  unsigned short* W = (unsigned short*)ws;
  const unsigned short* xh = (const unsigned short*)(ws + XPAD_HI_B);
  const unsigned short* xl = (const unsigned short*)(ws + XPAD_LO_B);
  unsigned char* st = ws + STATE_B;
  float* ringk = (float*)(ws + RINGK_B);
  float* ringv = (float*)(ws + RINGV_B);
  unsigned short* ctxh = (unsigned short*)(ws + CTXH_B);
  unsigned short* ctxl = (unsigned short*)(ws + CTXL_B);
  const float* d1bp = (const float*)(ws + D1BP_B);
  unsigned* C = (unsigned*)(st + BARO);
  auto CNT = [&](int l, int tt) { return C + l * 400 + tt; };

  auto hb = [&](size_t off, int par, int hl, int Hpad) {
    return (unsigned short*)(st + off) + (size_t)(par * 2 + hl) * 64 * Hpad;
  };
  auto bump = [&](int l, int tt) {
    if (tid == 0) __hip_atomic_fetch_add(CNT(l, tt), 1u, __ATOMIC_RELAXED, SCOPE_AGENT);
  };

  if (wg < 8) {  // ------------- e1 -------------
    const int ut = wg * 2 + pair;
    float c[4][4] = {{0.f}};
    for (int t = 0; t < 400; ++t) {
      const int p = t & 1, q = p ^ 1;
      f32x4 acc[4][4];
      zacc44(acc);
      if (tid == 0 && t >= 1) spin3(CNT(LE1, t - 1), 8, nullptr, 0, nullptr, 0);
      chunk_pass<256, 256>(lds, hb(HE1, q, 0, 256), hb(HE1, q, 1, 256), tid, lane, ut, 1, 256,
                           W + E1HI, W + E1LO, 352, 96, half, acc);
      if (tid == 0)
        spin3(t >= 21 ? CNT(LD3, t - 1) : nullptr, 3, t >= 2 ? CNT(LE2, t - 2) : nullptr, 8,
              nullptr, 0);
      if (t <= 20)
        chunk_pass<96, 128>(lds, xh + (size_t)t * 6144, xl + (size_t)t * 6144, tid, lane, ut, 1,
                            256, W + E1HI, W + E1LO, 352, 0, half, acc);
      else
        chunk_pass<96, 128>(lds, hb(HLAST, q, 0, 96), hb(HLAST, q, 1, 96), tid, lane, ut, 1,
                            256, W + E1HI, W + E1LO, 352, 0, half, acc);
      reduce_pair(lds, lane, pair, half, acc);
      if (!half)
        cell_update(lane, ut, 256, 256, e1b, acc, c, hb(HE1, p, 0, 256), hb(HE1, p, 1, 256),
                    nullptr);
      vm_drain();
      __syncthreads();
      bump(LE1, t);
    }
  } else if (wg < 16) {  // ------------- e2 -------------
    const int ut = (wg - 8) * 2 + pair;
    float c[4][4] = {{0.f}};
    for (int t = 0; t < 400; ++t) {
      const int p = t & 1, q = p ^ 1;
      f32x4 acc[4][4];
      zacc44(acc);
      if (tid == 0 && t >= 1) spin3(CNT(LE2, t - 1), 8, nullptr, 0, nullptr, 0);
      chunk_pass<256, 256>(lds, hb(HE2, q, 0, 256), hb(HE2, q, 1, 256), tid, lane, ut, 1, 256,
                           W + E2HI, W + E2LO, 512, 256, half, acc);
      if (tid == 0)
        spin3(CNT(LE1, t), 8, t >= 2 ? CNT(LE3, t - 2) : nullptr, 8, nullptr, 0);
      chunk_pass<256, 256>(lds, hb(HE1, p, 0, 256), hb(HE1, p, 1, 256), tid, lane, ut, 1, 256,
                           W + E2HI, W + E2LO, 512, 0, half, acc);
      reduce_pair(lds, lane, pair, half, acc);
      if (!half)
        cell_update(lane, ut, 256, 256, e2b, acc, c, hb(HE2, p, 0, 256), hb(HE2, p, 1, 256),
                    nullptr);
      vm_drain();
      __syncthreads();
      bump(LE2, t);
    }
  } else if (wg < 24) {  // ------------- e3 -------------
    const int ut = (wg - 16) * 2 + pair;
    float c[4][4] = {{0.f}};
    for (int t = 0; t < 400; ++t) {
      const int p = t & 1, q = p ^ 1;
      f32x4 acc[4][4];
      zacc44(acc);
      if (tid == 0 && t >= 1) spin3(CNT(LE3, t - 1), 8, nullptr, 0, nullptr, 0);
      chunk_pass<256, 256>(lds, hb(HE3, q, 0, 256), hb(HE3, q, 1, 256), tid, lane, ut, 1, 256,
                           W + E3HI, W + E3LO, 512, 256, half, acc);
      if (tid == 0)
        spin3(CNT(LE2, t), 8, t >= 2 ? CNT(LKV, t - 2) : nullptr, 8, nullptr, 0);
      chunk_pass<256, 256>(lds, hb(HE2, p, 0, 256), hb(HE2, p, 1, 256), tid, lane, ut, 1, 256,
                           W + E3HI, W + E3LO, 512, 0, half, acc);
      reduce_pair(lds, lane, pair, half, acc);
      if (!half)
        cell_update(lane, ut, 256, 256, e3b, acc, c, hb(HE3, p, 0, 256), hb(HE3, p, 1, 256),
                    nullptr);
      vm_drain();
      __syncthreads();
      bump(LE3, t);
    }
  } else if (wg < 32) {  // ------------- kv: 8 WGs (24-27 key, 28-31 val) -------------
    const bool isKey = wg < 28;
    const unsigned short* Whi = W + (isKey ? KHI : VHI);
    const unsigned short* Wlo = W + (isKey ? KLO : VLO);
    const float* bias = isKey ? keyb : valb;
    float* ring = isKey ? ringk : ringv;
    const int jt = (wg - (isKey ? 24 : 28)) * 4 + wv;
    const int col = lane & 15, kg = lane >> 4;
    for (int t = 0; t < 400; ++t) {
      const int p = t & 1;
      const int slot = t % 22;
      if (tid == 0)
        spin3(CNT(LE3, t), 8, t >= 22 ? CNT(LAT, t - 2) : nullptr, 16, nullptr, 0);
      __syncthreads();
      copy_hl<256, 256>(lds, hb(HE3, p, 0, 256), hb(HE3, p, 1, 256), tid);
      __syncthreads();
      float* outp = ring + (size_t)slot * 64 * 256;
      f32x4 acc[4];
#pragma unroll
      for (int m = 0; m < 4; m++) acc[m] = f32x4{0.f, 0.f, 0.f, 0.f};
      mfma_lin<256, 256>(lds, lane, jt, Whi, Wlo, 256, acc);
      int j = jt * 16 + col;
      float bj = bias[j];
#pragma unroll
      for (int m = 0; m < 4; m++)
#pragma unroll
        for (int r = 0; r < 4; r++) {
          int b = m * 16 + kg * 4 + r;
          st_sc_f32(outp + (size_t)b * 256 + j, acc[m][r] + bj);
        }
      vm_drain();
      __syncthreads();
      bump(LKV, t);
    }
  } else if (wg < 48) {  // ------------- attn: 16 WGs, 1 row/wave -------------
    const int b = (wg - 32) * 4 + wv;
    for (int t = 20; t < 400; ++t) {
      if (t == 20) {
        if (tid == 0) spin3(CNT(LKV, 20), 8, nullptr, 0, nullptr, 0);
        __syncthreads();
        // ctx := v20 (ring slot 20)
        const unsigned long long* vp =
            (const unsigned long long*)(ringv + ((size_t)20 * 64 + b) * 256 + lane * 4);
        unsigned long long v0 = ld_sc_u64(vp), v1 = ld_sc_u64(vp + 1);
        float f[4] = {__uint_as_float((unsigned)v0), __uint_as_float((unsigned)(v0 >> 32)),
                      __uint_as_float((unsigned)v1), __uint_as_float((unsigned)(v1 >> 32))};
        unsigned short hi[4], lo[4];
#pragma unroll
        for (int j = 0; j < 4; j++) f2hilo(f[j], hi[j], lo[j]);
        unsigned long long ph = (unsigned long long)hi[0] | ((unsigned long long)hi[1] << 16) |
                                ((unsigned long long)hi[2] << 32) |
                                ((unsigned long long)hi[3] << 48);
        unsigned long long pl = (unsigned long long)lo[0] | ((unsigned long long)lo[1] << 16) |
                                ((unsigned long long)lo[2] << 32) |
                                ((unsigned long long)lo[3] << 48);
        st_sc_u64((unsigned long long*)(ctxh + b * 256 + lane * 4), ph);
        st_sc_u64((unsigned long long*)(ctxl + b * 256 + lane * 4), pl);
      } else {
        if (tid == 0)
          spin3(CNT(LKV, t - 1), 8, CNT(LD2, t - 1), 8, CNT(LD1, t - 1), 8);
        __syncthreads();
        const int qp = (t & 1) ^ 1;
        const unsigned short* qh = hb(HD2, qp, 0, 256);
        const unsigned short* ql = hb(HD2, qp, 1, 256);
        unsigned long long hq = ld_sc_u64((const unsigned long long*)(qh + b * 256 + lane * 4));
        unsigned long long lq = ld_sc_u64((const unsigned long long*)(ql + b * 256 + lane * 4));
        float qv[4];
#pragma unroll
        for (int j = 0; j < 4; j++)
          qv[j] = bf2f((unsigned short)(hq >> (16 * j))) + bf2f((unsigned short)(lq >> (16 * j)));
        float sArr[20];
#pragma unroll
        for (int i = 0; i < 20; i++) {
          int slot = (t - 20 + i) % 22;
          const unsigned long long* kp =
              (const unsigned long long*)(ringk + ((size_t)slot * 64 + b) * 256 + lane * 4);
          unsigned long long k0 = ld_sc_u64(kp), k1 = ld_sc_u64(kp + 1);
          sArr[i] = __uint_as_float((unsigned)k0) * qv[0] +
                    __uint_as_float((unsigned)(k0 >> 32)) * qv[1] +
                    __uint_as_float((unsigned)k1) * qv[2] +
                    __uint_as_float((unsigned)(k1 >> 32)) * qv[3];
        }
#pragma unroll
        for (int off = 32; off >= 1; off >>= 1)
#pragma unroll
          for (int i = 0; i < 20; i++) sArr[i] += __shfl_xor(sArr[i], off, 64);
        float mx = sArr[0];
#pragma unroll
        for (int i = 1; i < 20; i++) mx = fmaxf(mx, sArr[i]);
        float den = 0.f;
#pragma unroll
        for (int i = 0; i < 20; i++) {
          sArr[i] = __expf(sArr[i] - mx);
          den += sArr[i];
        }
        float inv = 1.f / den;
        float a0 = 0.f, a1 = 0.f, a2 = 0.f, a3 = 0.f;
#pragma unroll
        for (int i = 0; i < 20; i++) {
          int slot = (t - 20 + i) % 22;
          const unsigned long long* vp =
              (const unsigned long long*)(ringv + ((size_t)slot * 64 + b) * 256 + lane * 4);
          unsigned long long v0 = ld_sc_u64(vp), v1 = ld_sc_u64(vp + 1);
          a0 += sArr[i] * __uint_as_float((unsigned)v0);
          a1 += sArr[i] * __uint_as_float((unsigned)(v0 >> 32));
          a2 += sArr[i] * __uint_as_float((unsigned)v1);
          a3 += sArr[i] * __uint_as_float((unsigned)(v1 >> 32));
        }
        float f[4] = {a0 * inv, a1 * inv, a2 * inv, a3 * inv};
        unsigned short hi[4], lo[4];
#pragma unroll
        for (int j = 0; j < 4; j++) f2hilo(f[j], hi[j], lo[j]);
        unsigned long long ph = (unsigned long long)hi[0] | ((unsigned long long)hi[1] << 16) |
                                ((unsigned long long)hi[2] << 32) |
                                ((unsigned long long)hi[3] << 48);
        unsigned long long pl = (unsigned long long)lo[0] | ((unsigned long long)lo[1] << 16) |
                                ((unsigned long long)lo[2] << 32) |
                                ((unsigned long long)lo[3] << 48);
        st_sc_u64((unsigned long long*)(ctxh + b * 256 + lane * 4), ph);
        st_sc_u64((unsigned long long*)(ctxl + b * 256 + lane * 4), pl);
      }
      vm_drain();
      __syncthreads();
      bump(LAT, t);
    }
  } else if (wg < 56) {  // ------------- d1 (emb folded): K = 96|256|256, Kp=608 -------
    const int ut = (wg - 48) * 2 + pair;
    float c[4][4] = {{0.f}};
    for (int t = 20; t < 400; ++t) {
      const int p = t & 1, q = p ^ 1;
      f32x4 acc[4][4];
      zacc44(acc);
      if (tid == 0 && t >= 21) spin3(CNT(LD1, t - 1), 8, nullptr, 0, nullptr, 0);
      chunk_pass<256, 256>(lds, hb(HD1, q, 0, 256), hb(HD1, q, 1, 256), tid, lane, ut, 1, 256,
                           W + D1HI, W + D1LO, 608, 352, half, acc);
      if (tid == 0 && t >= 21) spin3(CNT(LD3, t - 1), 3, nullptr, 0, nullptr, 0);
      if (t == 20)
        chunk_pass<96, 128>(lds, xh + (size_t)19 * 6144, xl + (size_t)19 * 6144, tid, lane, ut,
                            1, 256, W + D1HI, W + D1LO, 608, 0, half, acc);
      else
        chunk_pass<96, 128>(lds, hb(HLAST, q, 0, 96), hb(HLAST, q, 1, 96), tid, lane, ut, 1,
                            256, W + D1HI, W + D1LO, 608, 0, half, acc);
      if (tid == 0) spin3(CNT(LAT, t), 16, nullptr, 0, nullptr, 0);
      chunk_pass<256, 256>(lds, ctxh, ctxl, tid, lane, ut, 1, 256, W + D1HI, W + D1LO, 608, 96,
                           half, acc);
      reduce_pair(lds, lane, pair, half, acc);
      if (!half)
        cell_update(lane, ut, 256, 256, d1bp, acc, c, hb(HD1, p, 0, 256), hb(HD1, p, 1, 256),
                    nullptr);
      vm_drain();
      __syncthreads();
      bump(LD1, t);
    }
  } else if (wg < 64) {  // ------------- d2 -------------
    const int ut = (wg - 56) * 2 + pair;
    float c[4][4] = {{0.f}};
    for (int t = 20; t < 400; ++t) {
      const int p = t & 1, q = p ^ 1;
      f32x4 acc[4][4];
      zacc44(acc);
      if (tid == 0 && t >= 21) spin3(CNT(LD2, t - 1), 8, nullptr, 0, nullptr, 0);
      chunk_pass<256, 256>(lds, hb(HD2, q, 0, 256), hb(HD2, q, 1, 256), tid, lane, ut, 1, 256,
                           W + D2HI, W + D2LO, 512, 256, half, acc);
      if (tid == 0) spin3(CNT(LD1, t), 8, nullptr, 0, nullptr, 0);
      chunk_pass<256, 256>(lds, hb(HD1, p, 0, 256), hb(HD1, p, 1, 256), tid, lane, ut, 1, 256,
                           W + D2HI, W + D2LO, 512, 0, half, acc);
      reduce_pair(lds, lane, pair, half, acc);
      if (!half)
        cell_update(lane, ut, 256, 256, d2b, acc, c, hb(HD2, p, 0, 256), hb(HD2, p, 1, 256),
                    nullptr);
      vm_drain();
      __syncthreads();
      bump(LD2, t);
    }
  } else {  // ------------- d3: 3 WGs, ut 0..4 -------------
    const int ut = (wg - 64) * 2 + pair;
    const int utActive = (ut < 5) ? 1 : 0;
    float c[4][4] = {{0.f}};
    for (int t = 20; t < 400; ++t) {
      const int p = t & 1, q = p ^ 1;
      f32x4 acc[4][4];
      zacc44(acc);
      if (tid == 0 && t >= 21) spin3(CNT(LD3, t - 1), 3, nullptr, 0, nullptr, 0);
      chunk_pass<96, 128>(lds, hb(HLAST, q, 0, 96), hb(HLAST, q, 1, 96), tid, lane, ut, utActive,
                          80, W + D3HI, W + D3LO, 352, 256, half, acc);
      if (tid == 0) spin3(CNT(LD2, t), 8, nullptr, 0, nullptr, 0);
      chunk_pass<256, 256>(lds, hb(HD2, p, 0, 256), hb(HD2, p, 1, 256), tid, lane, ut, utActive,
                           80, W + D3HI, W + D3LO, 352, 0, half, acc);
      reduce_pair(lds, lane, pair, half, acc);
      if (!half && utActive)
        cell_update(lane, ut, 80, 96, d3b, acc, c, hb(HLAST, p, 0, 96), hb(HLAST, p, 1, 96),
                    dout + (size_t)(t - 20) * 80);
      vm_drain();
      __syncthreads();
      bump(LD3, t);
    }
  }
}

// ---------------- launch ----------------
extern "C" void kernel_launch(void* const* d_in, const int* in_sizes, int n_in, void* d_out,
                              int out_size, void* d_ws, size_t ws_size, hipStream_t stream) {
  if (ws_size < WS_NEED) return;

  const float* x = (const float*)d_in[0];
  const float* embW = (const float*)d_in[1];
  const float* embB = (const float*)d_in[2];
  const float* e1Wih = (const float*)d_in[3];
  const float* e1Whh = (const float*)d_in[4];
  const float* e1B = (const float*)d_in[5];
  const float* e2Wih = (const float*)d_in[6];
  const float* e2Whh = (const float*)d_in[7];
  const float* e2B = (const float*)d_in[8];
  const float* e3Wih = (const float*)d_in[9];
  const float* e3Whh = (const float*)d_in[10];
  const float* e3B = (const float*)d_in[11];
  const float* d1Wih = (const float*)d_in[12];
  const float* d1Whh = (const float*)d_in[13];
  const float* d1B = (const float*)d_in[14];
  const float* d2Wih = (const float*)d_in[15];
  const float* d2Whh = (const float*)d_in[16];
  const float* d2B = (const float*)d_in[17];
  const float* d3Wih = (const float*)d_in[18];
  const float* d3Whh = (const float*)d_in[19];
  const float* d3B = (const float*)d_in[20];
  const float* keyW = (const float*)d_in[21];
  const float* keyB = (const float*)d_in[22];
  const float* valW = (const float*)d_in[23];
  const float* valB = (const float*)d_in[24];

  unsigned char* ws = (unsigned char*)d_ws;
  unsigned short* W = (unsigned short*)ws;
  float* doutf = (float*)d_out;

  auto launch_w = [&](const float* wih, int din, const float* whh, int dh, int rows, int dinp,
                      int kp, size_t offhi, size_t offlo) {
    size_t tot = (size_t)rows * kp;
    int blocks = (int)((tot + 255) / 256);
    prep_w<<<blocks, 256, 0, stream>>>(wih, din, whh, dh, rows, dinp, kp, W + offhi, W + offlo);
  };
  launch_w(e1Wih, 80, e1Whh, 256, 1024, 96, 352, E1HI, E1LO);
  launch_w(e2Wih, 256, e2Whh, 256, 1024, 256, 512, E2HI, E2LO);
  launch_w(e3Wih, 256, e3Whh, 256, 1024, 256, 512, E3HI, E3LO);
  launch_w(d2Wih, 256, d2Whh, 256, 1024, 256, 512, D2HI, D2LO);
  launch_w(d3Wih, 256, d3Whh, 80, 320, 256, 352, D3HI, D3LO);
  launch_w(keyW, 256, nullptr, 0, 256, 256, 256, KHI, KLO);
  launch_w(valW, 256, nullptr, 0, 256, 256, 256, VHI, VLO);
  // d1 folded weights + bias
  {
    size_t tot = (size_t)1024 * 608;
    prep_d1_w<<<(int)((tot + 255) / 256), 256, 0, stream>>>(d1Wih, d1Whh, embW, W + D1HI,
                                                            W + D1LO);
    prep_d1_bias<<<4, 256, 0, stream>>>(d1Wih, embB, d1B, (float*)(ws + D1BP_B));
  }
  prep_x<<<(int)((XPAD_ELEMS + 255) / 256), 256, 0, stream>>>(
      x, (unsigned short*)(ws + XPAD_HI_B), (unsigned short*)(ws + XPAD_LO_B));
  hipMemsetAsync(ws + STATE_B, 0, STATE_BYTES, stream);

  seq_main<<<dim3(NWG), dim3(WGS), 0, stream>>>(e1B, e2B, e3B, d2B, d3B, keyB, valB, doutf, ws);
}